// Round 1
// baseline (850.647 us; speedup 1.0000x reference)
//
#include <hip/hip_runtime.h>
#include <math.h>

// Problem constants: B=16, H=W=128, C=64, M1=M2=16
// Workspace layout (float offsets):
#define OFF_TBL 0u            // 128 x {cos,sin}(2*pi*m/128)          (256)
#define OFF_S1  256u          // instance-norm-1 raw sums [b*64+c][2] (2048)
#define OFF_S2  2304u         // instance-norm-2 raw sums             (2048)
#define OFF_PQ  4352u         // P[b][h][ky][c][2] aliased with Q[b][h][ky][o][2] (4194304)
#define OFF_X   4198656u      // X[b][kx][ky][c][2]                   (1048576)
#define OFF_O   5247232u      // Out[b][kx][ky][o][2]                 (1048576)
#define OFF_WT  6295808u      // WT[mode][i][o][2]                    (4194304)
// total = 10490112 floats = 41.96 MB

__global__ void k_init(float* __restrict__ ws) {
    int t = threadIdx.x;
    if (t < 128) {
        double ang = 6.283185307179586476925286766559 * (double)t / 128.0;
        ws[OFF_TBL + 2*t]     = (float)cos(ang);
        ws[OFF_TBL + 2*t + 1] = (float)sin(ang);
    }
    for (int i = t; i < 4096; i += 256) ws[OFF_S1 + i] = 0.f;
}

// per-(b,c) sum & sumsq of x, atomically accumulated. grid (hg=16, b=16), 256 thr
__global__ void k_stats1(const float* __restrict__ x, float* __restrict__ ws) {
    __shared__ float red[16][16][8];
    int t = threadIdx.x;
    int hg = blockIdx.x, b = blockIdx.y;
    const float4* x4 = (const float4*)x;
    int q = t & 15, pslot = t >> 4;
    float4 sum = {0,0,0,0}, sq = {0,0,0,0};
    long base = ((long)(b*128 + hg*8)*128) * 16;   // float4 index
    for (int p = pslot; p < 1024; p += 16) {
        float4 v = x4[base + (long)p*16 + q];
        sum.x += v.x; sum.y += v.y; sum.z += v.z; sum.w += v.w;
        sq.x += v.x*v.x; sq.y += v.y*v.y; sq.z += v.z*v.z; sq.w += v.w*v.w;
    }
    red[pslot][q][0]=sum.x; red[pslot][q][1]=sum.y; red[pslot][q][2]=sum.z; red[pslot][q][3]=sum.w;
    red[pslot][q][4]=sq.x;  red[pslot][q][5]=sq.y;  red[pslot][q][6]=sq.z;  red[pslot][q][7]=sq.w;
    __syncthreads();
    if (t < 64) {
        int qq = t >> 2, ci = t & 3;
        float a = 0.f, s = 0.f;
        for (int p = 0; p < 16; p++) { a += red[p][qq][ci]; s += red[p][qq][4+ci]; }
        atomicAdd(&ws[OFF_S1 + (b*64 + t)*2],     a);
        atomicAdd(&ws[OFF_S1 + (b*64 + t)*2 + 1], s);
    }
}

// weight transpose: [i][o][kx][ky] (x4 arrays) -> WT[mode][i][o][{re,im}]. grid 64 (=i)
__global__ void k_trans(const float* __restrict__ w1r, const float* __restrict__ w1i,
                        const float* __restrict__ w2r, const float* __restrict__ w2i,
                        float* __restrict__ ws) {
    __shared__ float Lr[16*257], Li[16*257];
    int t = threadIdx.x;
    int i = blockIdx.x;
    float* WT = ws + OFF_WT;
    for (int part = 0; part < 2; part++) {
        const float* wr = part ? w2r : w1r;
        const float* wi = part ? w2i : w1i;
        for (int oc = 0; oc < 4; oc++) {
            int o0 = oc * 16;
            __syncthreads();
            for (int idx = t; idx < 4096; idx += 256) {
                int oo = idx >> 8, m = idx & 255;
                Lr[oo*257 + m] = wr[(i*64 + o0 + oo)*256 + m];
                Li[oo*257 + m] = wi[(i*64 + o0 + oo)*256 + m];
            }
            __syncthreads();
            for (int idx = t; idx < 8192; idx += 256) {
                int mode = idx >> 5, rem = idx & 31, oo = rem >> 1, ri = rem & 1;
                float val = ri ? Li[oo*257 + mode] : Lr[oo*257 + mode];
                int gm = part*256 + mode;
                WT[((gm*64 + i)*64 + (o0 + oo))*2 + ri] = val;
            }
        }
    }
}

// forward DFT along w (16 ky) with fused instance-norm-1. grid (hg=16,b=16)
__global__ void k_dftw(const float* __restrict__ x, float* __restrict__ ws) {
    __shared__ float xs[128*65];
    __shared__ float tblL[256];
    __shared__ float mu[64], rho[64];
    int t = threadIdx.x;
    int hg = blockIdx.x, b = blockIdx.y;
    for (int i = t; i < 256; i += 256) tblL[i] = ws[OFF_TBL + i];
    if (t < 64) {
        float s1 = ws[OFF_S1 + (b*64+t)*2], s2 = ws[OFF_S1 + (b*64+t)*2 + 1];
        float m = s1 * (1.f/16384.f);
        float v = s2 * (1.f/16384.f) - m*m;
        mu[t] = m; rho[t] = rsqrtf(v + 1e-5f);
    }
    __syncthreads();
    float* P = ws + OFF_PQ;
    int c = t & 63, kyg = t >> 6;
    for (int h = 0; h < 8; h++) {
        int habs = hg*8 + h;
        const float4* row = (const float4*)(x + ((long)(b*128 + habs)*128)*64);
        for (int idx = t; idx < 2048; idx += 256) {
            int w = idx >> 4, qq = idx & 15;
            float4 v = row[idx];
            int c0 = qq*4;
            xs[w*65 + c0]     = (v.x - mu[c0])   * rho[c0];
            xs[w*65 + c0 + 1] = (v.y - mu[c0+1]) * rho[c0+1];
            xs[w*65 + c0 + 2] = (v.z - mu[c0+2]) * rho[c0+2];
            xs[w*65 + c0 + 3] = (v.w - mu[c0+3]) * rho[c0+3];
        }
        __syncthreads();
        float accr[4] = {0,0,0,0}, acci[4] = {0,0,0,0};
        for (int w = 0; w < 128; w++) {
            float v = xs[w*65 + c];
            #pragma unroll
            for (int kk = 0; kk < 4; kk++) {
                int ky = kyg*4 + kk;
                int m = (ky * w) & 127;
                accr[kk] += v * tblL[2*m];      // e^{-i th}: re += v*cos
                acci[kk] -= v * tblL[2*m + 1];  //           im -= v*sin
            }
        }
        #pragma unroll
        for (int kk = 0; kk < 4; kk++) {
            int ky = kyg*4 + kk;
            float2* dst = (float2*)(P + (((b*128 + habs)*16 + ky)*128));
            dst[c] = make_float2(accr[kk], acci[kk]);
        }
        __syncthreads();
    }
}

// forward DFT along h (32 kx rows: 0..15 and 112..127). grid (ky=16, b=16)
__global__ void k_dfth(float* __restrict__ ws) {
    __shared__ float Ps[2048];
    __shared__ float tblL[256];
    int t = threadIdx.x;
    int ky = blockIdx.x, b = blockIdx.y;
    for (int i = t; i < 256; i += 256) tblL[i] = ws[OFF_TBL + i];
    const float* P = ws + OFF_PQ;
    float* X = ws + OFF_X;
    int c = t & 63, kxg = t >> 6;
    float accr[8] = {0,0,0,0,0,0,0,0}, acci[8] = {0,0,0,0,0,0,0,0};
    for (int hc = 0; hc < 8; hc++) {
        __syncthreads();
        for (int idx = t; idx < 2048; idx += 256) {
            int hh = idx >> 7, r = idx & 127;
            Ps[idx] = P[((long)((b*128 + hc*16 + hh)*16 + ky))*128 + r];
        }
        __syncthreads();
        for (int hh = 0; hh < 16; hh++) {
            int habs = hc*16 + hh;
            float vr = Ps[hh*128 + c*2], vi = Ps[hh*128 + c*2 + 1];
            #pragma unroll
            for (int kk = 0; kk < 8; kk++) {
                int kxI = kxg*8 + kk;
                int freq = kxI < 16 ? kxI : 96 + kxI;   // 112..127
                int m = (freq * habs) & 127;
                float cs = tblL[2*m], sn = tblL[2*m + 1];
                accr[kk] += vr*cs + vi*sn;              // * e^{-i th}
                acci[kk] += vi*cs - vr*sn;
            }
        }
    }
    #pragma unroll
    for (int kk = 0; kk < 8; kk++) {
        int kxI = kxg*8 + kk;
        float2* dst = (float2*)(X + (((b*32 + kxI)*16 + ky)*128));
        dst[c] = make_float2(accr[kk], acci[kk]);
    }
}

// per-mode complex mix: Out[b][o] = sum_i X[b][i] * W[i][o]. grid 512 (=mode)
__global__ void k_mix(float* __restrict__ ws) {
    __shared__ float Wsh[8192];
    __shared__ float Xs[2048];
    int t = threadIdx.x;
    int mode = blockIdx.x;
    int kxI = mode >> 4, ky = mode & 15;
    const float* WT = ws + OFF_WT;
    const float* X = ws + OFF_X;
    float* O = ws + OFF_O;
    for (int idx = t; idx < 8192; idx += 256) Wsh[idx] = WT[(long)mode*8192 + idx];
    for (int idx = t; idx < 2048; idx += 256) {
        int b = idx >> 7, r = idx & 127;
        Xs[idx] = X[((b*32 + kxI)*16 + ky)*128 + r];
    }
    __syncthreads();
    int o = t & 63, bg = t >> 6;
    float accr[4] = {0,0,0,0}, acci[4] = {0,0,0,0};
    for (int i = 0; i < 64; i++) {
        float wr = Wsh[(i*64 + o)*2], wi = Wsh[(i*64 + o)*2 + 1];
        #pragma unroll
        for (int j = 0; j < 4; j++) {
            float xr = Xs[(bg*4 + j)*128 + 2*i], xi = Xs[(bg*4 + j)*128 + 2*i + 1];
            accr[j] += xr*wr - xi*wi;
            acci[j] += xr*wi + xi*wr;
        }
    }
    #pragma unroll
    for (int j = 0; j < 4; j++) {
        int b = bg*4 + j;
        float2* dst = (float2*)(O + ((b*32 + kxI)*16 + ky)*128);
        dst[o] = make_float2(accr[j], acci[j]);
    }
}

// inverse DFT along h: Q[b][h][ky][o] = sum_kx Out[b][kx][ky][o] e^{+i 2pi kx h/128}. grid (hg=16,b=16)
__global__ void k_idfth(float* __restrict__ ws) {
    __shared__ float Os[8192];
    __shared__ float tblL[256];
    int t = threadIdx.x;
    int hg = blockIdx.x, b = blockIdx.y;
    for (int i = t; i < 256; i += 256) tblL[i] = ws[OFF_TBL + i];
    const float* O = ws + OFF_O;
    float* Q = ws + OFF_PQ;
    int o = t & 63, kyg = t >> 6;
    float accr[4][8], acci[4][8];
    #pragma unroll
    for (int kk = 0; kk < 4; kk++)
        #pragma unroll
        for (int h = 0; h < 8; h++) { accr[kk][h] = 0.f; acci[kk][h] = 0.f; }
    for (int kc = 0; kc < 8; kc++) {
        __syncthreads();
        for (int idx = t; idx < 8192; idx += 256) Os[idx] = O[(long)b*65536 + kc*8192 + idx];
        __syncthreads();
        for (int k4 = 0; k4 < 4; k4++) {
            int kxI = kc*4 + k4;
            int freq = kxI < 16 ? kxI : 96 + kxI;
            float vr[4], vi[4];
            #pragma unroll
            for (int kk = 0; kk < 4; kk++) {
                int ky = kyg*4 + kk;
                vr[kk] = Os[((k4*16 + ky)*64 + o)*2];
                vi[kk] = Os[((k4*16 + ky)*64 + o)*2 + 1];
            }
            for (int h = 0; h < 8; h++) {
                int habs = hg*8 + h;
                int m = (freq * habs) & 127;
                float cs = tblL[2*m], sn = tblL[2*m + 1];
                #pragma unroll
                for (int kk = 0; kk < 4; kk++) {
                    accr[kk][h] += vr[kk]*cs - vi[kk]*sn;   // * e^{+i th}
                    acci[kk][h] += vr[kk]*sn + vi[kk]*cs;
                }
            }
        }
    }
    #pragma unroll
    for (int kk = 0; kk < 4; kk++)
        #pragma unroll
        for (int h = 0; h < 8; h++) {
            int ky = kyg*4 + kk, habs = hg*8 + h;
            float2* dst = (float2*)(Q + ((long)(b*128 + habs)*16 + ky)*128);
            dst[o] = make_float2(accr[kk][h], acci[kk][h]);
        }
}

// stats of y (computed on the fly from Q). grid (hg=16,b=16)
__global__ void k_stats2(float* __restrict__ ws) {
    __shared__ float Qs[2048];
    __shared__ float tblL[256];
    __shared__ float red[256][2];
    int t = threadIdx.x;
    int hg = blockIdx.x, b = blockIdx.y;
    for (int i = t; i < 256; i += 256) tblL[i] = ws[OFF_TBL + i];
    const float* Q = ws + OFF_PQ;
    int o = t & 63, wg = t >> 6;
    float s1 = 0.f, s2 = 0.f;
    const float sc = 1.f/16384.f;
    for (int h = 0; h < 8; h++) {
        int habs = hg*8 + h;
        __syncthreads();
        for (int idx = t; idx < 2048; idx += 256) Qs[idx] = Q[(long)(b*128 + habs)*2048 + idx];
        __syncthreads();
        float qr[16], qi[16];
        #pragma unroll
        for (int ky = 0; ky < 16; ky++) { qr[ky] = Qs[(ky*64 + o)*2]; qi[ky] = Qs[(ky*64 + o)*2 + 1]; }
        for (int ww = 0; ww < 32; ww++) {
            int w = wg*32 + ww;
            float y = qr[0];
            #pragma unroll
            for (int ky = 1; ky < 16; ky++) {
                int m = (ky * w) & 127;
                y += 2.f * (qr[ky]*tblL[2*m] - qi[ky]*tblL[2*m + 1]);
            }
            y *= sc;
            s1 += y; s2 += y*y;
        }
    }
    red[t][0] = s1; red[t][1] = s2;
    __syncthreads();
    if (t < 64) {
        float a  = red[t][0] + red[t+64][0] + red[t+128][0] + red[t+192][0];
        float s  = red[t][1] + red[t+64][1] + red[t+128][1] + red[t+192][1];
        atomicAdd(&ws[OFF_S2 + (b*64 + t)*2],     a);
        atomicAdd(&ws[OFF_S2 + (b*64 + t)*2 + 1], s);
    }
}

// fused: recompute y from Q, instance-norm-2, MLP (64->128 GELU ->64). grid (h=128,b=16)
__global__ __launch_bounds__(256) void k_mlp(const float* __restrict__ mw1, const float* __restrict__ mb1,
                      const float* __restrict__ mw2, const float* __restrict__ mb2,
                      float* __restrict__ out, float* __restrict__ ws) {
    __shared__ float zs[128*65];
    __shared__ float hid[128*33];
    __shared__ float Qs[2048];
    __shared__ float tblL[256];
    __shared__ float mu[64], rho[64];
    int t = threadIdx.x;
    int h = blockIdx.x, b = blockIdx.y;
    for (int i = t; i < 256; i += 256) tblL[i] = ws[OFF_TBL + i];
    if (t < 64) {
        float s1 = ws[OFF_S2 + (b*64+t)*2], s2 = ws[OFF_S2 + (b*64+t)*2 + 1];
        float m = s1 * (1.f/16384.f);
        float v = s2 * (1.f/16384.f) - m*m;
        mu[t] = m; rho[t] = rsqrtf(v + 1e-5f);
    }
    const float* Q = ws + OFF_PQ;
    for (int idx = t; idx < 2048; idx += 256) Qs[idx] = Q[(long)(b*128 + h)*2048 + idx];
    __syncthreads();
    {   // z tile: normalize recomputed y
        int c = t & 63, wg = t >> 6;
        float qr[16], qi[16];
        #pragma unroll
        for (int ky = 0; ky < 16; ky++) { qr[ky] = Qs[(ky*64 + c)*2]; qi[ky] = Qs[(ky*64 + c)*2 + 1]; }
        float m_ = mu[c], r_ = rho[c];
        for (int ww = 0; ww < 32; ww++) {
            int w = wg*32 + ww;
            float y = qr[0];
            #pragma unroll
            for (int ky = 1; ky < 16; ky++) {
                int mm = (ky * w) & 127;
                y += 2.f * (qr[ky]*tblL[2*mm] - qi[ky]*tblL[2*mm + 1]);
            }
            y *= (1.f/16384.f);
            zs[w*65 + c] = (y - m_) * r_;
        }
    }
    __syncthreads();
    int w = t & 127, og = t >> 7;
    float zreg[64];
    #pragma unroll
    for (int c = 0; c < 64; c++) zreg[c] = zs[w*65 + c];
    float acc[32];
    #pragma unroll
    for (int i = 0; i < 32; i++) acc[i] = 0.f;
    for (int jq = 0; jq < 4; jq++) {
        // phase 1: hidden j in [jq*32, jq*32+32)
        for (int jj = 0; jj < 16; jj++) {
            int jl = og*16 + jj;        // local 0..31
            int j = jq*32 + jl;
            const float* wrow = mw1 + j*64;
            float a0 = 0.f, a1 = 0.f, a2 = 0.f, a3 = 0.f;
            #pragma unroll
            for (int c = 0; c < 64; c += 4) {
                a0 += wrow[c]   * zreg[c];
                a1 += wrow[c+1] * zreg[c+1];
                a2 += wrow[c+2] * zreg[c+2];
                a3 += wrow[c+3] * zreg[c+3];
            }
            float hv = mb1[j] + a0 + a1 + a2 + a3;
            hv = 0.5f * hv * (1.f + erff(hv * 0.70710678118654752f));  // exact GELU
            hid[w*33 + jl] = hv;
        }
        __syncthreads();
        // phase 2: accumulate outputs over this j-quarter
        float hreg[32];
        #pragma unroll
        for (int jl = 0; jl < 32; jl++) hreg[jl] = hid[w*33 + jl];
        for (int ol = 0; ol < 32; ol++) {
            int oo = og*32 + ol;
            const float* w2row = mw2 + oo*128 + jq*32;
            float a0 = 0.f, a1 = 0.f, a2 = 0.f, a3 = 0.f;
            #pragma unroll
            for (int jl = 0; jl < 32; jl += 4) {
                a0 += w2row[jl]   * hreg[jl];
                a1 += w2row[jl+1] * hreg[jl+1];
                a2 += w2row[jl+2] * hreg[jl+2];
                a3 += w2row[jl+3] * hreg[jl+3];
            }
            acc[ol] += a0 + a1 + a2 + a3;
        }
        __syncthreads();
    }
    float* dst = out + ((long)(b*128 + h)*128 + w)*64 + og*32;
    #pragma unroll
    for (int ol = 0; ol < 32; ol++) dst[ol] = acc[ol] + mb2[og*32 + ol];
}

extern "C" void kernel_launch(void* const* d_in, const int* in_sizes, int n_in,
                              void* d_out, int out_size, void* d_ws, size_t ws_size,
                              hipStream_t stream) {
    const float* x   = (const float*)d_in[0];
    const float* w1r = (const float*)d_in[1];
    const float* w1i = (const float*)d_in[2];
    const float* w2r = (const float*)d_in[3];
    const float* w2i = (const float*)d_in[4];
    const float* mw1 = (const float*)d_in[5];
    const float* mb1 = (const float*)d_in[6];
    const float* mw2 = (const float*)d_in[7];
    const float* mb2 = (const float*)d_in[8];
    float* ws  = (float*)d_ws;
    float* out = (float*)d_out;

    k_init  <<<dim3(1),      dim3(256), 0, stream>>>(ws);
    k_stats1<<<dim3(16,16),  dim3(256), 0, stream>>>(x, ws);
    k_trans <<<dim3(64),     dim3(256), 0, stream>>>(w1r, w1i, w2r, w2i, ws);
    k_dftw  <<<dim3(16,16),  dim3(256), 0, stream>>>(x, ws);
    k_dfth  <<<dim3(16,16),  dim3(256), 0, stream>>>(ws);
    k_mix   <<<dim3(512),    dim3(256), 0, stream>>>(ws);
    k_idfth <<<dim3(16,16),  dim3(256), 0, stream>>>(ws);
    k_stats2<<<dim3(16,16),  dim3(256), 0, stream>>>(ws);
    k_mlp   <<<dim3(128,16), dim3(256), 0, stream>>>(mw1, mb1, mw2, mb2, out, ws);
}

// Round 2
// 840.290 us; speedup vs baseline: 1.0123x; 1.0123x over previous
//
#include <hip/hip_runtime.h>
#include <math.h>

// Problem constants: B=16, H=W=128, C=64, M1=M2=16
// Workspace layout (float offsets):
#define OFF_TBL 0u            // 128 x {cos,sin}(2*pi*m/128)          (256)
#define OFF_S1  256u          // instance-norm-1 raw sums [b*64+c][2] (2048)
#define OFF_S2  2304u         // instance-norm-2 raw sums             (2048)
#define OFF_PQ  4352u         // P[b][h][ky][c][2] aliased with Q[b][h][ky][o][2] (4194304)
#define OFF_X   4198656u      // X[b][kx][ky][c][2]                   (1048576)
#define OFF_O   5247232u      // Out[b][kx][ky][o][2]                 (1048576)
#define OFF_WT  6295808u      // WT[mode][i][o][2]                    (4194304)
// total = 10490112 floats = 41.96 MB
// X region is dead after k_mix -> reuse for transposed MLP weights:
#define OFF_WM  OFF_X         // w1T[64][128] (8192) then w2T[128][64] (8192)

__global__ void k_init(float* __restrict__ ws) {
    int t = threadIdx.x;
    if (t < 128) {
        double ang = 6.283185307179586476925286766559 * (double)t / 128.0;
        ws[OFF_TBL + 2*t]     = (float)cos(ang);
        ws[OFF_TBL + 2*t + 1] = (float)sin(ang);
    }
    for (int i = t; i < 4096; i += 256) ws[OFF_S1 + i] = 0.f;
}

// per-(b,c) sum & sumsq of x, atomically accumulated. grid (hg=16, b=16), 256 thr
__global__ void k_stats1(const float* __restrict__ x, float* __restrict__ ws) {
    __shared__ float red[16][16][8];
    int t = threadIdx.x;
    int hg = blockIdx.x, b = blockIdx.y;
    const float4* x4 = (const float4*)x;
    int q = t & 15, pslot = t >> 4;
    float4 sum = {0,0,0,0}, sq = {0,0,0,0};
    long base = ((long)(b*128 + hg*8)*128) * 16;   // float4 index
    for (int p = pslot; p < 1024; p += 16) {
        float4 v = x4[base + (long)p*16 + q];
        sum.x += v.x; sum.y += v.y; sum.z += v.z; sum.w += v.w;
        sq.x += v.x*v.x; sq.y += v.y*v.y; sq.z += v.z*v.z; sq.w += v.w*v.w;
    }
    red[pslot][q][0]=sum.x; red[pslot][q][1]=sum.y; red[pslot][q][2]=sum.z; red[pslot][q][3]=sum.w;
    red[pslot][q][4]=sq.x;  red[pslot][q][5]=sq.y;  red[pslot][q][6]=sq.z;  red[pslot][q][7]=sq.w;
    __syncthreads();
    if (t < 64) {
        int qq = t >> 2, ci = t & 3;
        float a = 0.f, s = 0.f;
        for (int p = 0; p < 16; p++) { a += red[p][qq][ci]; s += red[p][qq][4+ci]; }
        atomicAdd(&ws[OFF_S1 + (b*64 + t)*2],     a);
        atomicAdd(&ws[OFF_S1 + (b*64 + t)*2 + 1], s);
    }
}

// weight transpose: [i][o][kx][ky] (x4 arrays) -> WT[mode][i][o][{re,im}]. grid 64 (=i)
__global__ void k_trans(const float* __restrict__ w1r, const float* __restrict__ w1i,
                        const float* __restrict__ w2r, const float* __restrict__ w2i,
                        float* __restrict__ ws) {
    __shared__ float Lr[16*257], Li[16*257];
    int t = threadIdx.x;
    int i = blockIdx.x;
    float* WT = ws + OFF_WT;
    for (int part = 0; part < 2; part++) {
        const float* wr = part ? w2r : w1r;
        const float* wi = part ? w2i : w1i;
        for (int oc = 0; oc < 4; oc++) {
            int o0 = oc * 16;
            __syncthreads();
            for (int idx = t; idx < 4096; idx += 256) {
                int oo = idx >> 8, m = idx & 255;
                Lr[oo*257 + m] = wr[(i*64 + o0 + oo)*256 + m];
                Li[oo*257 + m] = wi[(i*64 + o0 + oo)*256 + m];
            }
            __syncthreads();
            for (int idx = t; idx < 8192; idx += 256) {
                int mode = idx >> 5, rem = idx & 31, oo = rem >> 1, ri = rem & 1;
                float val = ri ? Li[oo*257 + mode] : Lr[oo*257 + mode];
                int gm = part*256 + mode;
                WT[((gm*64 + i)*64 + (o0 + oo))*2 + ri] = val;
            }
        }
    }
}

// MLP weight transposes: w1T[c][j] = mw1[j][c]; w2T[j][o] = mw2[o][j]. grid 64
__global__ void k_wmlp(const float* __restrict__ mw1, const float* __restrict__ mw2,
                       float* __restrict__ ws) {
    int i = blockIdx.x * 256 + threadIdx.x;   // 0..16383
    if (i < 8192) {
        int c = i >> 7, j = i & 127;
        ws[OFF_WM + i] = mw1[j*64 + c];
    } else {
        int k = i - 8192;
        int j = k >> 6, o = k & 63;
        ws[OFF_WM + 8192 + k] = mw2[o*128 + j];
    }
}

// forward DFT along w (16 ky) with fused instance-norm-1. grid (hg=16,b=16)
__global__ void k_dftw(const float* __restrict__ x, float* __restrict__ ws) {
    __shared__ float xs[128*65];
    __shared__ float tblL[256];
    __shared__ float mu[64], rho[64];
    int t = threadIdx.x;
    int hg = blockIdx.x, b = blockIdx.y;
    for (int i = t; i < 256; i += 256) tblL[i] = ws[OFF_TBL + i];
    if (t < 64) {
        float s1 = ws[OFF_S1 + (b*64+t)*2], s2 = ws[OFF_S1 + (b*64+t)*2 + 1];
        float m = s1 * (1.f/16384.f);
        float v = s2 * (1.f/16384.f) - m*m;
        mu[t] = m; rho[t] = rsqrtf(v + 1e-5f);
    }
    __syncthreads();
    float* P = ws + OFF_PQ;
    int c = t & 63, kyg = t >> 6;
    for (int h = 0; h < 8; h++) {
        int habs = hg*8 + h;
        const float4* row = (const float4*)(x + ((long)(b*128 + habs)*128)*64);
        for (int idx = t; idx < 2048; idx += 256) {
            int w = idx >> 4, qq = idx & 15;
            float4 v = row[idx];
            int c0 = qq*4;
            xs[w*65 + c0]     = (v.x - mu[c0])   * rho[c0];
            xs[w*65 + c0 + 1] = (v.y - mu[c0+1]) * rho[c0+1];
            xs[w*65 + c0 + 2] = (v.z - mu[c0+2]) * rho[c0+2];
            xs[w*65 + c0 + 3] = (v.w - mu[c0+3]) * rho[c0+3];
        }
        __syncthreads();
        float accr[4] = {0,0,0,0}, acci[4] = {0,0,0,0};
        for (int w = 0; w < 128; w++) {
            float v = xs[w*65 + c];
            #pragma unroll
            for (int kk = 0; kk < 4; kk++) {
                int ky = kyg*4 + kk;
                int m = (ky * w) & 127;
                accr[kk] += v * tblL[2*m];      // e^{-i th}: re += v*cos
                acci[kk] -= v * tblL[2*m + 1];  //           im -= v*sin
            }
        }
        #pragma unroll
        for (int kk = 0; kk < 4; kk++) {
            int ky = kyg*4 + kk;
            float2* dst = (float2*)(P + (((b*128 + habs)*16 + ky)*128));
            dst[c] = make_float2(accr[kk], acci[kk]);
        }
        __syncthreads();
    }
}

// forward DFT along h (32 kx rows: 0..15 and 112..127). grid (ky=16, b=16)
__global__ void k_dfth(float* __restrict__ ws) {
    __shared__ float Ps[2048];
    __shared__ float tblL[256];
    int t = threadIdx.x;
    int ky = blockIdx.x, b = blockIdx.y;
    for (int i = t; i < 256; i += 256) tblL[i] = ws[OFF_TBL + i];
    const float* P = ws + OFF_PQ;
    float* X = ws + OFF_X;
    int c = t & 63, kxg = t >> 6;
    float accr[8] = {0,0,0,0,0,0,0,0}, acci[8] = {0,0,0,0,0,0,0,0};
    for (int hc = 0; hc < 8; hc++) {
        __syncthreads();
        for (int idx = t; idx < 2048; idx += 256) {
            int hh = idx >> 7, r = idx & 127;
            Ps[idx] = P[((long)((b*128 + hc*16 + hh)*16 + ky))*128 + r];
        }
        __syncthreads();
        for (int hh = 0; hh < 16; hh++) {
            int habs = hc*16 + hh;
            float vr = Ps[hh*128 + c*2], vi = Ps[hh*128 + c*2 + 1];
            #pragma unroll
            for (int kk = 0; kk < 8; kk++) {
                int kxI = kxg*8 + kk;
                int freq = kxI < 16 ? kxI : 96 + kxI;   // 112..127
                int m = (freq * habs) & 127;
                float cs = tblL[2*m], sn = tblL[2*m + 1];
                accr[kk] += vr*cs + vi*sn;              // * e^{-i th}
                acci[kk] += vi*cs - vr*sn;
            }
        }
    }
    #pragma unroll
    for (int kk = 0; kk < 8; kk++) {
        int kxI = kxg*8 + kk;
        float2* dst = (float2*)(X + (((b*32 + kxI)*16 + ky)*128));
        dst[c] = make_float2(accr[kk], acci[kk]);
    }
}

// per-mode complex mix: Out[b][o] = sum_i X[b][i] * W[i][o]. grid 512 (=mode)
__global__ void k_mix(float* __restrict__ ws) {
    __shared__ float Wsh[8192];
    __shared__ float Xs[2048];
    int t = threadIdx.x;
    int mode = blockIdx.x;
    int kxI = mode >> 4, ky = mode & 15;
    const float* WT = ws + OFF_WT;
    const float* X = ws + OFF_X;
    float* O = ws + OFF_O;
    for (int idx = t; idx < 8192; idx += 256) Wsh[idx] = WT[(long)mode*8192 + idx];
    for (int idx = t; idx < 2048; idx += 256) {
        int b = idx >> 7, r = idx & 127;
        Xs[idx] = X[((b*32 + kxI)*16 + ky)*128 + r];
    }
    __syncthreads();
    int o = t & 63, bg = t >> 6;
    float accr[4] = {0,0,0,0}, acci[4] = {0,0,0,0};
    for (int i = 0; i < 64; i++) {
        float wr = Wsh[(i*64 + o)*2], wi = Wsh[(i*64 + o)*2 + 1];
        #pragma unroll
        for (int j = 0; j < 4; j++) {
            float xr = Xs[(bg*4 + j)*128 + 2*i], xi = Xs[(bg*4 + j)*128 + 2*i + 1];
            accr[j] += xr*wr - xi*wi;
            acci[j] += xr*wi + xi*wr;
        }
    }
    #pragma unroll
    for (int j = 0; j < 4; j++) {
        int b = bg*4 + j;
        float2* dst = (float2*)(O + ((b*32 + kxI)*16 + ky)*128);
        dst[o] = make_float2(accr[j], acci[j]);
    }
}

// inverse DFT along h: Q[b][h][ky][o] = sum_kx Out[b][kx][ky][o] e^{+i 2pi kx h/128}. grid (hg=16,b=16)
__global__ void k_idfth(float* __restrict__ ws) {
    __shared__ float Os[8192];
    __shared__ float tblL[256];
    int t = threadIdx.x;
    int hg = blockIdx.x, b = blockIdx.y;
    for (int i = t; i < 256; i += 256) tblL[i] = ws[OFF_TBL + i];
    const float* O = ws + OFF_O;
    float* Q = ws + OFF_PQ;
    int o = t & 63, kyg = t >> 6;
    float accr[4][8], acci[4][8];
    #pragma unroll
    for (int kk = 0; kk < 4; kk++)
        #pragma unroll
        for (int h = 0; h < 8; h++) { accr[kk][h] = 0.f; acci[kk][h] = 0.f; }
    for (int kc = 0; kc < 8; kc++) {
        __syncthreads();
        for (int idx = t; idx < 8192; idx += 256) Os[idx] = O[(long)b*65536 + kc*8192 + idx];
        __syncthreads();
        for (int k4 = 0; k4 < 4; k4++) {
            int kxI = kc*4 + k4;
            int freq = kxI < 16 ? kxI : 96 + kxI;
            float vr[4], vi[4];
            #pragma unroll
            for (int kk = 0; kk < 4; kk++) {
                int ky = kyg*4 + kk;
                vr[kk] = Os[((k4*16 + ky)*64 + o)*2];
                vi[kk] = Os[((k4*16 + ky)*64 + o)*2 + 1];
            }
            for (int h = 0; h < 8; h++) {
                int habs = hg*8 + h;
                int m = (freq * habs) & 127;
                float cs = tblL[2*m], sn = tblL[2*m + 1];
                #pragma unroll
                for (int kk = 0; kk < 4; kk++) {
                    accr[kk][h] += vr[kk]*cs - vi[kk]*sn;   // * e^{+i th}
                    acci[kk][h] += vr[kk]*sn + vi[kk]*cs;
                }
            }
        }
    }
    #pragma unroll
    for (int kk = 0; kk < 4; kk++)
        #pragma unroll
        for (int h = 0; h < 8; h++) {
            int ky = kyg*4 + kk, habs = hg*8 + h;
            float2* dst = (float2*)(Q + ((long)(b*128 + habs)*16 + ky)*128);
            dst[o] = make_float2(accr[kk][h], acci[kk][h]);
        }
}

// stats of y (computed on the fly from Q). grid (hg=16,b=16)
__global__ void k_stats2(float* __restrict__ ws) {
    __shared__ float Qs[2048];
    __shared__ float tblL[256];
    __shared__ float red[256][2];
    int t = threadIdx.x;
    int hg = blockIdx.x, b = blockIdx.y;
    for (int i = t; i < 256; i += 256) tblL[i] = ws[OFF_TBL + i];
    const float* Q = ws + OFF_PQ;
    int o = t & 63, wg = t >> 6;
    float s1 = 0.f, s2 = 0.f;
    const float sc = 1.f/16384.f;
    for (int h = 0; h < 8; h++) {
        int habs = hg*8 + h;
        __syncthreads();
        for (int idx = t; idx < 2048; idx += 256) Qs[idx] = Q[(long)(b*128 + habs)*2048 + idx];
        __syncthreads();
        float qr[16], qi[16];
        #pragma unroll
        for (int ky = 0; ky < 16; ky++) { qr[ky] = Qs[(ky*64 + o)*2]; qi[ky] = Qs[(ky*64 + o)*2 + 1]; }
        for (int ww = 0; ww < 32; ww++) {
            int w = wg*32 + ww;
            float y = qr[0];
            #pragma unroll
            for (int ky = 1; ky < 16; ky++) {
                int m = (ky * w) & 127;
                y += 2.f * (qr[ky]*tblL[2*m] - qi[ky]*tblL[2*m + 1]);
            }
            y *= sc;
            s1 += y; s2 += y*y;
        }
    }
    red[t][0] = s1; red[t][1] = s2;
    __syncthreads();
    if (t < 64) {
        float a  = red[t][0] + red[t+64][0] + red[t+128][0] + red[t+192][0];
        float s  = red[t][1] + red[t+64][1] + red[t+128][1] + red[t+192][1];
        atomicAdd(&ws[OFF_S2 + (b*64 + t)*2],     a);
        atomicAdd(&ws[OFF_S2 + (b*64 + t)*2 + 1], s);
    }
}

// fused: recompute y from Q, instance-norm-2, MLP (64->128 GELU ->64). grid (h=128,b=16)
// Two-phase j-chunked schedule; hid stays in LDS; weights read as float4 from
// pre-transposed w1T/w2T (L1-resident, 32KB each).
__global__ __launch_bounds__(256) void k_mlp(const float* __restrict__ mb1,
                      const float* __restrict__ mb2,
                      float* __restrict__ out, const float* __restrict__ ws) {
    __shared__ float zs[128*65];     // z[tok][c], pad 65 -> conflict-free
    __shared__ float hidL[128*33];   // hid chunk [tok][32j], pad 33
    __shared__ float tblL[256];
    __shared__ float mu[64], rho[64];
    int t = threadIdx.x;
    int h = blockIdx.x, b = blockIdx.y;
    for (int i = t; i < 256; i += 256) tblL[i] = ws[OFF_TBL + i];
    if (t < 64) {
        float s1 = ws[OFF_S2 + (b*64+t)*2], s2 = ws[OFF_S2 + (b*64+t)*2 + 1];
        float m = s1 * (1.f/16384.f);
        float v = s2 * (1.f/16384.f) - m*m;
        mu[t] = m; rho[t] = rsqrtf(v + 1e-5f);
    }
    __syncthreads();
    {   // z tile: normalize recomputed y (Q read directly from global, coalesced)
        int c = t & 63, wg = t >> 6;
        const float2* Qrow = (const float2*)(ws + OFF_PQ + (long)(b*128 + h)*2048);
        float qr[16], qi[16];
        #pragma unroll
        for (int ky = 0; ky < 16; ky++) { float2 v = Qrow[ky*64 + c]; qr[ky] = v.x; qi[ky] = v.y; }
        float m_ = mu[c], r_ = rho[c];
        for (int ww = 0; ww < 32; ww++) {
            int w = wg*32 + ww;
            float y = qr[0];
            #pragma unroll
            for (int ky = 1; ky < 16; ky++) {
                int mm = (ky * w) & 127;
                y += 2.f * (qr[ky]*tblL[2*mm] - qi[ky]*tblL[2*mm + 1]);
            }
            y *= (1.f/16384.f);
            zs[w*65 + c] = (y - m_) * r_;
        }
    }
    __syncthreads();
    const float4* w1t4 = (const float4*)(ws + OFF_WM);          // w1T[64][128]
    const float4* w2t4 = (const float4*)(ws + OFF_WM + 8192);   // w2T[128][64]
    int tokA = t & 127, jh = t >> 7;            // phase A: 16 j per thread
    int lane = t & 63, wv = t >> 6;
    int tokB = (wv & 1)*64 + lane, o0 = (wv >> 1)*32;  // phase B: 32 o per thread
    float accB[32];
    #pragma unroll
    for (int i = 0; i < 32; i++) accB[i] = 0.f;
    for (int p = 0; p < 4; p++) {
        // ---- phase A: hid[:, p*32 .. p*32+32) ----
        int j0 = p*32 + jh*16;
        float a[16];
        #pragma unroll
        for (int i = 0; i < 16; i++) a[i] = 0.f;
        #pragma unroll 4
        for (int c = 0; c < 64; c++) {
            float zv = zs[tokA*65 + c];
            int wbase = (c*128 + j0) >> 2;
            float4 wA = w1t4[wbase];
            float4 wB = w1t4[wbase + 1];
            float4 wC = w1t4[wbase + 2];
            float4 wD = w1t4[wbase + 3];
            a[0]  += zv*wA.x; a[1]  += zv*wA.y; a[2]  += zv*wA.z; a[3]  += zv*wA.w;
            a[4]  += zv*wB.x; a[5]  += zv*wB.y; a[6]  += zv*wB.z; a[7]  += zv*wB.w;
            a[8]  += zv*wC.x; a[9]  += zv*wC.y; a[10] += zv*wC.z; a[11] += zv*wC.w;
            a[12] += zv*wD.x; a[13] += zv*wD.y; a[14] += zv*wD.z; a[15] += zv*wD.w;
        }
        #pragma unroll
        for (int i = 0; i < 16; i++) {
            float hv = a[i] + mb1[j0 + i];
            hv = 0.5f * hv * (1.f + erff(hv * 0.70710678118654752f));  // exact GELU
            hidL[tokA*33 + jh*16 + i] = hv;
        }
        __syncthreads();
        // ---- phase B: accB[o] += w2[o][j-chunk] . hid[tokB][j-chunk] ----
        #pragma unroll 4
        for (int jl = 0; jl < 32; jl++) {
            int j = p*32 + jl;
            float hv = hidL[tokB*33 + jl];
            int ubase = (j*64 + o0) >> 2;
            float4 u0 = w2t4[ubase];
            float4 u1 = w2t4[ubase + 1];
            float4 u2 = w2t4[ubase + 2];
            float4 u3 = w2t4[ubase + 3];
            float4 u4 = w2t4[ubase + 4];
            float4 u5 = w2t4[ubase + 5];
            float4 u6 = w2t4[ubase + 6];
            float4 u7 = w2t4[ubase + 7];
            accB[0]  += hv*u0.x; accB[1]  += hv*u0.y; accB[2]  += hv*u0.z; accB[3]  += hv*u0.w;
            accB[4]  += hv*u1.x; accB[5]  += hv*u1.y; accB[6]  += hv*u1.z; accB[7]  += hv*u1.w;
            accB[8]  += hv*u2.x; accB[9]  += hv*u2.y; accB[10] += hv*u2.z; accB[11] += hv*u2.w;
            accB[12] += hv*u3.x; accB[13] += hv*u3.y; accB[14] += hv*u3.z; accB[15] += hv*u3.w;
            accB[16] += hv*u4.x; accB[17] += hv*u4.y; accB[18] += hv*u4.z; accB[19] += hv*u4.w;
            accB[20] += hv*u5.x; accB[21] += hv*u5.y; accB[22] += hv*u5.z; accB[23] += hv*u5.w;
            accB[24] += hv*u6.x; accB[25] += hv*u6.y; accB[26] += hv*u6.z; accB[27] += hv*u6.w;
            accB[28] += hv*u7.x; accB[29] += hv*u7.y; accB[30] += hv*u7.z; accB[31] += hv*u7.w;
        }
        __syncthreads();
    }
    float* dst = out + ((long)((b*128 + h)*128) + tokB)*64 + o0;
    #pragma unroll
    for (int k = 0; k < 8; k++) {
        float4 o4;
        o4.x = accB[4*k]     + mb2[o0 + 4*k];
        o4.y = accB[4*k + 1] + mb2[o0 + 4*k + 1];
        o4.z = accB[4*k + 2] + mb2[o0 + 4*k + 2];
        o4.w = accB[4*k + 3] + mb2[o0 + 4*k + 3];
        ((float4*)dst)[k] = o4;
    }
}

extern "C" void kernel_launch(void* const* d_in, const int* in_sizes, int n_in,
                              void* d_out, int out_size, void* d_ws, size_t ws_size,
                              hipStream_t stream) {
    const float* x   = (const float*)d_in[0];
    const float* w1r = (const float*)d_in[1];
    const float* w1i = (const float*)d_in[2];
    const float* w2r = (const float*)d_in[3];
    const float* w2i = (const float*)d_in[4];
    const float* mw1 = (const float*)d_in[5];
    const float* mb1 = (const float*)d_in[6];
    const float* mw2 = (const float*)d_in[7];
    const float* mb2 = (const float*)d_in[8];
    float* ws  = (float*)d_ws;
    float* out = (float*)d_out;

    k_init  <<<dim3(1),      dim3(256), 0, stream>>>(ws);
    k_stats1<<<dim3(16,16),  dim3(256), 0, stream>>>(x, ws);
    k_trans <<<dim3(64),     dim3(256), 0, stream>>>(w1r, w1i, w2r, w2i, ws);
    k_dftw  <<<dim3(16,16),  dim3(256), 0, stream>>>(x, ws);
    k_dfth  <<<dim3(16,16),  dim3(256), 0, stream>>>(ws);
    k_mix   <<<dim3(512),    dim3(256), 0, stream>>>(ws);
    k_wmlp  <<<dim3(64),     dim3(256), 0, stream>>>(mw1, mw2, ws);  // X dead after k_mix
    k_idfth <<<dim3(16,16),  dim3(256), 0, stream>>>(ws);
    k_stats2<<<dim3(16,16),  dim3(256), 0, stream>>>(ws);
    k_mlp   <<<dim3(128,16), dim3(256), 0, stream>>>(mb1, mb2, out, ws);
}

// Round 4
// 394.590 us; speedup vs baseline: 2.1558x; 2.1295x over previous
//
#include <hip/hip_runtime.h>
#include <math.h>

// Problem constants: B=16, H=W=128, C=64, M1=M2=16
// Workspace layout (float offsets):
#define OFF_TBL 0u            // 128 x {cos,sin}(2*pi*m/128)          (256)
#define OFF_S1  256u          // instance-norm-1 raw sums [b*64+c][2] (2048)
#define OFF_S2  2304u         // instance-norm-2 stats (s1,s2)        (2048)
#define OFF_PQ  4352u         // P[b][h][ky][c][2] aliased with Q[b][h][ky][o][2] (4194304)
#define OFF_X   4198656u      // X[b][kx][ky][c][2]                   (1048576)
#define OFF_O   5247232u      // Out[b][kx][ky][o][2]                 (1048576)
#define OFF_WT  6295808u      // WT[mode][i][o][2]                    (4194304)
// total = 10490112 floats = 41.96 MB
// X region is dead after k_mix -> reuse as u16 arrays for bf16-split weights:
//   u16[0..8192)      w1hi[j*64+c]     u16[8192..16384)  w1lo
//   u16[16384..24576) w2hi[o*128+j]    u16[24576..32768) w2lo
//   u16[32768..36864) Mhi[w*32+k]      u16[36864..40960) Mlo

typedef __attribute__((ext_vector_type(8))) short bfrag;
typedef __attribute__((ext_vector_type(4))) float f4v;
#define MFMA(A,B,C) __builtin_amdgcn_mfma_f32_16x16x32_bf16(A,B,C,0,0,0)

__device__ __forceinline__ unsigned short f2bf_rn(float x) {
    unsigned u = __float_as_uint(x);
    unsigned r = u + 0x7FFFu + ((u >> 16) & 1u);
    return (unsigned short)(r >> 16);
}
__device__ __forceinline__ float bf2f(unsigned short h) {
    return __uint_as_float(((unsigned)h) << 16);
}
__device__ __forceinline__ void split2(float x, unsigned short& hi, unsigned short& lo) {
    hi = f2bf_rn(x);
    lo = f2bf_rn(x - bf2f(hi));
}

__global__ void k_init(float* __restrict__ ws) {
    int t = threadIdx.x;
    if (t < 128) {
        double ang = 6.283185307179586476925286766559 * (double)t / 128.0;
        ws[OFF_TBL + 2*t]     = (float)cos(ang);
        ws[OFF_TBL + 2*t + 1] = (float)sin(ang);
    }
    for (int i = t; i < 4096; i += 256) ws[OFF_S1 + i] = 0.f;
}

// per-(b,c) sum & sumsq of x, atomically accumulated. grid (hg=16, b=16), 256 thr
__global__ void k_stats1(const float* __restrict__ x, float* __restrict__ ws) {
    __shared__ float red[16][16][8];
    int t = threadIdx.x;
    int hg = blockIdx.x, b = blockIdx.y;
    const float4* x4 = (const float4*)x;
    int q = t & 15, pslot = t >> 4;
    float4 sum = {0,0,0,0}, sq = {0,0,0,0};
    long base = ((long)(b*128 + hg*8)*128) * 16;   // float4 index
    for (int p = pslot; p < 1024; p += 16) {
        float4 v = x4[base + (long)p*16 + q];
        sum.x += v.x; sum.y += v.y; sum.z += v.z; sum.w += v.w;
        sq.x += v.x*v.x; sq.y += v.y*v.y; sq.z += v.z*v.z; sq.w += v.w*v.w;
    }
    red[pslot][q][0]=sum.x; red[pslot][q][1]=sum.y; red[pslot][q][2]=sum.z; red[pslot][q][3]=sum.w;
    red[pslot][q][4]=sq.x;  red[pslot][q][5]=sq.y;  red[pslot][q][6]=sq.z;  red[pslot][q][7]=sq.w;
    __syncthreads();
    if (t < 64) {
        int qq = t >> 2, ci = t & 3;
        float a = 0.f, s = 0.f;
        for (int p = 0; p < 16; p++) { a += red[p][qq][ci]; s += red[p][qq][4+ci]; }
        atomicAdd(&ws[OFF_S1 + (b*64 + t)*2],     a);
        atomicAdd(&ws[OFF_S1 + (b*64 + t)*2 + 1], s);
    }
}

// weight transpose: [i][o][kx][ky] (x4 arrays) -> WT[mode][i][o][{re,im}]. grid 64 (=i)
__global__ void k_trans(const float* __restrict__ w1r, const float* __restrict__ w1i,
                        const float* __restrict__ w2r, const float* __restrict__ w2i,
                        float* __restrict__ ws) {
    __shared__ float Lr[16*257], Li[16*257];
    int t = threadIdx.x;
    int i = blockIdx.x;
    float* WT = ws + OFF_WT;
    for (int part = 0; part < 2; part++) {
        const float* wr = part ? w2r : w1r;
        const float* wi = part ? w2i : w1i;
        for (int oc = 0; oc < 4; oc++) {
            int o0 = oc * 16;
            __syncthreads();
            for (int idx = t; idx < 4096; idx += 256) {
                int oo = idx >> 8, m = idx & 255;
                Lr[oo*257 + m] = wr[(i*64 + o0 + oo)*256 + m];
                Li[oo*257 + m] = wi[(i*64 + o0 + oo)*256 + m];
            }
            __syncthreads();
            for (int idx = t; idx < 8192; idx += 256) {
                int mode = idx >> 5, rem = idx & 31, oo = rem >> 1, ri = rem & 1;
                float val = ri ? Li[oo*257 + mode] : Lr[oo*257 + mode];
                int gm = part*256 + mode;
                WT[((gm*64 + i)*64 + (o0 + oo))*2 + ri] = val;
            }
        }
    }
}

// bf16-split MLP weights + iDFT-w matrix M into the dead X region. grid 80
__global__ void k_wmlp(const float* __restrict__ mw1, const float* __restrict__ mw2,
                       float* __restrict__ ws) {
    int i = blockIdx.x * 256 + threadIdx.x;   // [0, 20480)
    unsigned short* xu = (unsigned short*)(ws + OFF_X);
    if (i < 8192) {
        unsigned short hi, lo; split2(mw1[i], hi, lo);
        xu[i] = hi; xu[8192 + i] = lo;
    } else if (i < 16384) {
        int k = i - 8192;
        unsigned short hi, lo; split2(mw2[k], hi, lo);
        xu[16384 + k] = hi; xu[24576 + k] = lo;
    } else if (i < 20480) {
        int m = i - 16384;           // w*32 + k
        int w = m >> 5, k = m & 31;
        int ky = k >> 1;
        double ang = 6.283185307179586476925286766559 * (double)((ky * w) & 127) / 128.0;
        double v = (k & 1) ? -sin(ang) : cos(ang);
        double a = (ky == 0) ? 1.0 : 2.0;
        float val = (float)(v * a) * (1.f/16384.f);
        unsigned short hi, lo; split2(val, hi, lo);
        xu[32768 + m] = hi; xu[36864 + m] = lo;
    }
}

// forward DFT along w (16 ky) with fused instance-norm-1. grid (hg=16,b=16)
__global__ void k_dftw(const float* __restrict__ x, float* __restrict__ ws) {
    __shared__ float xs[128*65];
    __shared__ float tblL[256];
    __shared__ float mu[64], rho[64];
    int t = threadIdx.x;
    int hg = blockIdx.x, b = blockIdx.y;
    for (int i = t; i < 256; i += 256) tblL[i] = ws[OFF_TBL + i];
    if (t < 64) {
        float s1 = ws[OFF_S1 + (b*64+t)*2], s2 = ws[OFF_S1 + (b*64+t)*2 + 1];
        float m = s1 * (1.f/16384.f);
        float v = s2 * (1.f/16384.f) - m*m;
        mu[t] = m; rho[t] = rsqrtf(v + 1e-5f);
    }
    __syncthreads();
    float* P = ws + OFF_PQ;
    int c = t & 63, kyg = t >> 6;
    for (int h = 0; h < 8; h++) {
        int habs = hg*8 + h;
        const float4* row = (const float4*)(x + ((long)(b*128 + habs)*128)*64);
        for (int idx = t; idx < 2048; idx += 256) {
            int w = idx >> 4, qq = idx & 15;
            float4 v = row[idx];
            int c0 = qq*4;
            xs[w*65 + c0]     = (v.x - mu[c0])   * rho[c0];
            xs[w*65 + c0 + 1] = (v.y - mu[c0+1]) * rho[c0+1];
            xs[w*65 + c0 + 2] = (v.z - mu[c0+2]) * rho[c0+2];
            xs[w*65 + c0 + 3] = (v.w - mu[c0+3]) * rho[c0+3];
        }
        __syncthreads();
        float accr[4] = {0,0,0,0}, acci[4] = {0,0,0,0};
        for (int w = 0; w < 128; w++) {
            float v = xs[w*65 + c];
            #pragma unroll
            for (int kk = 0; kk < 4; kk++) {
                int ky = kyg*4 + kk;
                int m = (ky * w) & 127;
                accr[kk] += v * tblL[2*m];      // e^{-i th}: re += v*cos
                acci[kk] -= v * tblL[2*m + 1];  //           im -= v*sin
            }
        }
        #pragma unroll
        for (int kk = 0; kk < 4; kk++) {
            int ky = kyg*4 + kk;
            float2* dst = (float2*)(P + (((b*128 + habs)*16 + ky)*128));
            dst[c] = make_float2(accr[kk], acci[kk]);
        }
        __syncthreads();
    }
}

// forward DFT along h (32 kx rows: 0..15 and 112..127). grid (ky=16, b=16)
__global__ void k_dfth(float* __restrict__ ws) {
    __shared__ float Ps[2048];
    __shared__ float tblL[256];
    int t = threadIdx.x;
    int ky = blockIdx.x, b = blockIdx.y;
    for (int i = t; i < 256; i += 256) tblL[i] = ws[OFF_TBL + i];
    const float* P = ws + OFF_PQ;
    float* X = ws + OFF_X;
    int c = t & 63, kxg = t >> 6;
    float accr[8] = {0,0,0,0,0,0,0,0}, acci[8] = {0,0,0,0,0,0,0,0};
    for (int hc = 0; hc < 8; hc++) {
        __syncthreads();
        for (int idx = t; idx < 2048; idx += 256) {
            int hh = idx >> 7, r = idx & 127;
            Ps[idx] = P[((long)((b*128 + hc*16 + hh)*16 + ky))*128 + r];
        }
        __syncthreads();
        for (int hh = 0; hh < 16; hh++) {
            int habs = hc*16 + hh;
            float vr = Ps[hh*128 + c*2], vi = Ps[hh*128 + c*2 + 1];
            #pragma unroll
            for (int kk = 0; kk < 8; kk++) {
                int kxI = kxg*8 + kk;
                int freq = kxI < 16 ? kxI : 96 + kxI;   // 112..127
                int m = (freq * habs) & 127;
                float cs = tblL[2*m], sn = tblL[2*m + 1];
                accr[kk] += vr*cs + vi*sn;              // * e^{-i th}
                acci[kk] += vi*cs - vr*sn;
            }
        }
    }
    #pragma unroll
    for (int kk = 0; kk < 8; kk++) {
        int kxI = kxg*8 + kk;
        float2* dst = (float2*)(X + (((b*32 + kxI)*16 + ky)*128));
        dst[c] = make_float2(accr[kk], acci[kk]);
    }
}

// per-mode complex mix: Out[b][o] = sum_i X[b][i] * W[i][o]. grid 512 (=mode)
__global__ void k_mix(float* __restrict__ ws) {
    __shared__ float Wsh[8192];
    __shared__ float Xs[2048];
    int t = threadIdx.x;
    int mode = blockIdx.x;
    int kxI = mode >> 4, ky = mode & 15;
    const float* WT = ws + OFF_WT;
    const float* X = ws + OFF_X;
    float* O = ws + OFF_O;
    for (int idx = t; idx < 8192; idx += 256) Wsh[idx] = WT[(long)mode*8192 + idx];
    for (int idx = t; idx < 2048; idx += 256) {
        int b = idx >> 7, r = idx & 127;
        Xs[idx] = X[((b*32 + kxI)*16 + ky)*128 + r];
    }
    __syncthreads();
    int o = t & 63, bg = t >> 6;
    float accr[4] = {0,0,0,0}, acci[4] = {0,0,0,0};
    for (int i = 0; i < 64; i++) {
        float wr = Wsh[(i*64 + o)*2], wi = Wsh[(i*64 + o)*2 + 1];
        #pragma unroll
        for (int j = 0; j < 4; j++) {
            float xr = Xs[(bg*4 + j)*128 + 2*i], xi = Xs[(bg*4 + j)*128 + 2*i + 1];
            accr[j] += xr*wr - xi*wi;
            acci[j] += xr*wi + xi*wr;
        }
    }
    #pragma unroll
    for (int j = 0; j < 4; j++) {
        int b = bg*4 + j;
        float2* dst = (float2*)(O + ((b*32 + kxI)*16 + ky)*128);
        dst[o] = make_float2(accr[j], acci[j]);
    }
}

// Parseval stats of y directly from O. grid 16 (=b), 256 thr.
// Sum_{h,w} y^2 = [(1/2)T0 + (1/2)T1 + 2*T2] / 16384 ; store s2 = Sum y^2
// (legacy k_stats2 semantics: k_mlp computes var = s2/16384 - mu^2).
__global__ void k_pstats(float* __restrict__ ws) {
    __shared__ float red[256][2];
    int t = threadIdx.x, b = blockIdx.x;
    int c = t & 63, g = t >> 6;
    const float* O = ws + OFF_O + (long)b*65536;   // [(kxI*16+ky)*128 + 2c]
    float t0 = 0.f, t2 = 0.f;
    for (int kxI = g*8; kxI < g*8 + 8; kxI++)
        for (int ky = 0; ky < 16; ky++) {
            float re = O[(kxI*16 + ky)*128 + 2*c];
            float im = O[(kxI*16 + ky)*128 + 2*c + 1];
            float p = re*re + im*im;
            if (ky == 0) t0 += p; else t2 += p;
        }
    float s2p = 0.5f*t0 + 2.f*t2;
    float s1 = 0.f;
    if (g == 0) {
        float ar = O[2*c], ai = O[2*c + 1];        // kxI=0, ky=0
        s1 = ar;
        float t1 = ar*ar - ai*ai;
        for (int k = 1; k <= 15; k++) {
            float xr = O[(k*16)*128 + 2*c],        xi = O[(k*16)*128 + 2*c + 1];
            float yr = O[((32-k)*16)*128 + 2*c],   yi = O[((32-k)*16)*128 + 2*c + 1];
            t1 += 2.f*(xr*yr - xi*yi);
        }
        s2p += 0.5f*t1;
    }
    red[t][0] = s2p; red[t][1] = s1;
    __syncthreads();
    if (t < 64) {
        float s2 = red[t][0] + red[t+64][0] + red[t+128][0] + red[t+192][0];
        ws[OFF_S2 + (b*64 + t)*2]     = red[t][1];
        ws[OFF_S2 + (b*64 + t)*2 + 1] = s2 * (1.f/16384.f);   // = Sum y^2 (fix: was 16384x too large)
    }
}

// inverse DFT along h: Q[b][h][ky][o] = sum_kx Out e^{+i 2pi f(kx) h/128}. grid (hg=16,b=16)
__global__ void k_idfth(float* __restrict__ ws) {
    __shared__ float Os[8192];
    __shared__ float tblL[256];
    int t = threadIdx.x;
    int hg = blockIdx.x, b = blockIdx.y;
    for (int i = t; i < 256; i += 256) tblL[i] = ws[OFF_TBL + i];
    const float* O = ws + OFF_O;
    float* Q = ws + OFF_PQ;
    int o = t & 63, kyg = t >> 6;
    float accr[4][8], acci[4][8];
    #pragma unroll
    for (int kk = 0; kk < 4; kk++)
        #pragma unroll
        for (int h = 0; h < 8; h++) { accr[kk][h] = 0.f; acci[kk][h] = 0.f; }
    for (int kc = 0; kc < 8; kc++) {
        __syncthreads();
        for (int idx = t; idx < 8192; idx += 256) Os[idx] = O[(long)b*65536 + kc*8192 + idx];
        __syncthreads();
        for (int k4 = 0; k4 < 4; k4++) {
            int kxI = kc*4 + k4;
            int freq = kxI < 16 ? kxI : 96 + kxI;
            float vr[4], vi[4];
            #pragma unroll
            for (int kk = 0; kk < 4; kk++) {
                int ky = kyg*4 + kk;
                vr[kk] = Os[((k4*16 + ky)*64 + o)*2];
                vi[kk] = Os[((k4*16 + ky)*64 + o)*2 + 1];
            }
            for (int h = 0; h < 8; h++) {
                int habs = hg*8 + h;
                int m = (freq * habs) & 127;
                float cs = tblL[2*m], sn = tblL[2*m + 1];
                #pragma unroll
                for (int kk = 0; kk < 4; kk++) {
                    accr[kk][h] += vr[kk]*cs - vi[kk]*sn;   // * e^{+i th}
                    acci[kk][h] += vr[kk]*sn + vi[kk]*cs;
                }
            }
        }
    }
    #pragma unroll
    for (int kk = 0; kk < 4; kk++)
        #pragma unroll
        for (int h = 0; h < 8; h++) {
            int ky = kyg*4 + kk, habs = hg*8 + h;
            float2* dst = (float2*)(Q + ((long)(b*128 + habs)*16 + ky)*128);
            dst[o] = make_float2(accr[kk][h], acci[kk][h]);
        }
}

// fused MFMA kernel: Y = M@Qm (iDFT-w), z = (Y-mu)*rho, h = GELU(z@W1+b1),
// out = h@W2+b2. bf16-split (hi/lo, 3 MFMA) for ~fp32 precision. grid (h=128,b=16)
__global__ __launch_bounds__(256) void k_mlp(const float* __restrict__ mb1,
                      const float* __restrict__ mb2,
                      float* __restrict__ out, const float* __restrict__ ws) {
    __shared__ unsigned short zhS[8192], zlS[8192];     // z[w][64c] bf16 hi/lo, XOR-swz
    __shared__ unsigned short w1hS[8192], w1lS[8192];   // w1[j][64c]
    __shared__ unsigned short w2hS[8192], w2lS[8192];   // w2[o][128j]
    __shared__ unsigned short hhS[8192], hlS[8192];     // h-half [w][64jl]; head doubles as QmT[c][40k]
    __shared__ float muL[64], rhoL[64], b1L[128], b2L[64];
    int t = threadIdx.x;
    int h = blockIdx.x, b = blockIdx.y;
    int l = t & 63, wv = t >> 6;

    const unsigned short* xu = (const unsigned short*)(ws + OFF_X);
    const unsigned short* w1hG = xu,         *w1lG = xu + 8192;
    const unsigned short* w2hG = xu + 16384, *w2lG = xu + 24576;
    const unsigned short* MhG  = xu + 32768, *MlG  = xu + 36864;

    // ---- stage weights into LDS (XOR swizzle) ----
    for (int ch = t; ch < 1024; ch += 256) {       // w1: rows j, stride 128B, swz (j&7)<<4
        int j = ch >> 3, c0 = (ch & 7) * 8;
        unsigned off = (unsigned)(j*128 + c0*2) ^ (unsigned)((j & 7) << 4);
        *(bfrag*)((char*)w1hS + off) = *(const bfrag*)(w1hG + ch*8);
        *(bfrag*)((char*)w1lS + off) = *(const bfrag*)(w1lG + ch*8);
    }
    for (int ch = t; ch < 1024; ch += 256) {       // w2: rows o, stride 256B, swz (o&15)<<4
        int o = ch >> 4, j0 = (ch & 15) * 8;
        unsigned off = (unsigned)(o*256 + j0*2) ^ (unsigned)((o & 15) << 4);
        *(bfrag*)((char*)w2hS + off) = *(const bfrag*)(w2hG + ch*8);
        *(bfrag*)((char*)w2lS + off) = *(const bfrag*)(w2lG + ch*8);
    }
    // ---- QmT[c][k] build (k=2ky -> Qr, 2ky+1 -> Qi), stride 40 u16 ----
    const float* Qp = ws + OFF_PQ + (long)(b*128 + h)*2048;
    for (int i = t; i < 2048; i += 256) {
        int c = i & 63, k = i >> 6;
        float v = Qp[(k >> 1)*128 + c*2 + (k & 1)];
        unsigned short hi, lo; split2(v, hi, lo);
        hhS[c*40 + k] = hi; hlS[c*40 + k] = lo;
    }
    if (t < 64) {
        float s1 = ws[OFF_S2 + (b*64+t)*2], s2 = ws[OFF_S2 + (b*64+t)*2 + 1];
        float m = s1 * (1.f/16384.f);
        float v = s2 * (1.f/16384.f) - m*m;
        muL[t] = m; rhoL[t] = rsqrtf(v + 1e-5f);
        b2L[t] = mb2[t];
    }
    if (t >= 64 && t < 192) b1L[t - 64] = mb1[t - 64];
    // M A-frags from global (rows w of this wave's two 16-row tiles)
    bfrag ma_h[2], ma_l[2];
    #pragma unroll
    for (int q = 0; q < 2; q++) {
        int w = (wv + 4*q)*16 + (l & 15);
        ma_h[q] = *(const bfrag*)(MhG + w*32 + (l >> 4)*8);
        ma_l[q] = *(const bfrag*)(MlG + w*32 + (l >> 4)*8);
    }
    __syncthreads();

    // ---- G1: Y = M @ Qm ; z = (Y - mu) * rho -> zhS/zlS ----
    #pragma unroll
    for (int q = 0; q < 2; q++) {
        int wt = wv + 4*q;
        #pragma unroll
        for (int ct = 0; ct < 4; ct++) {
            unsigned ro = (unsigned)((ct*16 + (l & 15))*80 + (l >> 4)*16);
            bfrag bh = *(const bfrag*)((const char*)hhS + ro);
            bfrag bl = *(const bfrag*)((const char*)hlS + ro);
            f4v acc = {0.f, 0.f, 0.f, 0.f};
            acc = MFMA(ma_h[q], bh, acc);
            acc = MFMA(ma_h[q], bl, acc);
            acc = MFMA(ma_l[q], bh, acc);
            int c = ct*16 + (l & 15);
            float mu_ = muL[c], rh_ = rhoL[c];
            #pragma unroll
            for (int r = 0; r < 4; r++) {
                int w = wt*16 + (l >> 4)*4 + r;
                float z = (acc[r] - mu_) * rh_;
                unsigned short hi, lo; split2(z, hi, lo);
                unsigned off = (unsigned)(w*128 + c*2) ^ (unsigned)((w & 7) << 4);
                *(unsigned short*)((char*)zhS + off) = hi;
                *(unsigned short*)((char*)zlS + off) = lo;
            }
        }
    }
    __syncthreads();   // z ready; QmT region (hhS/hlS) now free

    // cache z A-frags (reused for both j-halves)
    bfrag za_h[2][2], za_l[2][2];
    #pragma unroll
    for (int q = 0; q < 2; q++) {
        int w = (wv + 4*q)*16 + (l & 15);
        #pragma unroll
        for (int ks = 0; ks < 2; ks++) {
            unsigned off = (unsigned)(w*128 + (ks*32 + (l >> 4)*8)*2) ^ (unsigned)((w & 7) << 4);
            za_h[q][ks] = *(const bfrag*)((const char*)zhS + off);
            za_l[q][ks] = *(const bfrag*)((const char*)zlS + off);
        }
    }
    f4v accO[2][4];
    #pragma unroll
    for (int q = 0; q < 2; q++)
        #pragma unroll
        for (int ot = 0; ot < 4; ot++) accO[q][ot] = (f4v){0.f,0.f,0.f,0.f};

    #pragma unroll
    for (int jh = 0; jh < 2; jh++) {
        // ---- G2: h-half = GELU(z @ W1[:, jh*64 .. +64) + b1) ----
        #pragma unroll
        for (int q = 0; q < 2; q++) {
            int wt = wv + 4*q;
            #pragma unroll
            for (int jt = 0; jt < 4; jt++) {
                int j = jh*64 + jt*16 + (l & 15);
                f4v acc = {0.f, 0.f, 0.f, 0.f};
                #pragma unroll
                for (int ks = 0; ks < 2; ks++) {
                    unsigned off = (unsigned)(j*128 + (ks*32 + (l >> 4)*8)*2) ^ (unsigned)((j & 7) << 4);
                    bfrag bh = *(const bfrag*)((const char*)w1hS + off);
                    bfrag bl = *(const bfrag*)((const char*)w1lS + off);
                    acc = MFMA(za_h[q][ks], bh, acc);
                    acc = MFMA(za_h[q][ks], bl, acc);
                    acc = MFMA(za_l[q][ks], bh, acc);
                }
                float bj = b1L[j];
                #pragma unroll
                for (int r = 0; r < 4; r++) {
                    int w = wt*16 + (l >> 4)*4 + r;
                    float hv = acc[r] + bj;
                    hv = 0.5f * hv * (1.f + erff(hv * 0.70710678118654752f));
                    unsigned short hi, lo; split2(hv, hi, lo);
                    int jl = jt*16 + (l & 15);
                    unsigned off = (unsigned)(w*128 + jl*2) ^ (unsigned)((w & 7) << 4);
                    *(unsigned short*)((char*)hhS + off) = hi;
                    *(unsigned short*)((char*)hlS + off) = lo;
                }
            }
        }
        __syncthreads();
        // ---- G3 partial: out += h-half @ W2[jh*64.., :] ----
        #pragma unroll
        for (int q = 0; q < 2; q++) {
            int w = (wv + 4*q)*16 + (l & 15);
            bfrag ha_h[2], ha_l[2];
            #pragma unroll
            for (int ks = 0; ks < 2; ks++) {
                unsigned off = (unsigned)(w*128 + (ks*32 + (l >> 4)*8)*2) ^ (unsigned)((w & 7) << 4);
                ha_h[ks] = *(const bfrag*)((const char*)hhS + off);
                ha_l[ks] = *(const bfrag*)((const char*)hlS + off);
            }
            #pragma unroll
            for (int ot = 0; ot < 4; ot++) {
                int o = ot*16 + (l & 15);
                f4v acc = accO[q][ot];
                #pragma unroll
                for (int ks = 0; ks < 2; ks++) {
                    int jj = jh*64 + ks*32 + (l >> 4)*8;
                    unsigned off = (unsigned)(o*256 + jj*2) ^ (unsigned)((o & 15) << 4);
                    bfrag bh = *(const bfrag*)((const char*)w2hS + off);
                    bfrag bl = *(const bfrag*)((const char*)w2lS + off);
                    acc = MFMA(ha_h[ks], bh, acc);
                    acc = MFMA(ha_h[ks], bl, acc);
                    acc = MFMA(ha_l[ks], bh, acc);
                }
                accO[q][ot] = acc;
            }
        }
        __syncthreads();   // protect h buffer before next half overwrites
    }
    // ---- store out + b2 ----
    #pragma unroll
    for (int q = 0; q < 2; q++) {
        int wt = wv + 4*q;
        #pragma unroll
        for (int ot = 0; ot < 4; ot++) {
            int o = ot*16 + (l & 15);
            float bo = b2L[o];
            #pragma unroll
            for (int r = 0; r < 4; r++) {
                int w = wt*16 + (l >> 4)*4 + r;
                out[((long)(b*128 + h)*128 + w)*64 + o] = accO[q][ot][r] + bo;
            }
        }
    }
}

extern "C" void kernel_launch(void* const* d_in, const int* in_sizes, int n_in,
                              void* d_out, int out_size, void* d_ws, size_t ws_size,
                              hipStream_t stream) {
    const float* x   = (const float*)d_in[0];
    const float* w1r = (const float*)d_in[1];
    const float* w1i = (const float*)d_in[2];
    const float* w2r = (const float*)d_in[3];
    const float* w2i = (const float*)d_in[4];
    const float* mw1 = (const float*)d_in[5];
    const float* mb1 = (const float*)d_in[6];
    const float* mw2 = (const float*)d_in[7];
    const float* mb2 = (const float*)d_in[8];
    float* ws  = (float*)d_ws;
    float* out = (float*)d_out;

    k_init  <<<dim3(1),      dim3(256), 0, stream>>>(ws);
    k_stats1<<<dim3(16,16),  dim3(256), 0, stream>>>(x, ws);
    k_trans <<<dim3(64),     dim3(256), 0, stream>>>(w1r, w1i, w2r, w2i, ws);
    k_dftw  <<<dim3(16,16),  dim3(256), 0, stream>>>(x, ws);
    k_dfth  <<<dim3(16,16),  dim3(256), 0, stream>>>(ws);
    k_mix   <<<dim3(512),    dim3(256), 0, stream>>>(ws);
    k_wmlp  <<<dim3(80),     dim3(256), 0, stream>>>(mw1, mw2, ws);  // X dead after k_mix
    k_pstats<<<dim3(16),     dim3(256), 0, stream>>>(ws);
    k_idfth <<<dim3(16,16),  dim3(256), 0, stream>>>(ws);
    k_mlp   <<<dim3(128,16), dim3(256), 0, stream>>>(mb1, mb2, out, ws);
}

// Round 5
// 300.069 us; speedup vs baseline: 2.8348x; 1.3150x over previous
//
#include <hip/hip_runtime.h>
#include <math.h>

// Problem constants: B=16, H=W=128, C=64, M1=M2=16
// Workspace layout (float offsets):
#define OFF_TBL 0u            // 128 x {cos,sin}(2*pi*m/128)          (256)
#define OFF_S1  256u          // instance-norm-1 raw sums [b*64+c][2] (2048)
#define OFF_S2  2304u         // instance-norm-2 stats (s1,s2)        (2048)
#define OFF_PQ  4352u         // P[b][h][ky][c][2] aliased with Q[b][h][ky][o][2] (4194304)
#define OFF_X   4198656u      // X[b][kx][ky][c][2]                   (1048576)
#define OFF_O   5247232u      // Out[b][kx][ky][o][2]                 (1048576)
#define OFF_WT  6295808u      // WT[mode][i][o][2]                    (4194304)
// total = 10490112 floats = 41.96 MB
// X region is dead after k_mix -> reuse as u16 arrays for bf16-split weights:
//   u16[0..8192)      w1hi[j*64+c]     u16[8192..16384)  w1lo (unused by k_mlp now)
//   u16[16384..24576) w2hi[o*128+j]    u16[24576..32768) w2lo (unused)
//   u16[32768..36864) Mhi[w*32+k]      u16[36864..40960) Mlo

typedef __attribute__((ext_vector_type(8))) short bfrag;
typedef __attribute__((ext_vector_type(4))) float f4v;
#define MFMA(A,B,C) __builtin_amdgcn_mfma_f32_16x16x32_bf16(A,B,C,0,0,0)

__device__ __forceinline__ unsigned short f2bf_rn(float x) {
    unsigned u = __float_as_uint(x);
    unsigned r = u + 0x7FFFu + ((u >> 16) & 1u);
    return (unsigned short)(r >> 16);
}
__device__ __forceinline__ float bf2f(unsigned short h) {
    return __uint_as_float(((unsigned)h) << 16);
}
__device__ __forceinline__ void split2(float x, unsigned short& hi, unsigned short& lo) {
    hi = f2bf_rn(x);
    lo = f2bf_rn(x - bf2f(hi));
}
// tanh-form GELU; matches exact GELU to <1e-5 for |x| <= 0.5 (our range)
__device__ __forceinline__ float gelu_t(float x) {
    float u = 0.79788456080286536f * (x + 0.044715f * x * x * x);
    float e = __expf(2.f * u);
    float th = 1.f - 2.f / (e + 1.f);
    return 0.5f * x * (1.f + th);
}

__global__ void k_init(float* __restrict__ ws) {
    int t = threadIdx.x;
    if (t < 128) {
        double ang = 6.283185307179586476925286766559 * (double)t / 128.0;
        ws[OFF_TBL + 2*t]     = (float)cos(ang);
        ws[OFF_TBL + 2*t + 1] = (float)sin(ang);
    }
    for (int i = t; i < 4096; i += 256) ws[OFF_S1 + i] = 0.f;
}

// per-(b,c) sum & sumsq of x, atomically accumulated. grid (hg=16, b=16), 256 thr
__global__ void k_stats1(const float* __restrict__ x, float* __restrict__ ws) {
    __shared__ float red[16][16][8];
    int t = threadIdx.x;
    int hg = blockIdx.x, b = blockIdx.y;
    const float4* x4 = (const float4*)x;
    int q = t & 15, pslot = t >> 4;
    float4 sum = {0,0,0,0}, sq = {0,0,0,0};
    long base = ((long)(b*128 + hg*8)*128) * 16;   // float4 index
    for (int p = pslot; p < 1024; p += 16) {
        float4 v = x4[base + (long)p*16 + q];
        sum.x += v.x; sum.y += v.y; sum.z += v.z; sum.w += v.w;
        sq.x += v.x*v.x; sq.y += v.y*v.y; sq.z += v.z*v.z; sq.w += v.w*v.w;
    }
    red[pslot][q][0]=sum.x; red[pslot][q][1]=sum.y; red[pslot][q][2]=sum.z; red[pslot][q][3]=sum.w;
    red[pslot][q][4]=sq.x;  red[pslot][q][5]=sq.y;  red[pslot][q][6]=sq.z;  red[pslot][q][7]=sq.w;
    __syncthreads();
    if (t < 64) {
        int qq = t >> 2, ci = t & 3;
        float a = 0.f, s = 0.f;
        for (int p = 0; p < 16; p++) { a += red[p][qq][ci]; s += red[p][qq][4+ci]; }
        atomicAdd(&ws[OFF_S1 + (b*64 + t)*2],     a);
        atomicAdd(&ws[OFF_S1 + (b*64 + t)*2 + 1], s);
    }
}

// weight transpose: [i][o][kx][ky] (x4 arrays) -> WT[mode][i][o][{re,im}]. grid (64=i, 2=part)
__global__ void k_trans(const float* __restrict__ w1r, const float* __restrict__ w1i,
                        const float* __restrict__ w2r, const float* __restrict__ w2i,
                        float* __restrict__ ws) {
    __shared__ float Lr[16*257], Li[16*257];
    int t = threadIdx.x;
    int i = blockIdx.x;
    int part = blockIdx.y;
    float* WT = ws + OFF_WT;
    const float* wr = part ? w2r : w1r;
    const float* wi = part ? w2i : w1i;
    for (int oc = 0; oc < 4; oc++) {
        int o0 = oc * 16;
        __syncthreads();
        for (int idx = t; idx < 4096; idx += 256) {
            int oo = idx >> 8, m = idx & 255;
            Lr[oo*257 + m] = wr[(i*64 + o0 + oo)*256 + m];
            Li[oo*257 + m] = wi[(i*64 + o0 + oo)*256 + m];
        }
        __syncthreads();
        for (int idx = t; idx < 8192; idx += 256) {
            int mode = idx >> 5, rem = idx & 31, oo = rem >> 1, ri = rem & 1;
            float val = ri ? Li[oo*257 + mode] : Lr[oo*257 + mode];
            int gm = part*256 + mode;
            WT[((gm*64 + i)*64 + (o0 + oo))*2 + ri] = val;
        }
    }
}

// bf16-split MLP weights + iDFT-w matrix M into the dead X region. grid 80
__global__ void k_wmlp(const float* __restrict__ mw1, const float* __restrict__ mw2,
                       float* __restrict__ ws) {
    int i = blockIdx.x * 256 + threadIdx.x;   // [0, 20480)
    unsigned short* xu = (unsigned short*)(ws + OFF_X);
    if (i < 8192) {
        unsigned short hi, lo; split2(mw1[i], hi, lo);
        xu[i] = hi; xu[8192 + i] = lo;
    } else if (i < 16384) {
        int k = i - 8192;
        unsigned short hi, lo; split2(mw2[k], hi, lo);
        xu[16384 + k] = hi; xu[24576 + k] = lo;
    } else if (i < 20480) {
        int m = i - 16384;           // w*32 + k
        int w = m >> 5, k = m & 31;
        int ky = k >> 1;
        double ang = 6.283185307179586476925286766559 * (double)((ky * w) & 127) / 128.0;
        double v = (k & 1) ? -sin(ang) : cos(ang);
        double a = (ky == 0) ? 1.0 : 2.0;
        float val = (float)(v * a) * (1.f/16384.f);
        unsigned short hi, lo; split2(val, hi, lo);
        xu[32768 + m] = hi; xu[36864 + m] = lo;
    }
}

// forward DFT along w (16 ky) with fused instance-norm-1. grid (hg=16,b=16)
__global__ void k_dftw(const float* __restrict__ x, float* __restrict__ ws) {
    __shared__ float xs[128*65];
    __shared__ float tblL[256];
    __shared__ float mu[64], rho[64];
    int t = threadIdx.x;
    int hg = blockIdx.x, b = blockIdx.y;
    for (int i = t; i < 256; i += 256) tblL[i] = ws[OFF_TBL + i];
    if (t < 64) {
        float s1 = ws[OFF_S1 + (b*64+t)*2], s2 = ws[OFF_S1 + (b*64+t)*2 + 1];
        float m = s1 * (1.f/16384.f);
        float v = s2 * (1.f/16384.f) - m*m;
        mu[t] = m; rho[t] = rsqrtf(v + 1e-5f);
    }
    __syncthreads();
    float* P = ws + OFF_PQ;
    int c = t & 63, kyg = t >> 6;
    for (int h = 0; h < 8; h++) {
        int habs = hg*8 + h;
        const float4* row = (const float4*)(x + ((long)(b*128 + habs)*128)*64);
        for (int idx = t; idx < 2048; idx += 256) {
            int w = idx >> 4, qq = idx & 15;
            float4 v = row[idx];
            int c0 = qq*4;
            xs[w*65 + c0]     = (v.x - mu[c0])   * rho[c0];
            xs[w*65 + c0 + 1] = (v.y - mu[c0+1]) * rho[c0+1];
            xs[w*65 + c0 + 2] = (v.z - mu[c0+2]) * rho[c0+2];
            xs[w*65 + c0 + 3] = (v.w - mu[c0+3]) * rho[c0+3];
        }
        __syncthreads();
        float accr[4] = {0,0,0,0}, acci[4] = {0,0,0,0};
        for (int w = 0; w < 128; w++) {
            float v = xs[w*65 + c];
            #pragma unroll
            for (int kk = 0; kk < 4; kk++) {
                int ky = kyg*4 + kk;
                int m = (ky * w) & 127;
                accr[kk] += v * tblL[2*m];      // e^{-i th}: re += v*cos
                acci[kk] -= v * tblL[2*m + 1];  //           im -= v*sin
            }
        }
        #pragma unroll
        for (int kk = 0; kk < 4; kk++) {
            int ky = kyg*4 + kk;
            float2* dst = (float2*)(P + (((b*128 + habs)*16 + ky)*128));
            dst[c] = make_float2(accr[kk], acci[kk]);
        }
        __syncthreads();
    }
}

// forward DFT along h (32 kx rows: 0..15 and 112..127). grid (ky=16, b=16)
__global__ void k_dfth(float* __restrict__ ws) {
    __shared__ float Ps[2048];
    __shared__ float tblL[256];
    int t = threadIdx.x;
    int ky = blockIdx.x, b = blockIdx.y;
    for (int i = t; i < 256; i += 256) tblL[i] = ws[OFF_TBL + i];
    const float* P = ws + OFF_PQ;
    float* X = ws + OFF_X;
    int c = t & 63, kxg = t >> 6;
    float accr[8] = {0,0,0,0,0,0,0,0}, acci[8] = {0,0,0,0,0,0,0,0};
    for (int hc = 0; hc < 8; hc++) {
        __syncthreads();
        for (int idx = t; idx < 2048; idx += 256) {
            int hh = idx >> 7, r = idx & 127;
            Ps[idx] = P[((long)((b*128 + hc*16 + hh)*16 + ky))*128 + r];
        }
        __syncthreads();
        for (int hh = 0; hh < 16; hh++) {
            int habs = hc*16 + hh;
            float vr = Ps[hh*128 + c*2], vi = Ps[hh*128 + c*2 + 1];
            #pragma unroll
            for (int kk = 0; kk < 8; kk++) {
                int kxI = kxg*8 + kk;
                int freq = kxI < 16 ? kxI : 96 + kxI;   // 112..127
                int m = (freq * habs) & 127;
                float cs = tblL[2*m], sn = tblL[2*m + 1];
                accr[kk] += vr*cs + vi*sn;              // * e^{-i th}
                acci[kk] += vi*cs - vr*sn;
            }
        }
    }
    #pragma unroll
    for (int kk = 0; kk < 8; kk++) {
        int kxI = kxg*8 + kk;
        float2* dst = (float2*)(X + (((b*32 + kxI)*16 + ky)*128));
        dst[c] = make_float2(accr[kk], acci[kk]);
    }
}

// per-mode complex mix: Out[b][o] = sum_i X[b][i] * W[i][o]. grid 512 (=mode)
__global__ void k_mix(float* __restrict__ ws) {
    __shared__ float Wsh[8192];
    __shared__ float Xs[2048];
    int t = threadIdx.x;
    int mode = blockIdx.x;
    int kxI = mode >> 4, ky = mode & 15;
    const float* WT = ws + OFF_WT;
    const float* X = ws + OFF_X;
    float* O = ws + OFF_O;
    for (int idx = t; idx < 8192; idx += 256) Wsh[idx] = WT[(long)mode*8192 + idx];
    for (int idx = t; idx < 2048; idx += 256) {
        int b = idx >> 7, r = idx & 127;
        Xs[idx] = X[((b*32 + kxI)*16 + ky)*128 + r];
    }
    __syncthreads();
    int o = t & 63, bg = t >> 6;
    float accr[4] = {0,0,0,0}, acci[4] = {0,0,0,0};
    for (int i = 0; i < 64; i++) {
        float wr = Wsh[(i*64 + o)*2], wi = Wsh[(i*64 + o)*2 + 1];
        #pragma unroll
        for (int j = 0; j < 4; j++) {
            float xr = Xs[(bg*4 + j)*128 + 2*i], xi = Xs[(bg*4 + j)*128 + 2*i + 1];
            accr[j] += xr*wr - xi*wi;
            acci[j] += xr*wi + xi*wr;
        }
    }
    #pragma unroll
    for (int j = 0; j < 4; j++) {
        int b = bg*4 + j;
        float2* dst = (float2*)(O + ((b*32 + kxI)*16 + ky)*128);
        dst[o] = make_float2(accr[j], acci[j]);
    }
}

// Parseval stats of y directly from O. grid (16=b, 4=gg), 256 thr.
// Sum y^2 = [(1/2)T0 + (1/2)T1 + 2*T2] / 16384, accumulated via atomics into S2.
__global__ void k_pstats(float* __restrict__ ws) {
    __shared__ float red[256];
    int t = threadIdx.x, b = blockIdx.x, gg = blockIdx.y;
    int c = t & 63, g = t >> 6;
    const float* O = ws + OFF_O + (long)b*65536;   // [(kxI*16+ky)*128 + 2c]
    float t0 = 0.f, t2 = 0.f;
    int k0 = gg*8 + g*2;
    for (int kxI = k0; kxI < k0 + 2; kxI++)
        for (int ky = 0; ky < 16; ky++) {
            float re = O[(kxI*16 + ky)*128 + 2*c];
            float im = O[(kxI*16 + ky)*128 + 2*c + 1];
            float p = re*re + im*im;
            if (ky == 0) t0 += p; else t2 += p;
        }
    float s2p = 0.5f*t0 + 2.f*t2;
    if (gg == 0 && g == 0) {
        float ar = O[2*c], ai = O[2*c + 1];        // kxI=0, ky=0
        float t1 = ar*ar - ai*ai;
        for (int k = 1; k <= 15; k++) {
            float xr = O[(k*16)*128 + 2*c],        xi = O[(k*16)*128 + 2*c + 1];
            float yr = O[((32-k)*16)*128 + 2*c],   yi = O[((32-k)*16)*128 + 2*c + 1];
            t1 += 2.f*(xr*yr - xi*yi);
        }
        s2p += 0.5f*t1;
        ws[OFF_S2 + (b*64 + c)*2] = ar;            // s1 = mean-related term
    }
    red[t] = s2p;
    __syncthreads();
    if (t < 64) {
        float s = red[t] + red[t+64] + red[t+128] + red[t+192];
        atomicAdd(&ws[OFF_S2 + (b*64 + t)*2 + 1], s * (1.f/16384.f));
    }
}

// inverse DFT along h: Q[b][h][ky][o] = sum_kx Out e^{+i 2pi f(kx) h/128}. grid (hg=16,b=16)
__global__ void k_idfth(float* __restrict__ ws) {
    __shared__ float Os[8192];
    __shared__ float tblL[256];
    int t = threadIdx.x;
    int hg = blockIdx.x, b = blockIdx.y;
    for (int i = t; i < 256; i += 256) tblL[i] = ws[OFF_TBL + i];
    const float* O = ws + OFF_O;
    float* Q = ws + OFF_PQ;
    int o = t & 63, kyg = t >> 6;
    float accr[4][8], acci[4][8];
    #pragma unroll
    for (int kk = 0; kk < 4; kk++)
        #pragma unroll
        for (int h = 0; h < 8; h++) { accr[kk][h] = 0.f; acci[kk][h] = 0.f; }
    for (int kc = 0; kc < 8; kc++) {
        __syncthreads();
        for (int idx = t; idx < 8192; idx += 256) Os[idx] = O[(long)b*65536 + kc*8192 + idx];
        __syncthreads();
        for (int k4 = 0; k4 < 4; k4++) {
            int kxI = kc*4 + k4;
            int freq = kxI < 16 ? kxI : 96 + kxI;
            float vr[4], vi[4];
            #pragma unroll
            for (int kk = 0; kk < 4; kk++) {
                int ky = kyg*4 + kk;
                vr[kk] = Os[((k4*16 + ky)*64 + o)*2];
                vi[kk] = Os[((k4*16 + ky)*64 + o)*2 + 1];
            }
            for (int h = 0; h < 8; h++) {
                int habs = hg*8 + h;
                int m = (freq * habs) & 127;
                float cs = tblL[2*m], sn = tblL[2*m + 1];
                #pragma unroll
                for (int kk = 0; kk < 4; kk++) {
                    accr[kk][h] += vr[kk]*cs - vi[kk]*sn;   // * e^{+i th}
                    acci[kk][h] += vr[kk]*sn + vi[kk]*cs;
                }
            }
        }
    }
    #pragma unroll
    for (int kk = 0; kk < 4; kk++)
        #pragma unroll
        for (int h = 0; h < 8; h++) {
            int ky = kyg*4 + kk, habs = hg*8 + h;
            float2* dst = (float2*)(Q + ((long)(b*128 + habs)*16 + ky)*128);
            dst[o] = make_float2(accr[kk][h], acci[kk][h]);
        }
}

// fused MFMA kernel: Y = M@Qm (iDFT-w), z = (Y-mu)*rho, h = GELU(z@W1+b1),
// out = h@W2+b2. G1 keeps hi/lo 3-MFMA (rho ~316 amplifies); z/W1/W2/h single bf16.
// LDS 75.3KB -> 2 blocks/CU. grid (h=128,b=16)
__global__ __launch_bounds__(256, 2) void k_mlp(const float* __restrict__ mb1,
                      const float* __restrict__ mb2,
                      float* __restrict__ out, const float* __restrict__ ws) {
    __shared__ unsigned short zhS[8192];                // z[w][64c], swz (w&7)<<4
    __shared__ unsigned short w1hS[8192];               // w1[j][64c], swz (j&7)<<4
    __shared__ unsigned short w2hS[8192];               // w2[o][128j], swz (o&15)<<4
    __shared__ unsigned short hhS[8192];                // h-half [w][64jl], swz (w&7)<<4
    __shared__ unsigned short qhS[2560], qlS[2560];     // QmT[c][40k] hi/lo
    __shared__ float muL[64], rhoL[64], b1L[128], b2L[64];
    int t = threadIdx.x;
    int h = blockIdx.x, b = blockIdx.y;
    int l = t & 63, wv = t >> 6;

    const unsigned short* xu = (const unsigned short*)(ws + OFF_X);
    const unsigned short* w1hG = xu;
    const unsigned short* w2hG = xu + 16384;
    const unsigned short* MhG  = xu + 32768, *MlG  = xu + 36864;

    // ---- stage weights into LDS (XOR swizzle), hi parts only ----
    for (int ch = t; ch < 1024; ch += 256) {       // w1: rows j, stride 128B
        int j = ch >> 3, c0 = (ch & 7) * 8;
        unsigned off = (unsigned)(j*128 + c0*2) ^ (unsigned)((j & 7) << 4);
        *(bfrag*)((char*)w1hS + off) = *(const bfrag*)(w1hG + ch*8);
    }
    for (int ch = t; ch < 1024; ch += 256) {       // w2: rows o, stride 256B
        int o = ch >> 4, j0 = (ch & 15) * 8;
        unsigned off = (unsigned)(o*256 + j0*2) ^ (unsigned)((o & 15) << 4);
        *(bfrag*)((char*)w2hS + off) = *(const bfrag*)(w2hG + ch*8);
    }
    // ---- QmT[c][k] build; lane-consecutive k -> ~2-way banks ----
    const float* Qp = ws + OFF_PQ + (long)(b*128 + h)*2048;
    for (int i = t; i < 2048; i += 256) {
        int k = i & 31, c = i >> 5;
        float v = Qp[(k >> 1)*128 + c*2 + (k & 1)];
        unsigned short hi, lo; split2(v, hi, lo);
        qhS[c*40 + k] = hi; qlS[c*40 + k] = lo;
    }
    if (t < 64) {
        float s1 = ws[OFF_S2 + (b*64+t)*2], s2 = ws[OFF_S2 + (b*64+t)*2 + 1];
        float m = s1 * (1.f/16384.f);
        float v = s2 * (1.f/16384.f) - m*m;
        muL[t] = m; rhoL[t] = rsqrtf(v + 1e-5f);
        b2L[t] = mb2[t];
    }
    if (t >= 64 && t < 192) b1L[t - 64] = mb1[t - 64];
    // M A-frags from global (rows w of this wave's two 16-row tiles)
    bfrag ma_h[2], ma_l[2];
    #pragma unroll
    for (int q = 0; q < 2; q++) {
        int w = (wv + 4*q)*16 + (l & 15);
        ma_h[q] = *(const bfrag*)(MhG + w*32 + (l >> 4)*8);
        ma_l[q] = *(const bfrag*)(MlG + w*32 + (l >> 4)*8);
    }
    __syncthreads();

    // ---- G1: Y = M @ Qm ; z = (Y - mu) * rho -> zhS (single bf16) ----
    #pragma unroll
    for (int q = 0; q < 2; q++) {
        int wt = wv + 4*q;
        #pragma unroll
        for (int ct = 0; ct < 4; ct++) {
            unsigned ro = (unsigned)((ct*16 + (l & 15))*80 + (l >> 4)*16);
            bfrag bh = *(const bfrag*)((const char*)qhS + ro);
            bfrag bl = *(const bfrag*)((const char*)qlS + ro);
            f4v acc = {0.f, 0.f, 0.f, 0.f};
            acc = MFMA(ma_h[q], bh, acc);
            acc = MFMA(ma_h[q], bl, acc);
            acc = MFMA(ma_l[q], bh, acc);
            int c = ct*16 + (l & 15);
            float mu_ = muL[c], rh_ = rhoL[c];
            #pragma unroll
            for (int r = 0; r < 4; r++) {
                int w = wt*16 + (l >> 4)*4 + r;
                float z = (acc[r] - mu_) * rh_;
                unsigned off = (unsigned)(w*128 + c*2) ^ (unsigned)((w & 7) << 4);
                *(unsigned short*)((char*)zhS + off) = f2bf_rn(z);
            }
        }
    }
    __syncthreads();

    // cache z A-frags (single, reused for both j-halves)
    bfrag za[2][2];
    #pragma unroll
    for (int q = 0; q < 2; q++) {
        int w = (wv + 4*q)*16 + (l & 15);
        #pragma unroll
        for (int ks = 0; ks < 2; ks++) {
            unsigned off = (unsigned)(w*128 + (ks*32 + (l >> 4)*8)*2) ^ (unsigned)((w & 7) << 4);
            za[q][ks] = *(const bfrag*)((const char*)zhS + off);
        }
    }
    f4v accO[2][4];
    #pragma unroll
    for (int q = 0; q < 2; q++)
        #pragma unroll
        for (int ot = 0; ot < 4; ot++) accO[q][ot] = (f4v){0.f,0.f,0.f,0.f};

    #pragma unroll
    for (int jh = 0; jh < 2; jh++) {
        // ---- G2: h-half = GELU(z @ W1[:, jh*64 .. +64) + b1) ----
        #pragma unroll
        for (int q = 0; q < 2; q++) {
            int wt = wv + 4*q;
            #pragma unroll
            for (int jt = 0; jt < 4; jt++) {
                int j = jh*64 + jt*16 + (l & 15);
                f4v acc = {0.f, 0.f, 0.f, 0.f};
                #pragma unroll
                for (int ks = 0; ks < 2; ks++) {
                    unsigned off = (unsigned)(j*128 + (ks*32 + (l >> 4)*8)*2) ^ (unsigned)((j & 7) << 4);
                    bfrag bh = *(const bfrag*)((const char*)w1hS + off);
                    acc = MFMA(za[q][ks], bh, acc);
                }
                float bj = b1L[j];
                #pragma unroll
                for (int r = 0; r < 4; r++) {
                    int w = wt*16 + (l >> 4)*4 + r;
                    float hv = gelu_t(acc[r] + bj);
                    int jl = jt*16 + (l & 15);
                    unsigned off = (unsigned)(w*128 + jl*2) ^ (unsigned)((w & 7) << 4);
                    *(unsigned short*)((char*)hhS + off) = f2bf_rn(hv);
                }
            }
        }
        __syncthreads();
        // ---- G3 partial: out += h-half @ W2[jh*64.., :] ----
        #pragma unroll
        for (int q = 0; q < 2; q++) {
            int w = (wv + 4*q)*16 + (l & 15);
            bfrag ha[2];
            #pragma unroll
            for (int ks = 0; ks < 2; ks++) {
                unsigned off = (unsigned)(w*128 + (ks*32 + (l >> 4)*8)*2) ^ (unsigned)((w & 7) << 4);
                ha[ks] = *(const bfrag*)((const char*)hhS + off);
            }
            #pragma unroll
            for (int ot = 0; ot < 4; ot++) {
                int o = ot*16 + (l & 15);
                f4v acc = accO[q][ot];
                #pragma unroll
                for (int ks = 0; ks < 2; ks++) {
                    int jj = jh*64 + ks*32 + (l >> 4)*8;
                    unsigned off = (unsigned)(o*256 + jj*2) ^ (unsigned)((o & 15) << 4);
                    bfrag bh = *(const bfrag*)((const char*)w2hS + off);
                    acc = MFMA(ha[ks], bh, acc);
                }
                accO[q][ot] = acc;
            }
        }
        __syncthreads();   // protect h buffer before next half overwrites
    }
    // ---- store out + b2 ----
    #pragma unroll
    for (int q = 0; q < 2; q++) {
        int wt = wv + 4*q;
        #pragma unroll
        for (int ot = 0; ot < 4; ot++) {
            int o = ot*16 + (l & 15);
            float bo = b2L[o];
            #pragma unroll
            for (int r = 0; r < 4; r++) {
                int w = wt*16 + (l >> 4)*4 + r;
                out[((long)(b*128 + h)*128 + w)*64 + o] = accO[q][ot][r] + bo;
            }
        }
    }
}

extern "C" void kernel_launch(void* const* d_in, const int* in_sizes, int n_in,
                              void* d_out, int out_size, void* d_ws, size_t ws_size,
                              hipStream_t stream) {
    const float* x   = (const float*)d_in[0];
    const float* w1r = (const float*)d_in[1];
    const float* w1i = (const float*)d_in[2];
    const float* w2r = (const float*)d_in[3];
    const float* w2i = (const float*)d_in[4];
    const float* mw1 = (const float*)d_in[5];
    const float* mb1 = (const float*)d_in[6];
    const float* mw2 = (const float*)d_in[7];
    const float* mb2 = (const float*)d_in[8];
    float* ws  = (float*)d_ws;
    float* out = (float*)d_out;

    k_init  <<<dim3(1),      dim3(256), 0, stream>>>(ws);
    k_stats1<<<dim3(16,16),  dim3(256), 0, stream>>>(x, ws);
    k_trans <<<dim3(64,2),   dim3(256), 0, stream>>>(w1r, w1i, w2r, w2i, ws);
    k_dftw  <<<dim3(16,16),  dim3(256), 0, stream>>>(x, ws);
    k_dfth  <<<dim3(16,16),  dim3(256), 0, stream>>>(ws);
    k_mix   <<<dim3(512),    dim3(256), 0, stream>>>(ws);
    k_wmlp  <<<dim3(80),     dim3(256), 0, stream>>>(mw1, mw2, ws);  // X dead after k_mix
    k_pstats<<<dim3(16,4),   dim3(256), 0, stream>>>(ws);
    k_idfth <<<dim3(16,16),  dim3(256), 0, stream>>>(ws);
    k_mlp   <<<dim3(128,16), dim3(256), 0, stream>>>(mb1, mb2, out, ws);
}

// Round 6
// 258.538 us; speedup vs baseline: 3.2902x; 1.1606x over previous
//
#include <hip/hip_runtime.h>
#include <math.h>

// Problem constants: B=16, H=W=128, C=64, M1=M2=16
// Workspace layout (float offsets):
#define OFF_TBL 0u            // 128 x {cos,sin}(2*pi*m/128)          (256)
#define OFF_S1  256u          // instance-norm-1 raw sums [b*64+c][2] (2048)
#define OFF_S2  2304u         // instance-norm-2 stats (s1,s2)        (2048)
#define OFF_PQ  4352u         // PT[b][(ky*64+c)*2+ri][h] u32-packed bf16 hi/lo (4194304)
                              //   aliased later with Q[b][h][ky][o][2] f32
#define OFF_X   4198656u      // X[b][kx][ky][c][2] f32               (1048576)
#define OFF_O   5247232u      // Out[b][kx][ky][o][2] f32             (1048576)
                              //   head doubles (pre-mix) as u16 trig tables:
                              //   FdAh[32][128] @0, FdAl @4096, EdAh[64][128] @8192, EdAl @16384
#define OFF_WT  6295808u      // WT[mode][i][o][2]                    (4194304)
// total = 10490112 floats = 41.96 MB
// X region is dead after k_mix -> reuse as u16 arrays for bf16-split MLP weights:
//   u16[0..8192) w1hi   [8192..16384) w1lo   [16384..24576) w2hi
//   [24576..32768) w2lo  [32768..36864) Mhi  [36864..40960) Mlo

typedef __attribute__((ext_vector_type(8))) short bfrag;
typedef __attribute__((ext_vector_type(4))) float f4v;
#define MFMA(A,B,C) __builtin_amdgcn_mfma_f32_16x16x32_bf16(A,B,C,0,0,0)

__device__ __forceinline__ unsigned short f2bf_rn(float x) {
    unsigned u = __float_as_uint(x);
    unsigned r = u + 0x7FFFu + ((u >> 16) & 1u);
    return (unsigned short)(r >> 16);
}
__device__ __forceinline__ float bf2f(unsigned short h) {
    return __uint_as_float(((unsigned)h) << 16);
}
__device__ __forceinline__ void split2(float x, unsigned short& hi, unsigned short& lo) {
    hi = f2bf_rn(x);
    lo = f2bf_rn(x - bf2f(hi));
}
// tanh-form GELU; matches exact GELU to <1e-5 for |x| <= 0.5 (our range)
__device__ __forceinline__ float gelu_t(float x) {
    float u = 0.79788456080286536f * (x + 0.044715f * x * x * x);
    float e = __expf(2.f * u);
    float th = 1.f - 2.f / (e + 1.f);
    return 0.5f * x * (1.f + th);
}

// block 0: twiddle table + zero S1/S2. blocks 1..48: bf16-split trig tables
// (F for dftw, E for dfth) into the O region (dead until k_mix overwrites).
__global__ void k_init(float* __restrict__ ws) {
    int t = threadIdx.x, bid = blockIdx.x;
    if (bid == 0) {
        if (t < 128) {
            double ang = 6.283185307179586476925286766559 * (double)t / 128.0;
            ws[OFF_TBL + 2*t]     = (float)cos(ang);
            ws[OFF_TBL + 2*t + 1] = (float)sin(ang);
        }
        for (int i = t; i < 4096; i += 256) ws[OFF_S1 + i] = 0.f;
        return;
    }
    int e = (bid - 1)*256 + t;   // 0..12287
    unsigned short* OU = (unsigned short*)(ws + OFF_O);
    const double TWO_PI = 6.283185307179586476925286766559;
    if (e < 4096) {              // FdA[row=ri*16+ky][w]: re rows cos, im rows -sin
        int row = e >> 7, w = e & 127, ky = row & 15;
        double ang = TWO_PI * (double)((ky * w) & 127) / 128.0;
        double v = (row < 16) ? cos(ang) : -sin(ang);
        unsigned short hi, lo; split2((float)v, hi, lo);
        OU[e] = hi; OU[4096 + e] = lo;
    } else {                     // EdA[row=2kx+s][h]: s=0 cos, s=1 sin (of freq f(kx))
        int e2 = e - 4096, row = e2 >> 7, h = e2 & 127;
        int kx = row >> 1, f = kx < 16 ? kx : 96 + kx;
        double ang = TWO_PI * (double)((f * h) & 127) / 128.0;
        double v = (row & 1) ? sin(ang) : cos(ang);
        unsigned short hi, lo; split2((float)v, hi, lo);
        OU[8192 + e2] = hi; OU[16384 + e2] = lo;
    }
}

// per-(b,c) sum & sumsq of x (feeds rho1 used in k_mix). grid (hg=16, b=16)
__global__ void k_stats1(const float* __restrict__ x, float* __restrict__ ws) {
    __shared__ float red[16][16][8];
    int t = threadIdx.x;
    int hg = blockIdx.x, b = blockIdx.y;
    const float4* x4 = (const float4*)x;
    int q = t & 15, pslot = t >> 4;
    float4 sum = {0,0,0,0}, sq = {0,0,0,0};
    long base = ((long)(b*128 + hg*8)*128) * 16;   // float4 index
    for (int p = pslot; p < 1024; p += 16) {
        float4 v = x4[base + (long)p*16 + q];
        sum.x += v.x; sum.y += v.y; sum.z += v.z; sum.w += v.w;
        sq.x += v.x*v.x; sq.y += v.y*v.y; sq.z += v.z*v.z; sq.w += v.w*v.w;
    }
    red[pslot][q][0]=sum.x; red[pslot][q][1]=sum.y; red[pslot][q][2]=sum.z; red[pslot][q][3]=sum.w;
    red[pslot][q][4]=sq.x;  red[pslot][q][5]=sq.y;  red[pslot][q][6]=sq.z;  red[pslot][q][7]=sq.w;
    __syncthreads();
    if (t < 64) {
        int qq = t >> 2, ci = t & 3;
        float a = 0.f, s = 0.f;
        for (int p = 0; p < 16; p++) { a += red[p][qq][ci]; s += red[p][qq][4+ci]; }
        atomicAdd(&ws[OFF_S1 + (b*64 + t)*2],     a);
        atomicAdd(&ws[OFF_S1 + (b*64 + t)*2 + 1], s);
    }
}

// weight transpose: [i][o][kx][ky] (x4 arrays) -> WT[mode][i][o][{re,im}]. grid (64=i, 2=part)
__global__ void k_trans(const float* __restrict__ w1r, const float* __restrict__ w1i,
                        const float* __restrict__ w2r, const float* __restrict__ w2i,
                        float* __restrict__ ws) {
    __shared__ float Lr[16*257], Li[16*257];
    int t = threadIdx.x;
    int i = blockIdx.x;
    int part = blockIdx.y;
    float* WT = ws + OFF_WT;
    const float* wr = part ? w2r : w1r;
    const float* wi = part ? w2i : w1i;
    for (int oc = 0; oc < 4; oc++) {
        int o0 = oc * 16;
        __syncthreads();
        for (int idx = t; idx < 4096; idx += 256) {
            int oo = idx >> 8, m = idx & 255;
            Lr[oo*257 + m] = wr[(i*64 + o0 + oo)*256 + m];
            Li[oo*257 + m] = wi[(i*64 + o0 + oo)*256 + m];
        }
        __syncthreads();
        for (int idx = t; idx < 8192; idx += 256) {
            int mode = idx >> 5, rem = idx & 31, oo = rem >> 1, ri = rem & 1;
            float val = ri ? Li[oo*257 + mode] : Lr[oo*257 + mode];
            int gm = part*256 + mode;
            WT[((gm*64 + i)*64 + (o0 + oo))*2 + ri] = val;
        }
    }
}

// bf16-split MLP weights + iDFT-w matrix M into the dead X region. grid 80
__global__ void k_wmlp(const float* __restrict__ mw1, const float* __restrict__ mw2,
                       float* __restrict__ ws) {
    int i = blockIdx.x * 256 + threadIdx.x;   // [0, 20480)
    unsigned short* xu = (unsigned short*)(ws + OFF_X);
    if (i < 8192) {
        unsigned short hi, lo; split2(mw1[i], hi, lo);
        xu[i] = hi; xu[8192 + i] = lo;
    } else if (i < 16384) {
        int k = i - 8192;
        unsigned short hi, lo; split2(mw2[k], hi, lo);
        xu[16384 + k] = hi; xu[24576 + k] = lo;
    } else if (i < 20480) {
        int m = i - 16384;           // w*32 + k
        int w = m >> 5, k = m & 31;
        int ky = k >> 1;
        double ang = 6.283185307179586476925286766559 * (double)((ky * w) & 127) / 128.0;
        double v = (k & 1) ? -sin(ang) : cos(ang);
        double a = (ky == 0) ? 1.0 : 2.0;
        float val = (float)(v * a) * (1.f/16384.f);
        unsigned short hi, lo; split2(val, hi, lo);
        xu[32768 + m] = hi; xu[36864 + m] = lo;
    }
}

// MFMA forward DFT along w on RAW x (norm deferred to k_mix).
// P[ky,ri][(h,c)] = FdA @ x. Output PT[b][(ky*64+c)*2+ri][h] u32-packed bf16 hi/lo.
// grid (cg=16, b=16): block owns 4 c (c0=cg*4), all 128 h. Wave wv owns h in
// [wv*32, wv*32+32) -- fully wave-private staging, NO barriers.
__global__ __launch_bounds__(256) void k_dftw(const float* __restrict__ x, float* __restrict__ ws) {
    __shared__ unsigned BTall[16384];    // 64KB: per-wave 16KB {BTh 8KB | BTl 8KB}, then trans buf
    int t = threadIdx.x;
    int cg = blockIdx.x, b = blockIdx.y;
    int c0 = cg*4;
    int l = t & 63, wv = t >> 6;
    char* wbase = (char*)BTall + wv*16384;

    const unsigned short* OU = (const unsigned short*)(ws + OFF_O);
    const unsigned short* FdAh = OU, *FdAl = OU + 4096;

    // A-frags: FdA rows (mt*16 + lane&15), k = kc*32 + oct*8
    bfrag ma_h[2][4], ma_l[2][4];
    #pragma unroll
    for (int mt = 0; mt < 2; mt++)
        #pragma unroll
        for (int kc = 0; kc < 4; kc++) {
            int off = (mt*16 + (l & 15))*128 + kc*32 + (l >> 4)*8;
            ma_h[mt][kc] = *(const bfrag*)(FdAh + off);
            ma_l[mt][kc] = *(const bfrag*)(FdAl + off);
        }
    f4v acc[2][4][2];
    #pragma unroll
    for (int mt = 0; mt < 2; mt++)
        #pragma unroll
        for (int cj = 0; cj < 4; cj++)
            #pragma unroll
            for (int q = 0; q < 2; q++) acc[mt][cj][q] = (f4v){0.f,0.f,0.f,0.f};

    const float* xb = x + ((long)(b*128 + wv*32))*8192 + c0;   // h stride 8192 floats
    #pragma unroll
    for (int kc = 0; kc < 4; kc++) {
        // ---- stage: x[h=wv*32+hl][w=kc*32+2kkq(+1)][c0..c0+3] -> BT[lc=cj*32+hl][kk] ----
        #pragma unroll
        for (int it = 0; it < 8; it++) {
            int p = l + 64*it;
            int hl = p >> 4, kkq = p & 15;
            const float* src = xb + (long)hl*8192 + (kc*32 + kkq*2)*64;
            float4 a = *(const float4*)src;
            float4 bb = *(const float4*)(src + 64);
            #pragma unroll
            for (int cj = 0; cj < 4; cj++) {
                float va = ((const float*)&a)[cj], vb = ((const float*)&bb)[cj];
                unsigned short ah, al2, bh2, bl2;
                split2(va, ah, al2); split2(vb, bh2, bl2);
                unsigned hp = (unsigned)ah | ((unsigned)bh2 << 16);
                unsigned lp = (unsigned)al2 | ((unsigned)bl2 << 16);
                int lc = cj*32 + hl;
                unsigned bad = (unsigned)(lc*64 + ((kkq*4) ^ ((lc & 3) << 4)));
                *(unsigned*)(wbase + bad) = hp;
                *(unsigned*)(wbase + 8192 + bad) = lp;
            }
        }
        // ---- MFMA: per (cj,q) Ntile, 2 Mtiles, 3-term hi/lo ----
        #pragma unroll
        for (int cj = 0; cj < 4; cj++)
            #pragma unroll
            for (int q = 0; q < 2; q++) {
                int lc = cj*32 + q*16 + (l & 15);
                unsigned ro = (unsigned)(lc*64 + (((l >> 4)*16) ^ ((lc & 3) << 4)));
                bfrag bh = *(const bfrag*)(wbase + ro);
                bfrag bl = *(const bfrag*)(wbase + 8192 + ro);
                #pragma unroll
                for (int mt = 0; mt < 2; mt++) {
                    f4v a_ = acc[mt][cj][q];
                    a_ = MFMA(ma_h[mt][kc], bh, a_);
                    a_ = MFMA(ma_h[mt][kc], bl, a_);
                    a_ = MFMA(ma_l[mt][kc], bh, a_);
                    acc[mt][cj][q] = a_;
                }
            }
    }
    // ---- epilogue: split-pack -> LDS trans [trow=(cj*2+mt)*16+ky][32 h] u32 ----
    #pragma unroll
    for (int mt = 0; mt < 2; mt++)
        #pragma unroll
        for (int cj = 0; cj < 4; cj++)
            #pragma unroll
            for (int q = 0; q < 2; q++)
                #pragma unroll
                for (int r = 0; r < 4; r++) {
                    float v = acc[mt][cj][q][r];
                    unsigned short hi, lo; split2(v, hi, lo);
                    int ky = (l >> 4)*4 + r;
                    int trow = (cj*2 + mt)*16 + ky;
                    int hl = q*16 + (l & 15);
                    unsigned ad = (unsigned)(trow*128 + ((hl*4) ^ ((trow & 7) << 4)));
                    *(unsigned*)(wbase + ad) = ((unsigned)hi << 16) | (unsigned)lo;
                }
    // ---- coalesced readback -> global PT (h-contiguous rows) ----
    unsigned* PT = (unsigned*)(ws + OFF_PQ);
    #pragma unroll
    for (int rr = 0; rr < 2; rr++) {
        int trow = l*2 + rr;
        int ky = trow & 15, tmp = trow >> 4;
        int mt = tmp & 1, cj = tmp >> 1;
        long grow = ((long)(ky*64 + c0 + cj))*2 + mt;
        unsigned* gdst = PT + (((long)b*2048 + grow) << 7) + wv*32;
        #pragma unroll
        for (int j = 0; j < 8; j++) {
            unsigned ad = (unsigned)(trow*128 + ((j*16) ^ ((trow & 7) << 4)));
            *(uint4*)(gdst + j*4) = *(const uint4*)(wbase + ad);
        }
    }
}

// MFMA forward DFT along h: X[2kx+s][(c,ri)] = EdA @ PT (per ky,b).
// Complex combine: Xr = G[2kx][colr]+G[2kx+1][coli], Xi = G[2kx][coli]-G[2kx+1][colr]
// via shfl_xor(1). grid (ky=16, b=16); wave wv = Mtile wv. X stays f32 legacy layout.
__global__ __launch_bounds__(256) void k_dfth(float* __restrict__ ws) {
    __shared__ unsigned Bsh[16384];   // BTh 32KB (128 cols x 256B) | BTl 32KB
    int t = threadIdx.x;
    int ky = blockIdx.x, b = blockIdx.y;
    int l = t & 63, wv = t >> 6;
    char* bh_base = (char*)Bsh;
    char* bl_base = bh_base + 32768;
    const unsigned* PT = (const unsigned*)(ws + OFF_PQ);
    const unsigned short* OU = (const unsigned short*)(ws + OFF_O);
    const unsigned short* EdAh = OU + 8192, *EdAl = OU + 16384;

    // ---- stage PT rows (col n = c*2+ri of this ky) -> BT[n][128 kk] hi/lo ----
    {
        int n = t >> 1, hh = (t & 1)*64;
        const uint4* src = (const uint4*)(PT + ((long)b*2048 + ky*128 + n)*128 + hh);
        #pragma unroll
        for (int jj = 0; jj < 16; jj++) {
            uint4 v = src[jj];
            unsigned h01 = (v.x >> 16) | (v.y & 0xFFFF0000u);
            unsigned h23 = (v.z >> 16) | (v.w & 0xFFFF0000u);
            unsigned l01 = (v.x & 0xFFFFu) | (v.y << 16);
            unsigned l23 = (v.z & 0xFFFFu) | (v.w << 16);
            int kk = hh + jj*4;
            unsigned ad = (unsigned)(n*256 + ((kk*2) ^ ((n & 7) << 4)));
            *(uint2*)(bh_base + ad) = make_uint2(h01, h23);
            *(uint2*)(bl_base + ad) = make_uint2(l01, l23);
        }
    }
    // A-frags for this wave's Mtile
    bfrag ea_h[4], ea_l[4];
    #pragma unroll
    for (int kc = 0; kc < 4; kc++) {
        int off = (wv*16 + (l & 15))*128 + kc*32 + (l >> 4)*8;
        ea_h[kc] = *(const bfrag*)(EdAh + off);
        ea_l[kc] = *(const bfrag*)(EdAl + off);
    }
    __syncthreads();
    f4v acc[8];
    #pragma unroll
    for (int nt = 0; nt < 8; nt++) acc[nt] = (f4v){0.f,0.f,0.f,0.f};
    #pragma unroll
    for (int kc = 0; kc < 4; kc++)
        #pragma unroll
        for (int nt = 0; nt < 8; nt++) {
            int col = nt*16 + (l & 15);
            unsigned ro = (unsigned)(col*256 + ((kc*64 + (l >> 4)*16) ^ ((col & 7) << 4)));
            bfrag bh = *(const bfrag*)(bh_base + ro);
            bfrag bl = *(const bfrag*)(bl_base + ro);
            acc[nt] = MFMA(ea_h[kc], bh, acc[nt]);
            acc[nt] = MFMA(ea_h[kc], bl, acc[nt]);
            acc[nt] = MFMA(ea_l[kc], bh, acc[nt]);
        }
    // ---- epilogue: complex combine + store X (f32, legacy layout) ----
    float* X = ws + OFF_X;
    #pragma unroll
    for (int nt = 0; nt < 8; nt++)
        #pragma unroll
        for (int p = 0; p < 2; p++) {
            float s0 = acc[nt][2*p], s1 = acc[nt][2*p + 1];
            float partner = __shfl_xor(s1, 1, 64);
            float res = (l & 1) ? (s0 - partner) : (s0 + partner);
            int kx = wv*8 + (l >> 4)*2 + p;
            X[(((long)b*32 + kx)*16 + ky)*128 + nt*16 + (l & 15)] = res;
        }
}

// per-mode complex mix with rho1 scaling folded into X staging. grid 512 (=mode)
__global__ void k_mix(float* __restrict__ ws) {
    __shared__ float Wsh[8192];
    __shared__ float Xs[2048];
    __shared__ float rhoT[1024];
    int t = threadIdx.x;
    int mode = blockIdx.x;
    int kxI = mode >> 4, ky = mode & 15;
    const float* WT = ws + OFF_WT;
    const float* X = ws + OFF_X;
    float* O = ws + OFF_O;
    for (int i = t; i < 1024; i += 256) {
        float a = ws[OFF_S1 + 2*i], s = ws[OFF_S1 + 2*i + 1];
        float m = a * (1.f/16384.f);
        float v = s * (1.f/16384.f) - m*m;
        rhoT[i] = rsqrtf(v + 1e-5f);
    }
    for (int idx = t; idx < 8192; idx += 256) Wsh[idx] = WT[(long)mode*8192 + idx];
    __syncthreads();
    for (int idx = t; idx < 2048; idx += 256) {
        int b = idx >> 7, r = idx & 127;
        Xs[idx] = X[((b*32 + kxI)*16 + ky)*128 + r] * rhoT[b*64 + (r >> 1)];
    }
    __syncthreads();
    int o = t & 63, bg = t >> 6;
    float accr[4] = {0,0,0,0}, acci[4] = {0,0,0,0};
    for (int i = 0; i < 64; i++) {
        float wr = Wsh[(i*64 + o)*2], wi = Wsh[(i*64 + o)*2 + 1];
        #pragma unroll
        for (int j = 0; j < 4; j++) {
            float xr = Xs[(bg*4 + j)*128 + 2*i], xi = Xs[(bg*4 + j)*128 + 2*i + 1];
            accr[j] += xr*wr - xi*wi;
            acci[j] += xr*wi + xi*wr;
        }
    }
    #pragma unroll
    for (int j = 0; j < 4; j++) {
        int b = bg*4 + j;
        float2* dst = (float2*)(O + ((b*32 + kxI)*16 + ky)*128);
        dst[o] = make_float2(accr[j], acci[j]);
    }
}

// Parseval stats of y directly from O. grid (16=b, 4=gg), 256 thr.
__global__ void k_pstats(float* __restrict__ ws) {
    __shared__ float red[256];
    int t = threadIdx.x, b = blockIdx.x, gg = blockIdx.y;
    int c = t & 63, g = t >> 6;
    const float* O = ws + OFF_O + (long)b*65536;   // [(kxI*16+ky)*128 + 2c]
    float t0 = 0.f, t2 = 0.f;
    int k0 = gg*8 + g*2;
    for (int kxI = k0; kxI < k0 + 2; kxI++)
        for (int ky = 0; ky < 16; ky++) {
            float re = O[(kxI*16 + ky)*128 + 2*c];
            float im = O[(kxI*16 + ky)*128 + 2*c + 1];
            float p = re*re + im*im;
            if (ky == 0) t0 += p; else t2 += p;
        }
    float s2p = 0.5f*t0 + 2.f*t2;
    if (gg == 0 && g == 0) {
        float ar = O[2*c], ai = O[2*c + 1];        // kxI=0, ky=0
        float t1 = ar*ar - ai*ai;
        for (int k = 1; k <= 15; k++) {
            float xr = O[(k*16)*128 + 2*c],        xi = O[(k*16)*128 + 2*c + 1];
            float yr = O[((32-k)*16)*128 + 2*c],   yi = O[((32-k)*16)*128 + 2*c + 1];
            t1 += 2.f*(xr*yr - xi*yi);
        }
        s2p += 0.5f*t1;
        ws[OFF_S2 + (b*64 + c)*2] = ar;            // s1 (mean term)
    }
    red[t] = s2p;
    __syncthreads();
    if (t < 64) {
        float s = red[t] + red[t+64] + red[t+128] + red[t+192];
        atomicAdd(&ws[OFF_S2 + (b*64 + t)*2 + 1], s * (1.f/16384.f));
    }
}

// inverse DFT along h: Q[b][h][ky][o] = sum_kx Out e^{+i 2pi f(kx) h/128}. grid (hg=16,b=16)
__global__ void k_idfth(float* __restrict__ ws) {
    __shared__ float Os[8192];
    __shared__ float tblL[256];
    int t = threadIdx.x;
    int hg = blockIdx.x, b = blockIdx.y;
    for (int i = t; i < 256; i += 256) tblL[i] = ws[OFF_TBL + i];
    const float* O = ws + OFF_O;
    float* Q = ws + OFF_PQ;
    int o = t & 63, kyg = t >> 6;
    float accr[4][8], acci[4][8];
    #pragma unroll
    for (int kk = 0; kk < 4; kk++)
        #pragma unroll
        for (int h = 0; h < 8; h++) { accr[kk][h] = 0.f; acci[kk][h] = 0.f; }
    for (int kc = 0; kc < 8; kc++) {
        __syncthreads();
        for (int idx = t; idx < 8192; idx += 256) Os[idx] = O[(long)b*65536 + kc*8192 + idx];
        __syncthreads();
        for (int k4 = 0; k4 < 4; k4++) {
            int kxI = kc*4 + k4;
            int freq = kxI < 16 ? kxI : 96 + kxI;
            float vr[4], vi[4];
            #pragma unroll
            for (int kk = 0; kk < 4; kk++) {
                int ky = kyg*4 + kk;
                vr[kk] = Os[((k4*16 + ky)*64 + o)*2];
                vi[kk] = Os[((k4*16 + ky)*64 + o)*2 + 1];
            }
            for (int h = 0; h < 8; h++) {
                int habs = hg*8 + h;
                int m = (freq * habs) & 127;
                float cs = tblL[2*m], sn = tblL[2*m + 1];
                #pragma unroll
                for (int kk = 0; kk < 4; kk++) {
                    accr[kk][h] += vr[kk]*cs - vi[kk]*sn;   // * e^{+i th}
                    acci[kk][h] += vr[kk]*sn + vi[kk]*cs;
                }
            }
        }
    }
    #pragma unroll
    for (int kk = 0; kk < 4; kk++)
        #pragma unroll
        for (int h = 0; h < 8; h++) {
            int ky = kyg*4 + kk, habs = hg*8 + h;
            float2* dst = (float2*)(Q + ((long)(b*128 + habs)*16 + ky)*128);
            dst[o] = make_float2(accr[kk][h], acci[kk][h]);
        }
}

// fused MFMA kernel: Y = M@Qm (iDFT-w), z = (Y-mu)*rho, h = GELU(z@W1+b1),
// out = h@W2+b2. G1 keeps hi/lo 3-MFMA (rho ~316 amplifies); z/W1/W2/h single bf16.
// LDS 75.3KB -> 2 blocks/CU. grid (h=128,b=16)
__global__ __launch_bounds__(256, 2) void k_mlp(const float* __restrict__ mb1,
                      const float* __restrict__ mb2,
                      float* __restrict__ out, const float* __restrict__ ws) {
    __shared__ unsigned short zhS[8192];                // z[w][64c], swz (w&7)<<4
    __shared__ unsigned short w1hS[8192];               // w1[j][64c], swz (j&7)<<4
    __shared__ unsigned short w2hS[8192];               // w2[o][128j], swz (o&15)<<4
    __shared__ unsigned short hhS[8192];                // h-half [w][64jl], swz (w&7)<<4
    __shared__ unsigned short qhS[2560], qlS[2560];     // QmT[c][40k] hi/lo
    __shared__ float muL[64], rhoL[64], b1L[128], b2L[64];
    int t = threadIdx.x;
    int h = blockIdx.x, b = blockIdx.y;
    int l = t & 63, wv = t >> 6;

    const unsigned short* xu = (const unsigned short*)(ws + OFF_X);
    const unsigned short* w1hG = xu;
    const unsigned short* w2hG = xu + 16384;
    const unsigned short* MhG  = xu + 32768, *MlG  = xu + 36864;

    // ---- stage weights into LDS (XOR swizzle), hi parts only ----
    for (int ch = t; ch < 1024; ch += 256) {       // w1: rows j, stride 128B
        int j = ch >> 3, c0 = (ch & 7) * 8;
        unsigned off = (unsigned)(j*128 + c0*2) ^ (unsigned)((j & 7) << 4);
        *(bfrag*)((char*)w1hS + off) = *(const bfrag*)(w1hG + ch*8);
    }
    for (int ch = t; ch < 1024; ch += 256) {       // w2: rows o, stride 256B
        int o = ch >> 4, j0 = (ch & 15) * 8;
        unsigned off = (unsigned)(o*256 + j0*2) ^ (unsigned)((o & 15) << 4);
        *(bfrag*)((char*)w2hS + off) = *(const bfrag*)(w2hG + ch*8);
    }
    // ---- QmT[c][k] build; lane-consecutive k -> ~2-way banks ----
    const float* Qp = ws + OFF_PQ + (long)(b*128 + h)*2048;
    for (int i = t; i < 2048; i += 256) {
        int k = i & 31, c = i >> 5;
        float v = Qp[(k >> 1)*128 + c*2 + (k & 1)];
        unsigned short hi, lo; split2(v, hi, lo);
        qhS[c*40 + k] = hi; qlS[c*40 + k] = lo;
    }
    if (t < 64) {
        float s1 = ws[OFF_S2 + (b*64+t)*2], s2 = ws[OFF_S2 + (b*64+t)*2 + 1];
        float m = s1 * (1.f/16384.f);
        float v = s2 * (1.f/16384.f) - m*m;
        muL[t] = m; rhoL[t] = rsqrtf(v + 1e-5f);
        b2L[t] = mb2[t];
    }
    if (t >= 64 && t < 192) b1L[t - 64] = mb1[t - 64];
    // M A-frags from global (rows w of this wave's two 16-row tiles)
    bfrag ma_h[2], ma_l[2];
    #pragma unroll
    for (int q = 0; q < 2; q++) {
        int w = (wv + 4*q)*16 + (l & 15);
        ma_h[q] = *(const bfrag*)(MhG + w*32 + (l >> 4)*8);
        ma_l[q] = *(const bfrag*)(MlG + w*32 + (l >> 4)*8);
    }
    __syncthreads();

    // ---- G1: Y = M @ Qm ; z = (Y - mu) * rho -> zhS (single bf16) ----
    #pragma unroll
    for (int q = 0; q < 2; q++) {
        int wt = wv + 4*q;
        #pragma unroll
        for (int ct = 0; ct < 4; ct++) {
            unsigned ro = (unsigned)((ct*16 + (l & 15))*80 + (l >> 4)*16);
            bfrag bh = *(const bfrag*)((const char*)qhS + ro);
            bfrag bl = *(const bfrag*)((const char*)qlS + ro);
            f4v acc = {0.f, 0.f, 0.f, 0.f};
            acc = MFMA(ma_h[q], bh, acc);
            acc = MFMA(ma_h[q], bl, acc);
            acc = MFMA(ma_l[q], bh, acc);
            int c = ct*16 + (l & 15);
            float mu_ = muL[c], rh_ = rhoL[c];
            #pragma unroll
            for (int r = 0; r < 4; r++) {
                int w = wt*16 + (l >> 4)*4 + r;
                float z = (acc[r] - mu_) * rh_;
                unsigned off = (unsigned)(w*128 + c*2) ^ (unsigned)((w & 7) << 4);
                *(unsigned short*)((char*)zhS + off) = f2bf_rn(z);
            }
        }
    }
    __syncthreads();

    // cache z A-frags (single, reused for both j-halves)
    bfrag za[2][2];
    #pragma unroll
    for (int q = 0; q < 2; q++) {
        int w = (wv + 4*q)*16 + (l & 15);
        #pragma unroll
        for (int ks = 0; ks < 2; ks++) {
            unsigned off = (unsigned)(w*128 + (ks*32 + (l >> 4)*8)*2) ^ (unsigned)((w & 7) << 4);
            za[q][ks] = *(const bfrag*)((const char*)zhS + off);
        }
    }
    f4v accO[2][4];
    #pragma unroll
    for (int q = 0; q < 2; q++)
        #pragma unroll
        for (int ot = 0; ot < 4; ot++) accO[q][ot] = (f4v){0.f,0.f,0.f,0.f};

    #pragma unroll
    for (int jh = 0; jh < 2; jh++) {
        // ---- G2: h-half = GELU(z @ W1[:, jh*64 .. +64) + b1) ----
        #pragma unroll
        for (int q = 0; q < 2; q++) {
            int wt = wv + 4*q;
            #pragma unroll
            for (int jt = 0; jt < 4; jt++) {
                int j = jh*64 + jt*16 + (l & 15);
                f4v acc = {0.f, 0.f, 0.f, 0.f};
                #pragma unroll
                for (int ks = 0; ks < 2; ks++) {
                    unsigned off = (unsigned)(j*128 + (ks*32 + (l >> 4)*8)*2) ^ (unsigned)((j & 7) << 4);
                    bfrag bh = *(const bfrag*)((const char*)w1hS + off);
                    acc = MFMA(za[q][ks], bh, acc);
                }
                float bj = b1L[j];
                #pragma unroll
                for (int r = 0; r < 4; r++) {
                    int w = wt*16 + (l >> 4)*4 + r;
                    float hv = gelu_t(acc[r] + bj);
                    int jl = jt*16 + (l & 15);
                    unsigned off = (unsigned)(w*128 + jl*2) ^ (unsigned)((w & 7) << 4);
                    *(unsigned short*)((char*)hhS + off) = f2bf_rn(hv);
                }
            }
        }
        __syncthreads();
        // ---- G3 partial: out += h-half @ W2[jh*64.., :] ----
        #pragma unroll
        for (int q = 0; q < 2; q++) {
            int w = (wv + 4*q)*16 + (l & 15);
            bfrag ha[2];
            #pragma unroll
            for (int ks = 0; ks < 2; ks++) {
                unsigned off = (unsigned)(w*128 + (ks*32 + (l >> 4)*8)*2) ^ (unsigned)((w & 7) << 4);
                ha[ks] = *(const bfrag*)((const char*)hhS + off);
            }
            #pragma unroll
            for (int ot = 0; ot < 4; ot++) {
                int o = ot*16 + (l & 15);
                f4v acc = accO[q][ot];
                #pragma unroll
                for (int ks = 0; ks < 2; ks++) {
                    int jj = jh*64 + ks*32 + (l >> 4)*8;
                    unsigned off = (unsigned)(o*256 + jj*2) ^ (unsigned)((o & 15) << 4);
                    bfrag bh = *(const bfrag*)((const char*)w2hS + off);
                    acc = MFMA(ha[ks], bh, acc);
                }
                accO[q][ot] = acc;
            }
        }
        __syncthreads();   // protect h buffer before next half overwrites
    }
    // ---- store out + b2 ----
    #pragma unroll
    for (int q = 0; q < 2; q++) {
        int wt = wv + 4*q;
        #pragma unroll
        for (int ot = 0; ot < 4; ot++) {
            int o = ot*16 + (l & 15);
            float bo = b2L[o];
            #pragma unroll
            for (int r = 0; r < 4; r++) {
                int w = wt*16 + (l >> 4)*4 + r;
                out[((long)(b*128 + h)*128 + w)*64 + o] = accO[q][ot][r] + bo;
            }
        }
    }
}

extern "C" void kernel_launch(void* const* d_in, const int* in_sizes, int n_in,
                              void* d_out, int out_size, void* d_ws, size_t ws_size,
                              hipStream_t stream) {
    const float* x   = (const float*)d_in[0];
    const float* w1r = (const float*)d_in[1];
    const float* w1i = (const float*)d_in[2];
    const float* w2r = (const float*)d_in[3];
    const float* w2i = (const float*)d_in[4];
    const float* mw1 = (const float*)d_in[5];
    const float* mb1 = (const float*)d_in[6];
    const float* mw2 = (const float*)d_in[7];
    const float* mb2 = (const float*)d_in[8];
    float* ws  = (float*)d_ws;
    float* out = (float*)d_out;

    k_init  <<<dim3(49),     dim3(256), 0, stream>>>(ws);
    k_stats1<<<dim3(16,16),  dim3(256), 0, stream>>>(x, ws);
    k_trans <<<dim3(64,2),   dim3(256), 0, stream>>>(w1r, w1i, w2r, w2i, ws);
    k_dftw  <<<dim3(16,16),  dim3(256), 0, stream>>>(x, ws);
    k_dfth  <<<dim3(16,16),  dim3(256), 0, stream>>>(ws);
    k_mix   <<<dim3(512),    dim3(256), 0, stream>>>(ws);
    k_wmlp  <<<dim3(80),     dim3(256), 0, stream>>>(mw1, mw2, ws);  // X dead after k_mix
    k_pstats<<<dim3(16,4),   dim3(256), 0, stream>>>(ws);
    k_idfth <<<dim3(16,16),  dim3(256), 0, stream>>>(ws);
    k_mlp   <<<dim3(128,16), dim3(256), 0, stream>>>(mb1, mb2, out, ws);
}

// Round 7
// 248.524 us; speedup vs baseline: 3.4228x; 1.0403x over previous
//
#include <hip/hip_runtime.h>
#include <math.h>

// Problem constants: B=16, H=W=128, C=64, M1=M2=16
// Workspace layout (float offsets):
#define OFF_TBL 0u            // 128 x {cos,sin}(2*pi*m/128)          (256)
#define OFF_S1  256u          // instance-norm-1 raw sums [b*64+c][2] (2048)
#define OFF_S2  2304u         // instance-norm-2 stats (s1,s2)        (2048)
#define OFF_PQ  4352u         // PT[b][(ky*64+c)*2+ri][h] u32-packed bf16 hi/lo (4194304)
                              //   aliased later with Q[b][h][ky][o][2] f32
#define OFF_X   4198656u      // X[b][kx][ky][c][2] f32               (1048576)
#define OFF_O   5247232u      // Out[b][kx][ky][o][2] f32             (1048576)
                              //   head doubles (pre-mix) as u16 trig tables:
                              //   FdAh[32][128] @0, FdAl @4096, EdAh[64][128] @8192, EdAl @16384
#define OFF_WT  6295808u      // WT[mode][i][o][2]                    (4194304)
// total = 10490112 floats = 41.96 MB
// X region is dead after k_mix -> reuse as u16 arrays for bf16-split MLP weights:
//   u16[0..8192) w1hi   [8192..16384) w1lo   [16384..24576) w2hi
//   [24576..32768) w2lo  [32768..36864) Mhi  [36864..40960) Mlo

typedef __attribute__((ext_vector_type(8))) short bfrag;
typedef __attribute__((ext_vector_type(4))) float f4v;
#define MFMA(A,B,C) __builtin_amdgcn_mfma_f32_16x16x32_bf16(A,B,C,0,0,0)

__device__ __forceinline__ unsigned short f2bf_rn(float x) {
    unsigned u = __float_as_uint(x);
    unsigned r = u + 0x7FFFu + ((u >> 16) & 1u);
    return (unsigned short)(r >> 16);
}
__device__ __forceinline__ float bf2f(unsigned short h) {
    return __uint_as_float(((unsigned)h) << 16);
}
__device__ __forceinline__ void split2(float x, unsigned short& hi, unsigned short& lo) {
    hi = f2bf_rn(x);
    lo = f2bf_rn(x - bf2f(hi));
}
// tanh-form GELU; matches exact GELU to <1e-5 for |x| <= 0.5 (our range)
__device__ __forceinline__ float gelu_t(float x) {
    float u = 0.79788456080286536f * (x + 0.044715f * x * x * x);
    float e = __expf(2.f * u);
    float th = 1.f - 2.f / (e + 1.f);
    return 0.5f * x * (1.f + th);
}

// block 0: twiddle table + zero S1/S2. blocks 1..48: bf16-split trig tables
// (F for dftw, E for dfth) into the O region (dead until k_mix overwrites).
__global__ void k_init(float* __restrict__ ws) {
    int t = threadIdx.x, bid = blockIdx.x;
    if (bid == 0) {
        if (t < 128) {
            double ang = 6.283185307179586476925286766559 * (double)t / 128.0;
            ws[OFF_TBL + 2*t]     = (float)cos(ang);
            ws[OFF_TBL + 2*t + 1] = (float)sin(ang);
        }
        for (int i = t; i < 4096; i += 256) ws[OFF_S1 + i] = 0.f;
        return;
    }
    int e = (bid - 1)*256 + t;   // 0..12287
    unsigned short* OU = (unsigned short*)(ws + OFF_O);
    const double TWO_PI = 6.283185307179586476925286766559;
    if (e < 4096) {              // FdA[row=ri*16+ky][w]: re rows cos, im rows -sin
        int row = e >> 7, w = e & 127, ky = row & 15;
        double ang = TWO_PI * (double)((ky * w) & 127) / 128.0;
        double v = (row < 16) ? cos(ang) : -sin(ang);
        unsigned short hi, lo; split2((float)v, hi, lo);
        OU[e] = hi; OU[4096 + e] = lo;
    } else {                     // EdA[row=2kx+s][h]: s=0 cos, s=1 sin (of freq f(kx))
        int e2 = e - 4096, row = e2 >> 7, h = e2 & 127;
        int kx = row >> 1, f = kx < 16 ? kx : 96 + kx;
        double ang = TWO_PI * (double)((f * h) & 127) / 128.0;
        double v = (row & 1) ? sin(ang) : cos(ang);
        unsigned short hi, lo; split2((float)v, hi, lo);
        OU[8192 + e2] = hi; OU[16384 + e2] = lo;
    }
}

// per-(b,c) sum & sumsq of x (feeds rho1 used in k_mix). grid (hg=16, b=16)
__global__ void k_stats1(const float* __restrict__ x, float* __restrict__ ws) {
    __shared__ float red[16][16][8];
    int t = threadIdx.x;
    int hg = blockIdx.x, b = blockIdx.y;
    const float4* x4 = (const float4*)x;
    int q = t & 15, pslot = t >> 4;
    float4 sum = {0,0,0,0}, sq = {0,0,0,0};
    long base = ((long)(b*128 + hg*8)*128) * 16;   // float4 index
    for (int p = pslot; p < 1024; p += 16) {
        float4 v = x4[base + (long)p*16 + q];
        sum.x += v.x; sum.y += v.y; sum.z += v.z; sum.w += v.w;
        sq.x += v.x*v.x; sq.y += v.y*v.y; sq.z += v.z*v.z; sq.w += v.w*v.w;
    }
    red[pslot][q][0]=sum.x; red[pslot][q][1]=sum.y; red[pslot][q][2]=sum.z; red[pslot][q][3]=sum.w;
    red[pslot][q][4]=sq.x;  red[pslot][q][5]=sq.y;  red[pslot][q][6]=sq.z;  red[pslot][q][7]=sq.w;
    __syncthreads();
    if (t < 64) {
        int qq = t >> 2, ci = t & 3;
        float a = 0.f, s = 0.f;
        for (int p = 0; p < 16; p++) { a += red[p][qq][ci]; s += red[p][qq][4+ci]; }
        atomicAdd(&ws[OFF_S1 + (b*64 + t)*2],     a);
        atomicAdd(&ws[OFF_S1 + (b*64 + t)*2 + 1], s);
    }
}

// weight transpose: [i][o][kx][ky] (x4 arrays) -> WT[mode][i][o][{re,im}]. grid (64=i, 2=part)
__global__ void k_trans(const float* __restrict__ w1r, const float* __restrict__ w1i,
                        const float* __restrict__ w2r, const float* __restrict__ w2i,
                        float* __restrict__ ws) {
    __shared__ float Lr[16*257], Li[16*257];
    int t = threadIdx.x;
    int i = blockIdx.x;
    int part = blockIdx.y;
    float* WT = ws + OFF_WT;
    const float* wr = part ? w2r : w1r;
    const float* wi = part ? w2i : w1i;
    for (int oc = 0; oc < 4; oc++) {
        int o0 = oc * 16;
        __syncthreads();
        for (int idx = t; idx < 4096; idx += 256) {
            int oo = idx >> 8, m = idx & 255;
            Lr[oo*257 + m] = wr[(i*64 + o0 + oo)*256 + m];
            Li[oo*257 + m] = wi[(i*64 + o0 + oo)*256 + m];
        }
        __syncthreads();
        for (int idx = t; idx < 8192; idx += 256) {
            int mode = idx >> 5, rem = idx & 31, oo = rem >> 1, ri = rem & 1;
            float val = ri ? Li[oo*257 + mode] : Lr[oo*257 + mode];
            int gm = part*256 + mode;
            WT[((gm*64 + i)*64 + (o0 + oo))*2 + ri] = val;
        }
    }
}

// bf16-split MLP weights + iDFT-w matrix M into the dead X region. grid 80
__global__ void k_wmlp(const float* __restrict__ mw1, const float* __restrict__ mw2,
                       float* __restrict__ ws) {
    int i = blockIdx.x * 256 + threadIdx.x;   // [0, 20480)
    unsigned short* xu = (unsigned short*)(ws + OFF_X);
    if (i < 8192) {
        unsigned short hi, lo; split2(mw1[i], hi, lo);
        xu[i] = hi; xu[8192 + i] = lo;
    } else if (i < 16384) {
        int k = i - 8192;
        unsigned short hi, lo; split2(mw2[k], hi, lo);
        xu[16384 + k] = hi; xu[24576 + k] = lo;
    } else if (i < 20480) {
        int m = i - 16384;           // w*32 + k
        int w = m >> 5, k = m & 31;
        int ky = k >> 1;
        double ang = 6.283185307179586476925286766559 * (double)((ky * w) & 127) / 128.0;
        double v = (k & 1) ? -sin(ang) : cos(ang);
        double a = (ky == 0) ? 1.0 : 2.0;
        float val = (float)(v * a) * (1.f/16384.f);
        unsigned short hi, lo; split2(val, hi, lo);
        xu[32768 + m] = hi; xu[36864 + m] = lo;
    }
}

// MFMA forward DFT along w on RAW x (norm deferred to k_mix).
// grid (cg=16, hq=4, b=16): block owns 4 c (c0=cg*4), 32 h (h0=hq*32).
// Wave wv owns 8 h -- wave-private staging, barrier only before global write.
// Output PT[b][(ky*64+c)*2+ri][h] u32-packed bf16 hi/lo (layout unchanged).
__global__ __launch_bounds__(256) void k_dftw(const float* __restrict__ x, float* __restrict__ ws) {
    __shared__ unsigned BTall[4096];    // 16KB: per-wave 4KB {BTh 2KB | BTl 2KB}, reused as trans
    int t = threadIdx.x;
    int cg = blockIdx.x, hq = blockIdx.y, b = blockIdx.z;
    int c0 = cg*4;
    int l = t & 63, wv = t >> 6;
    char* wbase = (char*)BTall + wv*4096;

    const unsigned short* OU = (const unsigned short*)(ws + OFF_O);
    const unsigned short* FdAh = OU, *FdAl = OU + 4096;

    // A-frags: FdA rows (mt*16 + lane&15), k = kc*32 + oct*8
    bfrag ma_h[2][4], ma_l[2][4];
    #pragma unroll
    for (int mt = 0; mt < 2; mt++)
        #pragma unroll
        for (int kc = 0; kc < 4; kc++) {
            int off = (mt*16 + (l & 15))*128 + kc*32 + (l >> 4)*8;
            ma_h[mt][kc] = *(const bfrag*)(FdAh + off);
            ma_l[mt][kc] = *(const bfrag*)(FdAl + off);
        }
    f4v acc[2][2];
    #pragma unroll
    for (int mt = 0; mt < 2; mt++)
        #pragma unroll
        for (int nt = 0; nt < 2; nt++) acc[mt][nt] = (f4v){0.f,0.f,0.f,0.f};

    const float* xb = x + ((long)(b*128 + hq*32 + wv*8))*8192 + c0;   // h stride 8192 floats
    #pragma unroll
    for (int kc = 0; kc < 4; kc++) {
        // ---- stage: x[h=..+hl][w=kc*32+2wp(+1)][c0..c0+3] -> BT[lc=cj*8+hl][w-pairs] ----
        #pragma unroll
        for (int it = 0; it < 2; it++) {
            int p = it*64 + l;
            int wp = p & 15, hl = p >> 4;     // hl in 0..7
            const float* src = xb + (long)hl*8192 + (kc*32 + wp*2)*64;
            float4 a = *(const float4*)src;
            float4 bb = *(const float4*)(src + 64);
            #pragma unroll
            for (int cj = 0; cj < 4; cj++) {
                float va = ((const float*)&a)[cj], vb = ((const float*)&bb)[cj];
                unsigned short ah, al2, bh2, bl2;
                split2(va, ah, al2); split2(vb, bh2, bl2);
                unsigned hp = (unsigned)ah | ((unsigned)bh2 << 16);
                unsigned lp = (unsigned)al2 | ((unsigned)bl2 << 16);
                int lc = cj*8 + hl;
                unsigned bad = (unsigned)(lc*64 + ((wp*4) ^ ((lc & 3) << 4)));
                *(unsigned*)(wbase + bad) = hp;
                *(unsigned*)(wbase + 2048 + bad) = lp;
            }
        }
        // ---- MFMA: 2 Ntiles x 2 Mtiles, 3-term hi/lo ----
        #pragma unroll
        for (int nt = 0; nt < 2; nt++) {
            int lc = nt*16 + (l & 15);
            unsigned ro = (unsigned)(lc*64 + (((l >> 4)*16) ^ ((lc & 3) << 4)));
            bfrag bh = *(const bfrag*)(wbase + ro);
            bfrag bl = *(const bfrag*)(wbase + 2048 + ro);
            #pragma unroll
            for (int mt = 0; mt < 2; mt++) {
                f4v a_ = acc[mt][nt];
                a_ = MFMA(ma_h[mt][kc], bh, a_);
                a_ = MFMA(ma_h[mt][kc], bl, a_);
                a_ = MFMA(ma_l[mt][kc], bh, a_);
                acc[mt][nt] = a_;
            }
        }
    }
    // ---- epilogue: split-pack -> wave trans buf [trow=ri*16+ky][lc 32] u32 ----
    #pragma unroll
    for (int mt = 0; mt < 2; mt++)
        #pragma unroll
        for (int nt = 0; nt < 2; nt++)
            #pragma unroll
            for (int r = 0; r < 4; r++) {
                float v = acc[mt][nt][r];
                unsigned short hi, lo; split2(v, hi, lo);
                int trow = mt*16 + (l >> 4)*4 + r;
                int lc = nt*16 + (l & 15);
                unsigned ad = (unsigned)(trow*128 + ((lc*4) ^ ((trow & 7) << 4)));
                *(unsigned*)(wbase + ad) = ((unsigned)hi << 16) | (unsigned)lo;
            }
    __syncthreads();
    // ---- coalesced global write: 8 lanes cover one row's 128B h-segment ----
    unsigned* PT = (unsigned*)(ws + OFF_PQ);
    int hpart = t & 7, rowi = t >> 3;    // 32 rows per pass, 4 passes
    #pragma unroll
    for (int ps = 0; ps < 4; ps++) {
        int row = ps*32 + rowi;          // row = ky*8 + cj*2 + ri
        int ri = row & 1, cj = (row >> 1) & 3, ky = row >> 3;
        int trow = ri*16 + ky;
        int wvp = hpart >> 1;
        int lc0 = cj*8 + (hpart & 1)*4;
        unsigned ad = (unsigned)(wvp*4096 + trow*128 + ((lc0*4) ^ ((trow & 7) << 4)));
        uint4 vz = *(const uint4*)((const char*)BTall + ad);
        long grow = ((long)(ky*64 + c0 + cj))*2 + ri;
        *(uint4*)(PT + (((long)b*2048 + grow) << 7) + hq*32 + hpart*4) = vz;
    }
}

// MFMA forward DFT along h: X[2kx+s][(c,ri)] = EdA @ PT (per ky,b).
// Complex combine: Xr = G[2kx][colr]+G[2kx+1][coli], Xi = G[2kx][coli]-G[2kx+1][colr]
// via shfl_xor(1). grid (ky=16, b=16); wave wv = Mtile wv. X stays f32 legacy layout.
__global__ __launch_bounds__(256) void k_dfth(float* __restrict__ ws) {
    __shared__ unsigned Bsh[16384];   // BTh 32KB (128 cols x 256B) | BTl 32KB
    int t = threadIdx.x;
    int ky = blockIdx.x, b = blockIdx.y;
    int l = t & 63, wv = t >> 6;
    char* bh_base = (char*)Bsh;
    char* bl_base = bh_base + 32768;
    const unsigned* PT = (const unsigned*)(ws + OFF_PQ);
    const unsigned short* OU = (const unsigned short*)(ws + OFF_O);
    const unsigned short* EdAh = OU + 8192, *EdAl = OU + 16384;

    // ---- stage PT rows (col n = c*2+ri of this ky) -> BT[n][128 kk] hi/lo ----
    {
        int n = t >> 1, hh = (t & 1)*64;
        const uint4* src = (const uint4*)(PT + ((long)b*2048 + ky*128 + n)*128 + hh);
        #pragma unroll
        for (int jj = 0; jj < 16; jj++) {
            uint4 v = src[jj];
            unsigned h01 = (v.x >> 16) | (v.y & 0xFFFF0000u);
            unsigned h23 = (v.z >> 16) | (v.w & 0xFFFF0000u);
            unsigned l01 = (v.x & 0xFFFFu) | (v.y << 16);
            unsigned l23 = (v.z & 0xFFFFu) | (v.w << 16);
            int kk = hh + jj*4;
            unsigned ad = (unsigned)(n*256 + ((kk*2) ^ ((n & 7) << 4)));
            *(uint2*)(bh_base + ad) = make_uint2(h01, h23);
            *(uint2*)(bl_base + ad) = make_uint2(l01, l23);
        }
    }
    // A-frags for this wave's Mtile
    bfrag ea_h[4], ea_l[4];
    #pragma unroll
    for (int kc = 0; kc < 4; kc++) {
        int off = (wv*16 + (l & 15))*128 + kc*32 + (l >> 4)*8;
        ea_h[kc] = *(const bfrag*)(EdAh + off);
        ea_l[kc] = *(const bfrag*)(EdAl + off);
    }
    __syncthreads();
    f4v acc[8];
    #pragma unroll
    for (int nt = 0; nt < 8; nt++) acc[nt] = (f4v){0.f,0.f,0.f,0.f};
    #pragma unroll
    for (int kc = 0; kc < 4; kc++)
        #pragma unroll
        for (int nt = 0; nt < 8; nt++) {
            int col = nt*16 + (l & 15);
            unsigned ro = (unsigned)(col*256 + ((kc*64 + (l >> 4)*16) ^ ((col & 7) << 4)));
            bfrag bh = *(const bfrag*)(bh_base + ro);
            bfrag bl = *(const bfrag*)(bl_base + ro);
            acc[nt] = MFMA(ea_h[kc], bh, acc[nt]);
            acc[nt] = MFMA(ea_h[kc], bl, acc[nt]);
            acc[nt] = MFMA(ea_l[kc], bh, acc[nt]);
        }
    // ---- epilogue: complex combine + store X (f32, legacy layout) ----
    float* X = ws + OFF_X;
    #pragma unroll
    for (int nt = 0; nt < 8; nt++)
        #pragma unroll
        for (int p = 0; p < 2; p++) {
            float s0 = acc[nt][2*p], s1 = acc[nt][2*p + 1];
            float partner = __shfl_xor(s1, 1, 64);
            float res = (l & 1) ? (s0 - partner) : (s0 + partner);
            int kx = wv*8 + (l >> 4)*2 + p;
            X[(((long)b*32 + kx)*16 + ky)*128 + nt*16 + (l & 15)] = res;
        }
}

// per-mode complex mix with rho1 scaling folded into X staging. grid 512 (=mode)
__global__ void k_mix(float* __restrict__ ws) {
    __shared__ float Wsh[8192];
    __shared__ float Xs[2048];
    __shared__ float rhoT[1024];
    int t = threadIdx.x;
    int mode = blockIdx.x;
    int kxI = mode >> 4, ky = mode & 15;
    const float* WT = ws + OFF_WT;
    const float* X = ws + OFF_X;
    float* O = ws + OFF_O;
    for (int i = t; i < 1024; i += 256) {
        float a = ws[OFF_S1 + 2*i], s = ws[OFF_S1 + 2*i + 1];
        float m = a * (1.f/16384.f);
        float v = s * (1.f/16384.f) - m*m;
        rhoT[i] = rsqrtf(v + 1e-5f);
    }
    for (int idx = t; idx < 8192; idx += 256) Wsh[idx] = WT[(long)mode*8192 + idx];
    __syncthreads();
    for (int idx = t; idx < 2048; idx += 256) {
        int b = idx >> 7, r = idx & 127;
        Xs[idx] = X[((b*32 + kxI)*16 + ky)*128 + r] * rhoT[b*64 + (r >> 1)];
    }
    __syncthreads();
    int o = t & 63, bg = t >> 6;
    float accr[4] = {0,0,0,0}, acci[4] = {0,0,0,0};
    for (int i = 0; i < 64; i++) {
        float wr = Wsh[(i*64 + o)*2], wi = Wsh[(i*64 + o)*2 + 1];
        #pragma unroll
        for (int j = 0; j < 4; j++) {
            float xr = Xs[(bg*4 + j)*128 + 2*i], xi = Xs[(bg*4 + j)*128 + 2*i + 1];
            accr[j] += xr*wr - xi*wi;
            acci[j] += xr*wi + xi*wr;
        }
    }
    #pragma unroll
    for (int j = 0; j < 4; j++) {
        int b = bg*4 + j;
        float2* dst = (float2*)(O + ((b*32 + kxI)*16 + ky)*128);
        dst[o] = make_float2(accr[j], acci[j]);
    }
}

// Parseval stats of y directly from O. grid (16=b, 4=gg), 256 thr.
__global__ void k_pstats(float* __restrict__ ws) {
    __shared__ float red[256];
    int t = threadIdx.x, b = blockIdx.x, gg = blockIdx.y;
    int c = t & 63, g = t >> 6;
    const float* O = ws + OFF_O + (long)b*65536;   // [(kxI*16+ky)*128 + 2c]
    float t0 = 0.f, t2 = 0.f;
    int k0 = gg*8 + g*2;
    for (int kxI = k0; kxI < k0 + 2; kxI++)
        for (int ky = 0; ky < 16; ky++) {
            float re = O[(kxI*16 + ky)*128 + 2*c];
            float im = O[(kxI*16 + ky)*128 + 2*c + 1];
            float p = re*re + im*im;
            if (ky == 0) t0 += p; else t2 += p;
        }
    float s2p = 0.5f*t0 + 2.f*t2;
    if (gg == 0 && g == 0) {
        float ar = O[2*c], ai = O[2*c + 1];        // kxI=0, ky=0
        float t1 = ar*ar - ai*ai;
        for (int k = 1; k <= 15; k++) {
            float xr = O[(k*16)*128 + 2*c],        xi = O[(k*16)*128 + 2*c + 1];
            float yr = O[((32-k)*16)*128 + 2*c],   yi = O[((32-k)*16)*128 + 2*c + 1];
            t1 += 2.f*(xr*yr - xi*yi);
        }
        s2p += 0.5f*t1;
        ws[OFF_S2 + (b*64 + c)*2] = ar;            // s1 (mean term)
    }
    red[t] = s2p;
    __syncthreads();
    if (t < 64) {
        float s = red[t] + red[t+64] + red[t+128] + red[t+192];
        atomicAdd(&ws[OFF_S2 + (b*64 + t)*2 + 1], s * (1.f/16384.f));
    }
}

// inverse DFT along h: Q[b][h][ky][o] = sum_kx Out e^{+i 2pi f(kx) h/128}. grid (hg=16,b=16)
__global__ void k_idfth(float* __restrict__ ws) {
    __shared__ float Os[8192];
    __shared__ float tblL[256];
    int t = threadIdx.x;
    int hg = blockIdx.x, b = blockIdx.y;
    for (int i = t; i < 256; i += 256) tblL[i] = ws[OFF_TBL + i];
    const float* O = ws + OFF_O;
    float* Q = ws + OFF_PQ;
    int o = t & 63, kyg = t >> 6;
    float accr[4][8], acci[4][8];
    #pragma unroll
    for (int kk = 0; kk < 4; kk++)
        #pragma unroll
        for (int h = 0; h < 8; h++) { accr[kk][h] = 0.f; acci[kk][h] = 0.f; }
    for (int kc = 0; kc < 8; kc++) {
        __syncthreads();
        for (int idx = t; idx < 8192; idx += 256) Os[idx] = O[(long)b*65536 + kc*8192 + idx];
        __syncthreads();
        for (int k4 = 0; k4 < 4; k4++) {
            int kxI = kc*4 + k4;
            int freq = kxI < 16 ? kxI : 96 + kxI;
            float vr[4], vi[4];
            #pragma unroll
            for (int kk = 0; kk < 4; kk++) {
                int ky = kyg*4 + kk;
                vr[kk] = Os[((k4*16 + ky)*64 + o)*2];
                vi[kk] = Os[((k4*16 + ky)*64 + o)*2 + 1];
            }
            for (int h = 0; h < 8; h++) {
                int habs = hg*8 + h;
                int m = (freq * habs) & 127;
                float cs = tblL[2*m], sn = tblL[2*m + 1];
                #pragma unroll
                for (int kk = 0; kk < 4; kk++) {
                    accr[kk][h] += vr[kk]*cs - vi[kk]*sn;   // * e^{+i th}
                    acci[kk][h] += vr[kk]*sn + vi[kk]*cs;
                }
            }
        }
    }
    #pragma unroll
    for (int kk = 0; kk < 4; kk++)
        #pragma unroll
        for (int h = 0; h < 8; h++) {
            int ky = kyg*4 + kk, habs = hg*8 + h;
            float2* dst = (float2*)(Q + ((long)(b*128 + habs)*16 + ky)*128);
            dst[o] = make_float2(accr[kk][h], acci[kk][h]);
        }
}

// fused MFMA kernel: Y = M@Qm (iDFT-w), z = (Y-mu)*rho, h = GELU(z@W1+b1),
// out = h@W2+b2. G1 keeps hi/lo 3-MFMA (rho ~316 amplifies); z/W1/W2/h single bf16.
// LDS 75.3KB -> 2 blocks/CU. grid (h=128,b=16)
__global__ __launch_bounds__(256, 2) void k_mlp(const float* __restrict__ mb1,
                      const float* __restrict__ mb2,
                      float* __restrict__ out, const float* __restrict__ ws) {
    __shared__ unsigned short zhS[8192];                // z[w][64c], swz (w&7)<<4
    __shared__ unsigned short w1hS[8192];               // w1[j][64c], swz (j&7)<<4
    __shared__ unsigned short w2hS[8192];               // w2[o][128j], swz (o&15)<<4
    __shared__ unsigned short hhS[8192];                // h-half [w][64jl], swz (w&7)<<4
    __shared__ unsigned short qhS[2560], qlS[2560];     // QmT[c][40k] hi/lo
    __shared__ float muL[64], rhoL[64], b1L[128], b2L[64];
    int t = threadIdx.x;
    int h = blockIdx.x, b = blockIdx.y;
    int l = t & 63, wv = t >> 6;

    const unsigned short* xu = (const unsigned short*)(ws + OFF_X);
    const unsigned short* w1hG = xu;
    const unsigned short* w2hG = xu + 16384;
    const unsigned short* MhG  = xu + 32768, *MlG  = xu + 36864;

    // ---- stage weights into LDS (XOR swizzle), hi parts only ----
    for (int ch = t; ch < 1024; ch += 256) {       // w1: rows j, stride 128B
        int j = ch >> 3, c0 = (ch & 7) * 8;
        unsigned off = (unsigned)(j*128 + c0*2) ^ (unsigned)((j & 7) << 4);
        *(bfrag*)((char*)w1hS + off) = *(const bfrag*)(w1hG + ch*8);
    }
    for (int ch = t; ch < 1024; ch += 256) {       // w2: rows o, stride 256B
        int o = ch >> 4, j0 = (ch & 15) * 8;
        unsigned off = (unsigned)(o*256 + j0*2) ^ (unsigned)((o & 15) << 4);
        *(bfrag*)((char*)w2hS + off) = *(const bfrag*)(w2hG + ch*8);
    }
    // ---- QmT[c][k] build; lane-consecutive k -> ~2-way banks ----
    const float* Qp = ws + OFF_PQ + (long)(b*128 + h)*2048;
    for (int i = t; i < 2048; i += 256) {
        int k = i & 31, c = i >> 5;
        float v = Qp[(k >> 1)*128 + c*2 + (k & 1)];
        unsigned short hi, lo; split2(v, hi, lo);
        qhS[c*40 + k] = hi; qlS[c*40 + k] = lo;
    }
    if (t < 64) {
        float s1 = ws[OFF_S2 + (b*64+t)*2], s2 = ws[OFF_S2 + (b*64+t)*2 + 1];
        float m = s1 * (1.f/16384.f);
        float v = s2 * (1.f/16384.f) - m*m;
        muL[t] = m; rhoL[t] = rsqrtf(v + 1e-5f);
        b2L[t] = mb2[t];
    }
    if (t >= 64 && t < 192) b1L[t - 64] = mb1[t - 64];
    // M A-frags from global (rows w of this wave's two 16-row tiles)
    bfrag ma_h[2], ma_l[2];
    #pragma unroll
    for (int q = 0; q < 2; q++) {
        int w = (wv + 4*q)*16 + (l & 15);
        ma_h[q] = *(const bfrag*)(MhG + w*32 + (l >> 4)*8);
        ma_l[q] = *(const bfrag*)(MlG + w*32 + (l >> 4)*8);
    }
    __syncthreads();

    // ---- G1: Y = M @ Qm ; z = (Y - mu) * rho -> zhS (single bf16) ----
    #pragma unroll
    for (int q = 0; q < 2; q++) {
        int wt = wv + 4*q;
        #pragma unroll
        for (int ct = 0; ct < 4; ct++) {
            unsigned ro = (unsigned)((ct*16 + (l & 15))*80 + (l >> 4)*16);
            bfrag bh = *(const bfrag*)((const char*)qhS + ro);
            bfrag bl = *(const bfrag*)((const char*)qlS + ro);
            f4v acc = {0.f, 0.f, 0.f, 0.f};
            acc = MFMA(ma_h[q], bh, acc);
            acc = MFMA(ma_h[q], bl, acc);
            acc = MFMA(ma_l[q], bh, acc);
            int c = ct*16 + (l & 15);
            float mu_ = muL[c], rh_ = rhoL[c];
            #pragma unroll
            for (int r = 0; r < 4; r++) {
                int w = wt*16 + (l >> 4)*4 + r;
                float z = (acc[r] - mu_) * rh_;
                unsigned off = (unsigned)(w*128 + c*2) ^ (unsigned)((w & 7) << 4);
                *(unsigned short*)((char*)zhS + off) = f2bf_rn(z);
            }
        }
    }
    __syncthreads();

    // cache z A-frags (single, reused for both j-halves)
    bfrag za[2][2];
    #pragma unroll
    for (int q = 0; q < 2; q++) {
        int w = (wv + 4*q)*16 + (l & 15);
        #pragma unroll
        for (int ks = 0; ks < 2; ks++) {
            unsigned off = (unsigned)(w*128 + (ks*32 + (l >> 4)*8)*2) ^ (unsigned)((w & 7) << 4);
            za[q][ks] = *(const bfrag*)((const char*)zhS + off);
        }
    }
    f4v accO[2][4];
    #pragma unroll
    for (int q = 0; q < 2; q++)
        #pragma unroll
        for (int ot = 0; ot < 4; ot++) accO[q][ot] = (f4v){0.f,0.f,0.f,0.f};

    #pragma unroll
    for (int jh = 0; jh < 2; jh++) {
        // ---- G2: h-half = GELU(z @ W1[:, jh*64 .. +64) + b1) ----
        #pragma unroll
        for (int q = 0; q < 2; q++) {
            int wt = wv + 4*q;
            #pragma unroll
            for (int jt = 0; jt < 4; jt++) {
                int j = jh*64 + jt*16 + (l & 15);
                f4v acc = {0.f, 0.f, 0.f, 0.f};
                #pragma unroll
                for (int ks = 0; ks < 2; ks++) {
                    unsigned off = (unsigned)(j*128 + (ks*32 + (l >> 4)*8)*2) ^ (unsigned)((j & 7) << 4);
                    bfrag bh = *(const bfrag*)((const char*)w1hS + off);
                    acc = MFMA(za[q][ks], bh, acc);
                }
                float bj = b1L[j];
                #pragma unroll
                for (int r = 0; r < 4; r++) {
                    int w = wt*16 + (l >> 4)*4 + r;
                    float hv = gelu_t(acc[r] + bj);
                    int jl = jt*16 + (l & 15);
                    unsigned off = (unsigned)(w*128 + jl*2) ^ (unsigned)((w & 7) << 4);
                    *(unsigned short*)((char*)hhS + off) = f2bf_rn(hv);
                }
            }
        }
        __syncthreads();
        // ---- G3 partial: out += h-half @ W2[jh*64.., :] ----
        #pragma unroll
        for (int q = 0; q < 2; q++) {
            int w = (wv + 4*q)*16 + (l & 15);
            bfrag ha[2];
            #pragma unroll
            for (int ks = 0; ks < 2; ks++) {
                unsigned off = (unsigned)(w*128 + (ks*32 + (l >> 4)*8)*2) ^ (unsigned)((w & 7) << 4);
                ha[ks] = *(const bfrag*)((const char*)hhS + off);
            }
            #pragma unroll
            for (int ot = 0; ot < 4; ot++) {
                int o = ot*16 + (l & 15);
                f4v acc = accO[q][ot];
                #pragma unroll
                for (int ks = 0; ks < 2; ks++) {
                    int jj = jh*64 + ks*32 + (l >> 4)*8;
                    unsigned off = (unsigned)(o*256 + jj*2) ^ (unsigned)((o & 15) << 4);
                    bfrag bh = *(const bfrag*)((const char*)w2hS + off);
                    acc = MFMA(ha[ks], bh, acc);
                }
                accO[q][ot] = acc;
            }
        }
        __syncthreads();   // protect h buffer before next half overwrites
    }
    // ---- store out + b2 ----
    #pragma unroll
    for (int q = 0; q < 2; q++) {
        int wt = wv + 4*q;
        #pragma unroll
        for (int ot = 0; ot < 4; ot++) {
            int o = ot*16 + (l & 15);
            float bo = b2L[o];
            #pragma unroll
            for (int r = 0; r < 4; r++) {
                int w = wt*16 + (l >> 4)*4 + r;
                out[((long)(b*128 + h)*128 + w)*64 + o] = accO[q][ot][r] + bo;
            }
        }
    }
}

extern "C" void kernel_launch(void* const* d_in, const int* in_sizes, int n_in,
                              void* d_out, int out_size, void* d_ws, size_t ws_size,
                              hipStream_t stream) {
    const float* x   = (const float*)d_in[0];
    const float* w1r = (const float*)d_in[1];
    const float* w1i = (const float*)d_in[2];
    const float* w2r = (const float*)d_in[3];
    const float* w2i = (const float*)d_in[4];
    const float* mw1 = (const float*)d_in[5];
    const float* mb1 = (const float*)d_in[6];
    const float* mw2 = (const float*)d_in[7];
    const float* mb2 = (const float*)d_in[8];
    float* ws  = (float*)d_ws;
    float* out = (float*)d_out;

    k_init  <<<dim3(49),      dim3(256), 0, stream>>>(ws);
    k_stats1<<<dim3(16,16),   dim3(256), 0, stream>>>(x, ws);
    k_trans <<<dim3(64,2),    dim3(256), 0, stream>>>(w1r, w1i, w2r, w2i, ws);
    k_dftw  <<<dim3(16,4,16), dim3(256), 0, stream>>>(x, ws);
    k_dfth  <<<dim3(16,16),   dim3(256), 0, stream>>>(ws);
    k_mix   <<<dim3(512),     dim3(256), 0, stream>>>(ws);
    k_wmlp  <<<dim3(80),      dim3(256), 0, stream>>>(mw1, mw2, ws);  // X dead after k_mix
    k_pstats<<<dim3(16,4),    dim3(256), 0, stream>>>(ws);
    k_idfth <<<dim3(16,16),   dim3(256), 0, stream>>>(ws);
    k_mlp   <<<dim3(128,16),  dim3(256), 0, stream>>>(mb1, mb2, out, ws);
}

// Round 8
// 213.536 us; speedup vs baseline: 3.9836x; 1.1638x over previous
//
#include <hip/hip_runtime.h>
#include <math.h>

// Problem constants: B=16, H=W=128, C=64, M1=M2=16
// Workspace layout (float offsets):
#define OFF_TBL 0u            // 128 x {cos,sin}(2*pi*m/128)          (256)
#define OFF_S1  256u          // instance-norm-1 raw sums [b*64+c][2] (2048)
#define OFF_S2  2304u         // instance-norm-2 stats (s1,s2)        (2048)
#define OFF_PQ  4352u         // PT[b][(ky*64+c)*2+ri][h] u32-packed bf16 hi/lo (4194304)
                              //   aliased later with Q[b][h][ky][o][2] f32
#define OFF_X   4198656u      // X[b][kx][ky][c][2] f32               (1048576)
#define OFF_O   5247232u      // Out[b][kx][ky][o][2] f32             (1048576)
                              //   head doubles (pre-mix) as u16 trig tables:
                              //   FdAh[32][128] @0, FdAl @4096, EdAh[64][128] @8192, EdAl @16384
#define OFF_WT  6295808u      // WT[mode][i][o][2]                    (4194304)
// total = 10490112 floats = 41.96 MB
// X region is dead after k_mix -> reuse as u16 arrays for bf16-split MLP weights:
//   u16[0..8192) w1hi   [8192..16384) w1lo   [16384..24576) w2hi
//   [24576..32768) w2lo  [32768..36864) Mhi  [36864..40960) Mlo

typedef __attribute__((ext_vector_type(8))) short bfrag;
typedef __attribute__((ext_vector_type(4))) float f4v;
#define MFMA(A,B,C) __builtin_amdgcn_mfma_f32_16x16x32_bf16(A,B,C,0,0,0)

__device__ __forceinline__ unsigned short f2bf_rn(float x) {
    unsigned u = __float_as_uint(x);
    unsigned r = u + 0x7FFFu + ((u >> 16) & 1u);
    return (unsigned short)(r >> 16);
}
__device__ __forceinline__ float bf2f(unsigned short h) {
    return __uint_as_float(((unsigned)h) << 16);
}
__device__ __forceinline__ void split2(float x, unsigned short& hi, unsigned short& lo) {
    hi = f2bf_rn(x);
    lo = f2bf_rn(x - bf2f(hi));
}
// tanh-form GELU; matches exact GELU to <1e-5 for |x| <= 0.5 (our range)
__device__ __forceinline__ float gelu_t(float x) {
    float u = 0.79788456080286536f * (x + 0.044715f * x * x * x);
    float e = __expf(2.f * u);
    float th = 1.f - 2.f / (e + 1.f);
    return 0.5f * x * (1.f + th);
}

// block 0: twiddle table + zero S1/S2. blocks 1..48: bf16-split trig tables
// (F for dftw, E for dfth) into the O region (dead until k_mix overwrites).
__global__ void k_init(float* __restrict__ ws) {
    int t = threadIdx.x, bid = blockIdx.x;
    if (bid == 0) {
        if (t < 128) {
            double ang = 6.283185307179586476925286766559 * (double)t / 128.0;
            ws[OFF_TBL + 2*t]     = (float)cos(ang);
            ws[OFF_TBL + 2*t + 1] = (float)sin(ang);
        }
        for (int i = t; i < 4096; i += 256) ws[OFF_S1 + i] = 0.f;
        return;
    }
    int e = (bid - 1)*256 + t;   // 0..12287
    unsigned short* OU = (unsigned short*)(ws + OFF_O);
    const double TWO_PI = 6.283185307179586476925286766559;
    if (e < 4096) {              // FdA[row=ri*16+ky][w]: re rows cos, im rows -sin
        int row = e >> 7, w = e & 127, ky = row & 15;
        double ang = TWO_PI * (double)((ky * w) & 127) / 128.0;
        double v = (row < 16) ? cos(ang) : -sin(ang);
        unsigned short hi, lo; split2((float)v, hi, lo);
        OU[e] = hi; OU[4096 + e] = lo;
    } else {                     // EdA[row=2kx+s][h]: s=0 cos, s=1 sin (of freq f(kx))
        int e2 = e - 4096, row = e2 >> 7, h = e2 & 127;
        int kx = row >> 1, f = kx < 16 ? kx : 96 + kx;
        double ang = TWO_PI * (double)((f * h) & 127) / 128.0;
        double v = (row & 1) ? sin(ang) : cos(ang);
        unsigned short hi, lo; split2((float)v, hi, lo);
        OU[8192 + e2] = hi; OU[16384 + e2] = lo;
    }
}

// weight transpose: [i][o][kx][ky] (x4 arrays) -> WT[mode][i][o][{re,im}]. grid (64=i, 2=part)
__global__ void k_trans(const float* __restrict__ w1r, const float* __restrict__ w1i,
                        const float* __restrict__ w2r, const float* __restrict__ w2i,
                        float* __restrict__ ws) {
    __shared__ float Lr[16*257], Li[16*257];
    int t = threadIdx.x;
    int i = blockIdx.x;
    int part = blockIdx.y;
    float* WT = ws + OFF_WT;
    const float* wr = part ? w2r : w1r;
    const float* wi = part ? w2i : w1i;
    for (int oc = 0; oc < 4; oc++) {
        int o0 = oc * 16;
        __syncthreads();
        for (int idx = t; idx < 4096; idx += 256) {
            int oo = idx >> 8, m = idx & 255;
            Lr[oo*257 + m] = wr[(i*64 + o0 + oo)*256 + m];
            Li[oo*257 + m] = wi[(i*64 + o0 + oo)*256 + m];
        }
        __syncthreads();
        for (int idx = t; idx < 8192; idx += 256) {
            int mode = idx >> 5, rem = idx & 31, oo = rem >> 1, ri = rem & 1;
            float val = ri ? Li[oo*257 + mode] : Lr[oo*257 + mode];
            int gm = part*256 + mode;
            WT[((gm*64 + i)*64 + (o0 + oo))*2 + ri] = val;
        }
    }
}

// bf16-split MLP weights + iDFT-w matrix M into the dead X region. grid 80
__global__ void k_wmlp(const float* __restrict__ mw1, const float* __restrict__ mw2,
                       float* __restrict__ ws) {
    int i = blockIdx.x * 256 + threadIdx.x;   // [0, 20480)
    unsigned short* xu = (unsigned short*)(ws + OFF_X);
    if (i < 8192) {
        unsigned short hi, lo; split2(mw1[i], hi, lo);
        xu[i] = hi; xu[8192 + i] = lo;
    } else if (i < 16384) {
        int k = i - 8192;
        unsigned short hi, lo; split2(mw2[k], hi, lo);
        xu[16384 + k] = hi; xu[24576 + k] = lo;
    } else if (i < 20480) {
        int m = i - 16384;           // w*32 + k
        int w = m >> 5, k = m & 31;
        int ky = k >> 1;
        double ang = 6.283185307179586476925286766559 * (double)((ky * w) & 127) / 128.0;
        double v = (k & 1) ? -sin(ang) : cos(ang);
        double a = (ky == 0) ? 1.0 : 2.0;
        float val = (float)(v * a) * (1.f/16384.f);
        unsigned short hi, lo; split2(val, hi, lo);
        xu[32768 + m] = hi; xu[36864 + m] = lo;
    }
}

// MFMA forward DFT along w on RAW x, sector-dense reads (block owns ALL 64 c),
// with instance-norm-1 stats folded into the staging pass (k_stats1 deleted).
// grid (hq=32, b=16): block = 4 h (wave wv owns h = hq*4+wv), 64 c.
// Wave-private staging; barrier only before the cross-wave PT write.
// Output PT[b][(ky*64+c)*2+ri][h] u32-packed bf16 hi/lo (layout unchanged).
__global__ __launch_bounds__(256) void k_dftw(const float* __restrict__ x, float* __restrict__ ws) {
    __shared__ unsigned BTall[8192];    // 32KB: per-wave 8KB {BTh 4KB | BTl 4KB}; reused as trans
    int t = threadIdx.x;
    int hq = blockIdx.x, b = blockIdx.y;
    int l = t & 63, wv = t >> 6;
    int h = hq*4 + wv;
    char* wbase = (char*)BTall + wv*8192;

    const unsigned short* OU = (const unsigned short*)(ws + OFF_O);
    const unsigned short* FdAh = OU, *FdAl = OU + 4096;

    // A-frags: FdA rows (mt*16 + lane&15), k = kc*32 + oct*8
    bfrag ma_h[2][4], ma_l[2][4];
    #pragma unroll
    for (int mt = 0; mt < 2; mt++)
        #pragma unroll
        for (int kc = 0; kc < 4; kc++) {
            int off = (mt*16 + (l & 15))*128 + kc*32 + (l >> 4)*8;
            ma_h[mt][kc] = *(const bfrag*)(FdAh + off);
            ma_l[mt][kc] = *(const bfrag*)(FdAl + off);
        }
    f4v acc[2][4];
    #pragma unroll
    for (int mt = 0; mt < 2; mt++)
        #pragma unroll
        for (int nt = 0; nt < 4; nt++) acc[mt][nt] = (f4v){0.f,0.f,0.f,0.f};

    float s1a[4] = {0,0,0,0}, s2a[4] = {0,0,0,0};   // stats for c = 4*cq + j
    int cq = l & 15, r = l >> 4;
    const float* xb = x + ((long)(b*128 + h))*8192;  // this wave's h row

    #pragma unroll
    for (int kc = 0; kc < 4; kc++) {
        // ---- stage (dense): 16-lane groups read full 256B c-lines ----
        #pragma unroll
        for (int it = 0; it < 4; it++) {
            int wp = it*4 + r;                       // w-pair 0..15
            const float* src = xb + (kc*32 + wp*2)*64 + cq*4;
            float4 a = *(const float4*)src;
            float4 bb = *(const float4*)(src + 64);
            #pragma unroll
            for (int j = 0; j < 4; j++) {
                float va = ((const float*)&a)[j], vb = ((const float*)&bb)[j];
                s1a[j] += va + vb;
                s2a[j] += va*va + vb*vb;
                unsigned short ah, al2, bh2, bl2;
                split2(va, ah, al2); split2(vb, bh2, bl2);
                unsigned hp = (unsigned)ah | ((unsigned)bh2 << 16);
                unsigned lp = (unsigned)al2 | ((unsigned)bl2 << 16);
                int lc = cq + 16*j;                  // col index
                unsigned bad = (unsigned)(lc*64 + ((wp*4) ^ (((lc >> 1) & 3) << 4)));
                *(unsigned*)(wbase + bad) = hp;
                *(unsigned*)(wbase + 4096 + bad) = lp;
            }
        }
        // ---- MFMA: 4 Ntiles x 2 Mtiles, 3-term hi/lo ----
        #pragma unroll
        for (int nt = 0; nt < 4; nt++) {
            int lc = nt*16 + (l & 15);
            unsigned ro = (unsigned)(lc*64 + (((l >> 4)*16) ^ (((lc >> 1) & 3) << 4)));
            bfrag bh = *(const bfrag*)(wbase + ro);
            bfrag bl = *(const bfrag*)(wbase + 4096 + ro);
            #pragma unroll
            for (int mt = 0; mt < 2; mt++) {
                f4v a_ = acc[mt][nt];
                a_ = MFMA(ma_h[mt][kc], bh, a_);
                a_ = MFMA(ma_h[mt][kc], bl, a_);
                a_ = MFMA(ma_l[mt][kc], bh, a_);
                acc[mt][nt] = a_;
            }
        }
    }
    // ---- stats reduce (lanes r=0..3 share cq) + atomics ----
    #pragma unroll
    for (int j = 0; j < 4; j++) {
        s1a[j] += __shfl_down(s1a[j], 16, 64);
        s1a[j] += __shfl_down(s1a[j], 32, 64);
        s2a[j] += __shfl_down(s2a[j], 16, 64);
        s2a[j] += __shfl_down(s2a[j], 32, 64);
    }
    if (l < 16) {
        #pragma unroll
        for (int j = 0; j < 4; j++) {
            int c = 4*cq + j;
            atomicAdd(&ws[OFF_S1 + (b*64 + c)*2],     s1a[j]);
            atomicAdd(&ws[OFF_S1 + (b*64 + c)*2 + 1], s2a[j]);
        }
    }
    // ---- epilogue: split-pack -> wave trans buf [trow=ri*16+ky][c 64] u32 ----
    #pragma unroll
    for (int mt = 0; mt < 2; mt++)
        #pragma unroll
        for (int nt = 0; nt < 4; nt++)
            #pragma unroll
            for (int rr = 0; rr < 4; rr++) {
                float v = acc[mt][nt][rr];
                unsigned short hi, lo; split2(v, hi, lo);
                int trow = mt*16 + (l >> 4)*4 + rr;
                int c = 4*(l & 15) + nt;
                unsigned ad = (unsigned)(trow*256 + ((c*4) ^ ((trow & 7) << 4)));
                *(unsigned*)(wbase + ad) = ((unsigned)hi << 16) | (unsigned)lo;
            }
    __syncthreads();
    // ---- cross-wave gather: uint4 = 4 h values -> PT row segment ----
    unsigned* PT = (unsigned*)(ws + OFF_PQ);
    #pragma unroll
    for (int s = 0; s < 8; s++) {
        int seg = s*256 + t;
        int trow = seg >> 6, c = seg & 63;
        unsigned ad = (unsigned)(trow*256 + ((c*4) ^ ((trow & 7) << 4)));
        uint4 vz;
        vz.x = *(const unsigned*)((const char*)BTall + ad);
        vz.y = *(const unsigned*)((const char*)BTall + 8192 + ad);
        vz.z = *(const unsigned*)((const char*)BTall + 16384 + ad);
        vz.w = *(const unsigned*)((const char*)BTall + 24576 + ad);
        int ri = trow >> 4, ky = trow & 15;
        long grow = ((long)(ky*64 + c))*2 + ri;
        *(uint4*)(PT + (((long)b*2048 + grow) << 7) + hq*4) = vz;
    }
}

// MFMA forward DFT along h: X[2kx+s][(c,ri)] = EdA @ PT (per ky,b).
// Complex combine: Xr = G[2kx][colr]+G[2kx+1][coli], Xi = G[2kx][coli]-G[2kx+1][colr]
// via shfl_xor(1). grid (ky=16, b=16); wave wv = Mtile wv. X stays f32 legacy layout.
__global__ __launch_bounds__(256) void k_dfth(float* __restrict__ ws) {
    __shared__ unsigned Bsh[16384];   // BTh 32KB (128 cols x 256B) | BTl 32KB
    int t = threadIdx.x;
    int ky = blockIdx.x, b = blockIdx.y;
    int l = t & 63, wv = t >> 6;
    char* bh_base = (char*)Bsh;
    char* bl_base = bh_base + 32768;
    const unsigned* PT = (const unsigned*)(ws + OFF_PQ);
    const unsigned short* OU = (const unsigned short*)(ws + OFF_O);
    const unsigned short* EdAh = OU + 8192, *EdAl = OU + 16384;

    // ---- stage PT rows (col n = c*2+ri of this ky) -> BT[n][128 kk] hi/lo ----
    {
        int n = t >> 1, hh = (t & 1)*64;
        const uint4* src = (const uint4*)(PT + ((long)b*2048 + ky*128 + n)*128 + hh);
        #pragma unroll
        for (int jj = 0; jj < 16; jj++) {
            uint4 v = src[jj];
            unsigned h01 = (v.x >> 16) | (v.y & 0xFFFF0000u);
            unsigned h23 = (v.z >> 16) | (v.w & 0xFFFF0000u);
            unsigned l01 = (v.x & 0xFFFFu) | (v.y << 16);
            unsigned l23 = (v.z & 0xFFFFu) | (v.w << 16);
            int kk = hh + jj*4;
            unsigned ad = (unsigned)(n*256 + ((kk*2) ^ ((n & 7) << 4)));
            *(uint2*)(bh_base + ad) = make_uint2(h01, h23);
            *(uint2*)(bl_base + ad) = make_uint2(l01, l23);
        }
    }
    // A-frags for this wave's Mtile
    bfrag ea_h[4], ea_l[4];
    #pragma unroll
    for (int kc = 0; kc < 4; kc++) {
        int off = (wv*16 + (l & 15))*128 + kc*32 + (l >> 4)*8;
        ea_h[kc] = *(const bfrag*)(EdAh + off);
        ea_l[kc] = *(const bfrag*)(EdAl + off);
    }
    __syncthreads();
    f4v acc[8];
    #pragma unroll
    for (int nt = 0; nt < 8; nt++) acc[nt] = (f4v){0.f,0.f,0.f,0.f};
    #pragma unroll
    for (int kc = 0; kc < 4; kc++)
        #pragma unroll
        for (int nt = 0; nt < 8; nt++) {
            int col = nt*16 + (l & 15);
            unsigned ro = (unsigned)(col*256 + ((kc*64 + (l >> 4)*16) ^ ((col & 7) << 4)));
            bfrag bh = *(const bfrag*)(bh_base + ro);
            bfrag bl = *(const bfrag*)(bl_base + ro);
            acc[nt] = MFMA(ea_h[kc], bh, acc[nt]);
            acc[nt] = MFMA(ea_h[kc], bl, acc[nt]);
            acc[nt] = MFMA(ea_l[kc], bh, acc[nt]);
        }
    // ---- epilogue: complex combine + store X (f32, legacy layout) ----
    float* X = ws + OFF_X;
    #pragma unroll
    for (int nt = 0; nt < 8; nt++)
        #pragma unroll
        for (int p = 0; p < 2; p++) {
            float s0 = acc[nt][2*p], s1 = acc[nt][2*p + 1];
            float partner = __shfl_xor(s1, 1, 64);
            float res = (l & 1) ? (s0 - partner) : (s0 + partner);
            int kx = wv*8 + (l >> 4)*2 + p;
            X[(((long)b*32 + kx)*16 + ky)*128 + nt*16 + (l & 15)] = res;
        }
}

// per-mode complex mix with rho1 scaling folded into X staging. grid 512 (=mode)
__global__ void k_mix(float* __restrict__ ws) {
    __shared__ float Wsh[8192];
    __shared__ float Xs[2048];
    __shared__ float rhoT[1024];
    int t = threadIdx.x;
    int mode = blockIdx.x;
    int kxI = mode >> 4, ky = mode & 15;
    const float* WT = ws + OFF_WT;
    const float* X = ws + OFF_X;
    float* O = ws + OFF_O;
    for (int i = t; i < 1024; i += 256) {
        float a = ws[OFF_S1 + 2*i], s = ws[OFF_S1 + 2*i + 1];
        float m = a * (1.f/16384.f);
        float v = s * (1.f/16384.f) - m*m;
        rhoT[i] = rsqrtf(v + 1e-5f);
    }
    for (int idx = t; idx < 8192; idx += 256) Wsh[idx] = WT[(long)mode*8192 + idx];
    __syncthreads();
    for (int idx = t; idx < 2048; idx += 256) {
        int b = idx >> 7, r = idx & 127;
        Xs[idx] = X[((b*32 + kxI)*16 + ky)*128 + r] * rhoT[b*64 + (r >> 1)];
    }
    __syncthreads();
    int o = t & 63, bg = t >> 6;
    float accr[4] = {0,0,0,0}, acci[4] = {0,0,0,0};
    for (int i = 0; i < 64; i++) {
        float wr = Wsh[(i*64 + o)*2], wi = Wsh[(i*64 + o)*2 + 1];
        #pragma unroll
        for (int j = 0; j < 4; j++) {
            float xr = Xs[(bg*4 + j)*128 + 2*i], xi = Xs[(bg*4 + j)*128 + 2*i + 1];
            accr[j] += xr*wr - xi*wi;
            acci[j] += xr*wi + xi*wr;
        }
    }
    #pragma unroll
    for (int j = 0; j < 4; j++) {
        int b = bg*4 + j;
        float2* dst = (float2*)(O + ((b*32 + kxI)*16 + ky)*128);
        dst[o] = make_float2(accr[j], acci[j]);
    }
}

// Parseval stats of y directly from O. grid (16=b, 4=gg), 256 thr.
__global__ void k_pstats(float* __restrict__ ws) {
    __shared__ float red[256];
    int t = threadIdx.x, b = blockIdx.x, gg = blockIdx.y;
    int c = t & 63, g = t >> 6;
    const float* O = ws + OFF_O + (long)b*65536;   // [(kxI*16+ky)*128 + 2c]
    float t0 = 0.f, t2 = 0.f;
    int k0 = gg*8 + g*2;
    for (int kxI = k0; kxI < k0 + 2; kxI++)
        for (int ky = 0; ky < 16; ky++) {
            float re = O[(kxI*16 + ky)*128 + 2*c];
            float im = O[(kxI*16 + ky)*128 + 2*c + 1];
            float p = re*re + im*im;
            if (ky == 0) t0 += p; else t2 += p;
        }
    float s2p = 0.5f*t0 + 2.f*t2;
    if (gg == 0 && g == 0) {
        float ar = O[2*c], ai = O[2*c + 1];        // kxI=0, ky=0
        float t1 = ar*ar - ai*ai;
        for (int k = 1; k <= 15; k++) {
            float xr = O[(k*16)*128 + 2*c],        xi = O[(k*16)*128 + 2*c + 1];
            float yr = O[((32-k)*16)*128 + 2*c],   yi = O[((32-k)*16)*128 + 2*c + 1];
            t1 += 2.f*(xr*yr - xi*yi);
        }
        s2p += 0.5f*t1;
        ws[OFF_S2 + (b*64 + c)*2] = ar;            // s1 (mean term)
    }
    red[t] = s2p;
    __syncthreads();
    if (t < 64) {
        float s = red[t] + red[t+64] + red[t+128] + red[t+192];
        atomicAdd(&ws[OFF_S2 + (b*64 + t)*2 + 1], s * (1.f/16384.f));
    }
}

// inverse DFT along h: Q[b][h][ky][o] = sum_kx Out e^{+i 2pi f(kx) h/128}. grid (hg=16,b=16)
__global__ void k_idfth(float* __restrict__ ws) {
    __shared__ float Os[8192];
    __shared__ float tblL[256];
    int t = threadIdx.x;
    int hg = blockIdx.x, b = blockIdx.y;
    for (int i = t; i < 256; i += 256) tblL[i] = ws[OFF_TBL + i];
    const float* O = ws + OFF_O;
    float* Q = ws + OFF_PQ;
    int o = t & 63, kyg = t >> 6;
    float accr[4][8], acci[4][8];
    #pragma unroll
    for (int kk = 0; kk < 4; kk++)
        #pragma unroll
        for (int h = 0; h < 8; h++) { accr[kk][h] = 0.f; acci[kk][h] = 0.f; }
    for (int kc = 0; kc < 8; kc++) {
        __syncthreads();
        for (int idx = t; idx < 8192; idx += 256) Os[idx] = O[(long)b*65536 + kc*8192 + idx];
        __syncthreads();
        for (int k4 = 0; k4 < 4; k4++) {
            int kxI = kc*4 + k4;
            int freq = kxI < 16 ? kxI : 96 + kxI;
            float vr[4], vi[4];
            #pragma unroll
            for (int kk = 0; kk < 4; kk++) {
                int ky = kyg*4 + kk;
                vr[kk] = Os[((k4*16 + ky)*64 + o)*2];
                vi[kk] = Os[((k4*16 + ky)*64 + o)*2 + 1];
            }
            for (int h = 0; h < 8; h++) {
                int habs = hg*8 + h;
                int m = (freq * habs) & 127;
                float cs = tblL[2*m], sn = tblL[2*m + 1];
                #pragma unroll
                for (int kk = 0; kk < 4; kk++) {
                    accr[kk][h] += vr[kk]*cs - vi[kk]*sn;   // * e^{+i th}
                    acci[kk][h] += vr[kk]*sn + vi[kk]*cs;
                }
            }
        }
    }
    #pragma unroll
    for (int kk = 0; kk < 4; kk++)
        #pragma unroll
        for (int h = 0; h < 8; h++) {
            int ky = kyg*4 + kk, habs = hg*8 + h;
            float2* dst = (float2*)(Q + ((long)(b*128 + habs)*16 + ky)*128);
            dst[o] = make_float2(accr[kk][h], acci[kk][h]);
        }
}

// fused MFMA kernel: Y = M@Qm (iDFT-w), z = (Y-mu)*rho, h = GELU(z@W1+b1),
// out = h@W2+b2. G1 keeps hi/lo 3-MFMA (rho ~316 amplifies); z/W1/W2/h single bf16.
// LDS 75.3KB -> 2 blocks/CU. grid (h=128,b=16)
__global__ __launch_bounds__(256, 2) void k_mlp(const float* __restrict__ mb1,
                      const float* __restrict__ mb2,
                      float* __restrict__ out, const float* __restrict__ ws) {
    __shared__ unsigned short zhS[8192];                // z[w][64c], swz (w&7)<<4
    __shared__ unsigned short w1hS[8192];               // w1[j][64c], swz (j&7)<<4
    __shared__ unsigned short w2hS[8192];               // w2[o][128j], swz (o&15)<<4
    __shared__ unsigned short hhS[8192];                // h-half [w][64jl], swz (w&7)<<4
    __shared__ unsigned short qhS[2560], qlS[2560];     // QmT[c][40k] hi/lo
    __shared__ float muL[64], rhoL[64], b1L[128], b2L[64];
    int t = threadIdx.x;
    int h = blockIdx.x, b = blockIdx.y;
    int l = t & 63, wv = t >> 6;

    const unsigned short* xu = (const unsigned short*)(ws + OFF_X);
    const unsigned short* w1hG = xu;
    const unsigned short* w2hG = xu + 16384;
    const unsigned short* MhG  = xu + 32768, *MlG  = xu + 36864;

    // ---- stage weights into LDS (XOR swizzle), hi parts only ----
    for (int ch = t; ch < 1024; ch += 256) {       // w1: rows j, stride 128B
        int j = ch >> 3, c0 = (ch & 7) * 8;
        unsigned off = (unsigned)(j*128 + c0*2) ^ (unsigned)((j & 7) << 4);
        *(bfrag*)((char*)w1hS + off) = *(const bfrag*)(w1hG + ch*8);
    }
    for (int ch = t; ch < 1024; ch += 256) {       // w2: rows o, stride 256B
        int o = ch >> 4, j0 = (ch & 15) * 8;
        unsigned off = (unsigned)(o*256 + j0*2) ^ (unsigned)((o & 15) << 4);
        *(bfrag*)((char*)w2hS + off) = *(const bfrag*)(w2hG + ch*8);
    }
    // ---- QmT[c][k] build; lane-consecutive k -> ~2-way banks ----
    const float* Qp = ws + OFF_PQ + (long)(b*128 + h)*2048;
    for (int i = t; i < 2048; i += 256) {
        int k = i & 31, c = i >> 5;
        float v = Qp[(k >> 1)*128 + c*2 + (k & 1)];
        unsigned short hi, lo; split2(v, hi, lo);
        qhS[c*40 + k] = hi; qlS[c*40 + k] = lo;
    }
    if (t < 64) {
        float s1 = ws[OFF_S2 + (b*64+t)*2], s2 = ws[OFF_S2 + (b*64+t)*2 + 1];
        float m = s1 * (1.f/16384.f);
        float v = s2 * (1.f/16384.f) - m*m;
        muL[t] = m; rhoL[t] = rsqrtf(v + 1e-5f);
        b2L[t] = mb2[t];
    }
    if (t >= 64 && t < 192) b1L[t - 64] = mb1[t - 64];
    // M A-frags from global (rows w of this wave's two 16-row tiles)
    bfrag ma_h[2], ma_l[2];
    #pragma unroll
    for (int q = 0; q < 2; q++) {
        int w = (wv + 4*q)*16 + (l & 15);
        ma_h[q] = *(const bfrag*)(MhG + w*32 + (l >> 4)*8);
        ma_l[q] = *(const bfrag*)(MlG + w*32 + (l >> 4)*8);
    }
    __syncthreads();

    // ---- G1: Y = M @ Qm ; z = (Y - mu) * rho -> zhS (single bf16) ----
    #pragma unroll
    for (int q = 0; q < 2; q++) {
        int wt = wv + 4*q;
        #pragma unroll
        for (int ct = 0; ct < 4; ct++) {
            unsigned ro = (unsigned)((ct*16 + (l & 15))*80 + (l >> 4)*16);
            bfrag bh = *(const bfrag*)((const char*)qhS + ro);
            bfrag bl = *(const bfrag*)((const char*)qlS + ro);
            f4v acc = {0.f, 0.f, 0.f, 0.f};
            acc = MFMA(ma_h[q], bh, acc);
            acc = MFMA(ma_h[q], bl, acc);
            acc = MFMA(ma_l[q], bh, acc);
            int c = ct*16 + (l & 15);
            float mu_ = muL[c], rh_ = rhoL[c];
            #pragma unroll
            for (int r = 0; r < 4; r++) {
                int w = wt*16 + (l >> 4)*4 + r;
                float z = (acc[r] - mu_) * rh_;
                unsigned off = (unsigned)(w*128 + c*2) ^ (unsigned)((w & 7) << 4);
                *(unsigned short*)((char*)zhS + off) = f2bf_rn(z);
            }
        }
    }
    __syncthreads();

    // cache z A-frags (single, reused for both j-halves)
    bfrag za[2][2];
    #pragma unroll
    for (int q = 0; q < 2; q++) {
        int w = (wv + 4*q)*16 + (l & 15);
        #pragma unroll
        for (int ks = 0; ks < 2; ks++) {
            unsigned off = (unsigned)(w*128 + (ks*32 + (l >> 4)*8)*2) ^ (unsigned)((w & 7) << 4);
            za[q][ks] = *(const bfrag*)((const char*)zhS + off);
        }
    }
    f4v accO[2][4];
    #pragma unroll
    for (int q = 0; q < 2; q++)
        #pragma unroll
        for (int ot = 0; ot < 4; ot++) accO[q][ot] = (f4v){0.f,0.f,0.f,0.f};

    #pragma unroll
    for (int jh = 0; jh < 2; jh++) {
        // ---- G2: h-half = GELU(z @ W1[:, jh*64 .. +64) + b1) ----
        #pragma unroll
        for (int q = 0; q < 2; q++) {
            int wt = wv + 4*q;
            #pragma unroll
            for (int jt = 0; jt < 4; jt++) {
                int j = jh*64 + jt*16 + (l & 15);
                f4v acc = {0.f, 0.f, 0.f, 0.f};
                #pragma unroll
                for (int ks = 0; ks < 2; ks++) {
                    unsigned off = (unsigned)(j*128 + (ks*32 + (l >> 4)*8)*2) ^ (unsigned)((j & 7) << 4);
                    bfrag bh = *(const bfrag*)((const char*)w1hS + off);
                    acc = MFMA(za[q][ks], bh, acc);
                }
                float bj = b1L[j];
                #pragma unroll
                for (int r = 0; r < 4; r++) {
                    int w = wt*16 + (l >> 4)*4 + r;
                    float hv = gelu_t(acc[r] + bj);
                    int jl = jt*16 + (l & 15);
                    unsigned off = (unsigned)(w*128 + jl*2) ^ (unsigned)((w & 7) << 4);
                    *(unsigned short*)((char*)hhS + off) = f2bf_rn(hv);
                }
            }
        }
        __syncthreads();
        // ---- G3 partial: out += h-half @ W2[jh*64.., :] ----
        #pragma unroll
        for (int q = 0; q < 2; q++) {
            int w = (wv + 4*q)*16 + (l & 15);
            bfrag ha[2];
            #pragma unroll
            for (int ks = 0; ks < 2; ks++) {
                unsigned off = (unsigned)(w*128 + (ks*32 + (l >> 4)*8)*2) ^ (unsigned)((w & 7) << 4);
                ha[ks] = *(const bfrag*)((const char*)hhS + off);
            }
            #pragma unroll
            for (int ot = 0; ot < 4; ot++) {
                int o = ot*16 + (l & 15);
                f4v acc = accO[q][ot];
                #pragma unroll
                for (int ks = 0; ks < 2; ks++) {
                    int jj = jh*64 + ks*32 + (l >> 4)*8;
                    unsigned off = (unsigned)(o*256 + jj*2) ^ (unsigned)((o & 15) << 4);
                    bfrag bh = *(const bfrag*)((const char*)w2hS + off);
                    acc = MFMA(ha[ks], bh, acc);
                }
                accO[q][ot] = acc;
            }
        }
        __syncthreads();   // protect h buffer before next half overwrites
    }
    // ---- store out + b2 ----
    #pragma unroll
    for (int q = 0; q < 2; q++) {
        int wt = wv + 4*q;
        #pragma unroll
        for (int ot = 0; ot < 4; ot++) {
            int o = ot*16 + (l & 15);
            float bo = b2L[o];
            #pragma unroll
            for (int r = 0; r < 4; r++) {
                int w = wt*16 + (l >> 4)*4 + r;
                out[((long)(b*128 + h)*128 + w)*64 + o] = accO[q][ot][r] + bo;
            }
        }
    }
}

extern "C" void kernel_launch(void* const* d_in, const int* in_sizes, int n_in,
                              void* d_out, int out_size, void* d_ws, size_t ws_size,
                              hipStream_t stream) {
    const float* x   = (const float*)d_in[0];
    const float* w1r = (const float*)d_in[1];
    const float* w1i = (const float*)d_in[2];
    const float* w2r = (const float*)d_in[3];
    const float* w2i = (const float*)d_in[4];
    const float* mw1 = (const float*)d_in[5];
    const float* mb1 = (const float*)d_in[6];
    const float* mw2 = (const float*)d_in[7];
    const float* mb2 = (const float*)d_in[8];
    float* ws  = (float*)d_ws;
    float* out = (float*)d_out;

    k_init  <<<dim3(49),      dim3(256), 0, stream>>>(ws);
    k_trans <<<dim3(64,2),    dim3(256), 0, stream>>>(w1r, w1i, w2r, w2i, ws);
    k_dftw  <<<dim3(32,16),   dim3(256), 0, stream>>>(x, ws);   // stats1 folded in
    k_dfth  <<<dim3(16,16),   dim3(256), 0, stream>>>(ws);
    k_mix   <<<dim3(512),     dim3(256), 0, stream>>>(ws);
    k_wmlp  <<<dim3(80),      dim3(256), 0, stream>>>(mw1, mw2, ws);  // X dead after k_mix
    k_pstats<<<dim3(16,4),    dim3(256), 0, stream>>>(ws);
    k_idfth <<<dim3(16,16),   dim3(256), 0, stream>>>(ws);
    k_mlp   <<<dim3(128,16),  dim3(256), 0, stream>>>(mb1, mb2, out, ws);
}